// Round 6
// baseline (1674.955 us; speedup 1.0000x reference)
//
#include <hip/hip_runtime.h>

#define F_IN 144
typedef __attribute__((ext_vector_type(8))) short short8v;
typedef __attribute__((ext_vector_type(8))) unsigned short ushort8v;
typedef __attribute__((ext_vector_type(4))) float f32x4;
typedef unsigned short u16;

// ---------------- bf16 hi/lo helpers ----------------
__device__ __forceinline__ u16 bf16rn(float x) {
    union { float f; unsigned u; } a; a.f = x;
    return (u16)((a.u + 0x7FFFu + ((a.u >> 16) & 1u)) >> 16);
}
__device__ __forceinline__ float bf16tof(u16 h) {
    union { float f; unsigned u; } a; a.u = ((unsigned)h) << 16;
    return a.f;
}
__device__ __forceinline__ void gload_lds16(const u16* g, u16* s) {
    __builtin_amdgcn_global_load_lds(
        (const __attribute__((address_space(1))) void*)g,
        (__attribute__((address_space(3))) void*)s, 16, 0, 0);
}

// ---------------- utility ----------------
__global__ void zero_i32(int* __restrict__ p, int n) {
    int i = blockIdx.x * blockDim.x + threadIdx.x;
    if (i < n) p[i] = 0;
}
__global__ void zero_f32(float* __restrict__ p, int n) {
    int i = blockIdx.x * blockDim.x + threadIdx.x;
    if (i < n) p[i] = 0.f;
}
__global__ void copy_i32(const int* __restrict__ a, int* __restrict__ b, int n) {
    int i = blockIdx.x * blockDim.x + threadIdx.x;
    if (i < n) b[i] = a[i];
}
__global__ void conv_hl(const float* __restrict__ src, u16* __restrict__ dh,
                        u16* __restrict__ dl, int n) {
    int i = blockIdx.x * 256 + threadIdx.x;
    if (i < n) {
        float v = src[i];
        u16 h = bf16rn(v);
        dh[i] = h;
        dl[i] = bf16rn(v - bf16tof(h));
    }
}

// ---------------- CSR build ----------------
__global__ void count_edges(const int* __restrict__ dst, int* __restrict__ counts, int E) {
    int e = blockIdx.x * blockDim.x + threadIdx.x;
    if (e < E) atomicAdd(&counts[dst[e]], 1);
}

__global__ __launch_bounds__(1024) void scan_counts(const int* __restrict__ counts,
                                                    int* __restrict__ rowptr, int N) {
    __shared__ int part[1024];
    int t = threadIdx.x;
    int chunk = (N + 1023) >> 10;
    int beg = t * chunk;
    int end = min(beg + chunk, N);
    int s = 0;
    for (int i = beg; i < end; ++i) s += counts[i];
    part[t] = s;
    __syncthreads();
    for (int off = 1; off < 1024; off <<= 1) {
        int v = (t >= off) ? part[t - off] : 0;
        __syncthreads();
        part[t] += v;
        __syncthreads();
    }
    int run = (t == 0) ? 0 : part[t - 1];
    for (int i = beg; i < end; ++i) { rowptr[i] = run; run += counts[i]; }
    if (end == N) rowptr[N] = run;
}

__global__ void fill_edges(const int* __restrict__ src, const int* __restrict__ dst,
                           const float* __restrict__ ea, int* __restrict__ fillhead,
                           int* __restrict__ col, float* __restrict__ wv, int E) {
    int e = blockIdx.x * blockDim.x + threadIdx.x;
    if (e < E) {
        int d = dst[e];
        int pos = atomicAdd(&fillhead[d], 1);
        col[pos] = src[e];
        wv[pos]  = ea[e];
    }
}

// ---------------- aggregation: lane-split hi/lo, one wave per node ----------------
// MODE 0: out = agg (hi/lo planes). MODE 1: out = agg + root (hi/lo planes).
// MODE 2: out = agg + root (f32).
template<int MODE>
__global__ __launch_bounds__(256) void aggregate2(
    const u16* __restrict__ Sh, const u16* __restrict__ Sl, int SS, int NC,
    const int* __restrict__ rowptr, const int* __restrict__ col,
    const float* __restrict__ wv,
    const u16* __restrict__ Rh, const u16* __restrict__ Rl,
    u16* __restrict__ Dh, u16* __restrict__ Dl, float* __restrict__ Df,
    int F, int N)
{
    int wid = (int)((blockIdx.x * 256 + threadIdx.x) >> 6);
    if (wid >= N) return;
    int lane = threadIdx.x & 63;
    int half = lane >> 5;     // 0: hi plane, 1: lo plane
    int cl   = lane & 31;     // 8-feature chunk index
    float acc[8] = {};
    int beg = rowptr[wid], end = rowptr[wid + 1];
    if (cl < NC) {
        const u16* S = half ? Sl : Sh;
        for (int e = beg; e < end; ++e) {
            float wgt = wv[e];
            ushort8v v = *(const ushort8v*)&S[(size_t)col[e] * SS + (cl << 3)];
#pragma unroll
            for (int r = 0; r < 8; ++r) acc[r] = fmaf(wgt, bf16tof(v[r]), acc[r]);
        }
        if (MODE >= 1) {
            const u16* R = half ? Rl : Rh;
            ushort8v v = *(const ushort8v*)&R[(size_t)wid * SS + (cl << 3)];
#pragma unroll
            for (int r = 0; r < 8; ++r) acc[r] += bf16tof(v[r]);
        }
    }
#pragma unroll
    for (int r = 0; r < 8; ++r) acc[r] += __shfl_xor(acc[r], 32);
    if (cl < NC) {
        if (MODE == 2) {
            float4 o = half ? make_float4(acc[4], acc[5], acc[6], acc[7])
                            : make_float4(acc[0], acc[1], acc[2], acc[3]);
            *(float4*)&Df[(size_t)wid * F + (cl << 3) + half * 4] = o;
        } else if (half == 0) {
            ushort8v o;
#pragma unroll
            for (int r = 0; r < 8; ++r) o[r] = bf16rn(acc[r]);
            *(ushort8v*)&Dh[(size_t)wid * F + (cl << 3)] = o;
        } else {
            ushort8v o;
#pragma unroll
            for (int r = 0; r < 8; ++r) {
                u16 h = bf16rn(acc[r]);
                o[r] = bf16rn(acc[r] - bf16tof(h));
            }
            *(ushort8v*)&Dl[(size_t)wid * F + (cl << 3)] = o;
        }
    }
}

// ---------------- split-bf16 MFMA GEMM, 128x128, double-buffered 2-phase ---------
// DUALK=true : A = [A1|A2] along K (KK=2*K1), B = [B1|B2] along K. (aggregate-first)
// DUALK=false: A = A1 (KK=K1), B rows: r<NR1 -> B1[r], else B2[r-NR1]. (transform-first)
// 3-term split product: C = Ah*Bh + Ah*Bl + Al*Bh (~fp24). Output hi/lo planes.
// 2 LDS buffers x 32KB: per buffer Ah[0,4096) Al[..8192) Bh[..12288) Bl[..16384) u16,
// plane = 128 rows x 32 k. Stage of tile t+1 issued BEFORE compute of tile t; single
// __syncthreads() per step (its vmcnt(0) drain lands after the compute phase).
// XOR chunk swizzle on global source + ds_read (both-sides, G21); 0 bank conflicts.
#define GBM 128
#define GBN 128
#define GBK 32

template<bool DUALK>
__global__ __launch_bounds__(256) void gemm2(
    const u16* __restrict__ A1h, const u16* __restrict__ A1l,
    const u16* __restrict__ A2h, const u16* __restrict__ A2l,
    const u16* __restrict__ B1h, const u16* __restrict__ B1l,
    const u16* __restrict__ B2h, const u16* __restrict__ B2l,
    const float* __restrict__ biasA, const float* __restrict__ biasB,
    u16* __restrict__ Ch, u16* __restrict__ Cl,
    int M, int K1, int NR1, int ldc, int doRelu)
{
    __shared__ u16 lds[32768];   // 2 x 32KB buffers

    const int tid = threadIdx.x;
    const int l = tid & 63, w = tid >> 6;
    const int wm = w >> 1, wn = w & 1;           // 2x2 wave grid, 64x64 each
    const int lane15 = l & 15, slot = l >> 4;
    const int row0 = blockIdx.x * GBM;
    const int col0 = blockIdx.y * GBN;
    const int KK = DUALK ? 2 * K1 : K1;
    const int nsteps = KK / GBK;

    // stage one 32KB buffer: 2048 chunks of 16B, 8 per thread.
    // idx = i*256+tid: plane p=idx>>9 (Ah,Al,Bh,Bl), row rw=(idx>>2)&127, chunk c=idx&3.
    // LDS dest linear; source chunk pre-swizzled: cp = c ^ ((rw>>1)&3).
    auto stage = [&](u16* buf, int kk0) {
#pragma unroll
        for (int i = 0; i < 8; ++i) {
            int idx = i * 256 + tid;
            int p   = idx >> 9;
            int rw  = (idx >> 2) & 127;
            int c   = idx & 3;
            int cp  = c ^ ((rw >> 1) & 3);
            int k   = kk0 + (cp << 3);
            const u16* sp; size_t off;
            if (p < 2) {
                int gr = min(row0 + rw, M - 1);
                int kk = k;
                if (DUALK && k >= K1) { sp = (p == 0) ? A2h : A2l; kk = k - K1; }
                else                  { sp = (p == 0) ? A1h : A1l; }
                off = (size_t)gr * K1 + kk;
            } else {
                int gc = col0 + rw;
                int kk = k, rb = gc;
                if (DUALK) {
                    if (k >= K1) { sp = (p == 2) ? B2h : B2l; kk = k - K1; }
                    else         { sp = (p == 2) ? B1h : B1l; }
                } else {
                    if (gc >= NR1) { sp = (p == 2) ? B2h : B2l; rb = gc - NR1; }
                    else           { sp = (p == 2) ? B1h : B1l; }
                }
                off = (size_t)rb * K1 + kk;
            }
            gload_lds16(sp + off, buf + ((size_t)p << 12) + ((idx & 511) << 3));
        }
    };

    f32x4 acc[4][4] = {};

    // prologue: stage tile 0 into buffer 0
    stage(lds, 0);
    __syncthreads();

    int cur = 0;
    for (int step = 0; step < nsteps; ++step) {
        u16* cbuf = lds + (cur << 14);
        // issue next tile's loads first — they fly under the compute below
        if (step + 1 < nsteps) stage(lds + ((cur ^ 1) << 14), (step + 1) * GBK);

        short8v bh[4], bl[4];
#pragma unroll
        for (int bj = 0; bj < 4; ++bj) {
            int cc = wn * 64 + bj * 16 + lane15;
            int j = slot ^ ((cc >> 1) & 3);
            bh[bj] = *(const short8v*)&cbuf[8192 + cc * 32 + j * 8];
            bl[bj] = *(const short8v*)&cbuf[12288 + cc * 32 + j * 8];
        }
#pragma unroll
        for (int bi = 0; bi < 4; ++bi) {
            int r = wm * 64 + bi * 16 + lane15;
            int j = slot ^ ((r >> 1) & 3);
            short8v ah = *(const short8v*)&cbuf[r * 32 + j * 8];
            short8v al = *(const short8v*)&cbuf[4096 + r * 32 + j * 8];
#pragma unroll
            for (int bj = 0; bj < 4; ++bj) {
                acc[bi][bj] = __builtin_amdgcn_mfma_f32_16x16x32_bf16(ah, bh[bj], acc[bi][bj], 0, 0, 0);
                acc[bi][bj] = __builtin_amdgcn_mfma_f32_16x16x32_bf16(ah, bl[bj], acc[bi][bj], 0, 0, 0);
                acc[bi][bj] = __builtin_amdgcn_mfma_f32_16x16x32_bf16(al, bh[bj], acc[bi][bj], 0, 0, 0);
            }
        }
        __syncthreads();   // drains this wave's stage loads; all waves done reading cbuf
        cur ^= 1;
    }

    // ---- epilogue: C/D layout col=lane&15, row=slot*4+q ----
#pragma unroll
    for (int bj = 0; bj < 4; ++bj) {
        int cc = col0 + wn * 64 + bj * 16 + lane15;
        float bv = (cc < NR1) ? (biasA ? biasA[cc] : 0.f)
                              : (biasB ? biasB[cc - NR1] : 0.f);
#pragma unroll
        for (int bi = 0; bi < 4; ++bi) {
            int rbase = row0 + wm * 64 + bi * 16 + slot * 4;
#pragma unroll
            for (int q = 0; q < 4; ++q) {
                int rr = rbase + q;
                if (rr < M) {
                    float o = acc[bi][bj][q] + bv;
                    if (doRelu) o = fmaxf(o, 0.f);
                    u16 h = bf16rn(o);
                    Ch[(size_t)rr * ldc + cc] = h;
                    Cl[(size_t)rr * ldc + cc] = bf16rn(o - bf16tof(h));
                }
            }
        }
    }
}

// ---------------- GraphNorm (F = 256) on hi/lo storage ----------------
__global__ __launch_bounds__(256) void colstats_hl(const u16* __restrict__ Hh,
                                                   const u16* __restrict__ Hl,
                                                   float* __restrict__ sums,
                                                   float* __restrict__ sqs, int N) {
    int f = threadIdx.x;
    float s = 0.f, q = 0.f;
    for (int i = blockIdx.x; i < N; i += gridDim.x) {
        float v = bf16tof(Hh[(size_t)i * 256 + f]) + bf16tof(Hl[(size_t)i * 256 + f]);
        s += v;
        q = fmaf(v, v, q);
    }
    atomicAdd(&sums[f], s);
    atomicAdd(&sqs[f], q);
}

__global__ void norm_prep(const float* __restrict__ sums, const float* __restrict__ sqs,
                          const float* __restrict__ gw, const float* __restrict__ gb,
                          const float* __restrict__ gms, float* __restrict__ scaleF,
                          float* __restrict__ shiftF, float invN) {
    int f = threadIdx.x;  // 256 threads
    float mu  = sums[f] * invN;
    float ex2 = sqs[f] * invN;
    float a   = gms[f] * mu;
    float var = ex2 - 2.f * a * mu + a * a;
    float inv = rsqrtf(var + 1e-5f);
    float sc  = gw[f] * inv;
    scaleF[f] = sc;
    shiftF[f] = gb[f] - a * sc;
}

__global__ __launch_bounds__(256) void norm_apply_hl(
    ushort4* __restrict__ Hh, ushort4* __restrict__ Hl,
    const float4* __restrict__ scaleF, const float4* __restrict__ shiftF, int n4) {
    int i = blockIdx.x * 256 + threadIdx.x;
    if (i >= n4) return;
    int f4 = i & 63;
    ushort4 h = Hh[i], lo = Hl[i];
    float4 sc = scaleF[f4], sh = shiftF[f4];
    float vx = fmaxf(fmaf(bf16tof(h.x) + bf16tof(lo.x), sc.x, sh.x), 0.f);
    float vy = fmaxf(fmaf(bf16tof(h.y) + bf16tof(lo.y), sc.y, sh.y), 0.f);
    float vz = fmaxf(fmaf(bf16tof(h.z) + bf16tof(lo.z), sc.z, sh.z), 0.f);
    float vw = fmaxf(fmaf(bf16tof(h.w) + bf16tof(lo.w), sc.w, sh.w), 0.f);
    ushort4 oh, ol;
    oh.x = bf16rn(vx); ol.x = bf16rn(vx - bf16tof(oh.x));
    oh.y = bf16rn(vy); ol.y = bf16rn(vy - bf16tof(oh.y));
    oh.z = bf16rn(vz); ol.z = bf16rn(vz - bf16tof(oh.z));
    oh.w = bf16rn(vw); ol.w = bf16rn(vw - bf16tof(oh.w));
    Hh[i] = oh;
    Hl[i] = ol;
}

// ---------------- launch ----------------
extern "C" void kernel_launch(void* const* d_in, const int* in_sizes, int n_in,
                              void* d_out, int out_size, void* d_ws, size_t ws_size,
                              hipStream_t stream) {
    const float* x   = (const float*)d_in[0];
    const int*   ei  = (const int*)d_in[1];
    const float* ea  = (const float*)d_in[2];
    const float* Wr1 = (const float*)d_in[3];
    const float* b1  = (const float*)d_in[4];
    const float* Wo1 = (const float*)d_in[5];
    const float* Wr2 = (const float*)d_in[6];
    const float* b2  = (const float*)d_in[7];
    const float* Wo2 = (const float*)d_in[8];
    const float* Wr3 = (const float*)d_in[9];
    const float* b3  = (const float*)d_in[10];
    const float* Wo3 = (const float*)d_in[11];
    const float* Wr4 = (const float*)d_in[12];
    const float* b4  = (const float*)d_in[13];
    const float* Wo4 = (const float*)d_in[14];
    const float* gw  = (const float*)d_in[15];
    const float* gb  = (const float*)d_in[16];
    const float* gms = (const float*)d_in[17];

    const int Nn = in_sizes[0] / F_IN;   // 50000
    const int E  = in_sizes[1] / 2;      // 400000
    const int* src = ei;
    const int* dst = ei + E;

    char* wp = (char*)d_ws;
    auto alloc = [&](size_t bytes) -> void* {
        void* p = (void*)wp;
        wp += (bytes + 255) & ~(size_t)255;
        return p;
    };
    int*   counts   = (int*)alloc((size_t)Nn * 4);
    int*   rowptr   = (int*)alloc((size_t)(Nn + 1) * 4);
    int*   fillhead = (int*)alloc((size_t)Nn * 4);
    int*   col      = (int*)alloc((size_t)E * 4);
    float* wv       = (float*)alloc((size_t)E * 4);
    float* stats    = (float*)alloc(1024 * 4);
    float* sums = stats, *sqs = stats + 256, *scaleF = stats + 512, *shiftF = stats + 768;
    // weights hi/lo
    u16* wr1h = (u16*)alloc(2u * 256 * 144); u16* wr1l = (u16*)alloc(2u * 256 * 144);
    u16* wo1h = (u16*)alloc(2u * 256 * 144); u16* wo1l = (u16*)alloc(2u * 256 * 144);
    u16* wr2h = (u16*)alloc(2u * 512 * 256); u16* wr2l = (u16*)alloc(2u * 512 * 256);
    u16* wo2h = (u16*)alloc(2u * 512 * 256); u16* wo2l = (u16*)alloc(2u * 512 * 256);
    u16* wr3h = (u16*)alloc(2u * 256 * 512); u16* wr3l = (u16*)alloc(2u * 256 * 512);
    u16* wo3h = (u16*)alloc(2u * 256 * 512); u16* wo3l = (u16*)alloc(2u * 256 * 512);
    u16* wr4h = (u16*)alloc(2u * 128 * 256); u16* wr4l = (u16*)alloc(2u * 128 * 256);
    u16* wo4h = (u16*)alloc(2u * 128 * 256); u16* wo4l = (u16*)alloc(2u * 128 * 256);

    // ---- single lifetime-packed big region (u16 units), total Nn*2336*2 B = 233.6 MB ----
    // live layout:  X[0, 288) | AGG[288, 800) | H1[800, 1312) | H2[1312, 2336)   (per node)
    // reuse:        Y3 -> [0, 1024)   (X+AGG+H1 dead after GEMM2)
    //               H3 -> [1312, 1824) (H2 dead after GEMM3)
    //               Y4 -> [0, 512)    (Y3 dead after L3 aggregate)
    u16* big = (u16*)alloc((size_t)Nn * 2336 * 2);
    const size_t NS = (size_t)Nn;
    u16* Xh  = big;               u16* Xl  = big + NS * 144;
    u16* AGh = big + NS * 288;    u16* AGl = big + NS * 544;
    u16* H1h = big + NS * 800;    u16* H1l = big + NS * 1056;
    u16* H2h = big + NS * 1312;   u16* H2l = big + NS * 1824;
    u16* Y3h = big;               u16* Y3l = big + NS * 512;
    u16* H3h = big + NS * 1312;   u16* H3l = big + NS * 1568;
    u16* Y4h = big;               u16* Y4l = big + NS * 256;

    const int TB = 256;
    // CSR build
    zero_i32<<<(Nn + TB - 1) / TB, TB, 0, stream>>>(counts, Nn);
    count_edges<<<(E + TB - 1) / TB, TB, 0, stream>>>(dst, counts, E);
    scan_counts<<<1, 1024, 0, stream>>>(counts, rowptr, Nn);
    copy_i32<<<(Nn + TB - 1) / TB, TB, 0, stream>>>(rowptr, fillhead, Nn);
    fill_edges<<<(E + TB - 1) / TB, TB, 0, stream>>>(src, dst, ea, fillhead, col, wv, E);

    // conversions
    int nx = Nn * F_IN;
    conv_hl<<<(nx + 255) / 256, 256, 0, stream>>>(x, Xh, Xl, nx);
    struct WC { const float* s; u16* h; u16* l; int n; } wc[8] = {
        {Wr1, wr1h, wr1l, 256 * 144}, {Wo1, wo1h, wo1l, 256 * 144},
        {Wr2, wr2h, wr2l, 512 * 256}, {Wo2, wo2h, wo2l, 512 * 256},
        {Wr3, wr3h, wr3l, 256 * 512}, {Wo3, wo3h, wo3l, 256 * 512},
        {Wr4, wr4h, wr4l, 128 * 256}, {Wo4, wo4h, wo4l, 128 * 256}};
    for (int i = 0; i < 8; ++i)
        conv_hl<<<(wc[i].n + 255) / 256, 256, 0, stream>>>(wc[i].s, wc[i].h, wc[i].l, wc[i].n);

    int aggGrid = (Nn + 3) / 4;
    int mB = (Nn + GBM - 1) / GBM;  // 391

    // Layer 1 (aggregate-first): agg(x) ; [agg|x] * [Wr1|Wo1]^T + b1, relu -> H1
    aggregate2<0><<<aggGrid, TB, 0, stream>>>(Xh, Xl, 144, 18, rowptr, col, wv,
                                              nullptr, nullptr, AGh, AGl, nullptr, 144, Nn);
    gemm2<true><<<dim3(mB, 2), 256, 0, stream>>>(AGh, AGl, Xh, Xl,
                                                 wr1h, wr1l, wo1h, wo1l,
                                                 b1, nullptr, H1h, H1l,
                                                 Nn, 144, 256, 256, 1);
    // Layer 2 (aggregate-first): 256 -> 512, relu -> H2
    aggregate2<0><<<aggGrid, TB, 0, stream>>>(H1h, H1l, 256, 32, rowptr, col, wv,
                                              nullptr, nullptr, AGh, AGl, nullptr, 256, Nn);
    gemm2<true><<<dim3(mB, 4), 256, 0, stream>>>(AGh, AGl, H1h, H1l,
                                                 wr2h, wr2l, wo2h, wo2l,
                                                 b2, nullptr, H2h, H2l,
                                                 Nn, 256, 512, 512, 1);
    // Layer 3 (transform-first): Y3 = [H2*Wr3^T, H2*Wo3^T + b3]; H3 = agg(Yrel)+Yroot
    gemm2<false><<<dim3(mB, 4), 256, 0, stream>>>(H2h, H2l, H2h, H2l,
                                                  wr3h, wr3l, wo3h, wo3l,
                                                  nullptr, b3, Y3h, Y3l,
                                                  Nn, 512, 256, 512, 0);
    aggregate2<1><<<aggGrid, TB, 0, stream>>>(Y3h, Y3l, 512, 32, rowptr, col, wv,
                                              Y3h + 256, Y3l + 256, H3h, H3l, nullptr, 256, Nn);
    // GraphNorm + relu in place on H3
    zero_f32<<<2, TB, 0, stream>>>(stats, 512);
    colstats_hl<<<256, TB, 0, stream>>>(H3h, H3l, sums, sqs, Nn);
    norm_prep<<<1, 256, 0, stream>>>(sums, sqs, gw, gb, gms, scaleF, shiftF, 1.0f / Nn);
    norm_apply_hl<<<(Nn * 64 + TB - 1) / TB, TB, 0, stream>>>(
        (ushort4*)H3h, (ushort4*)H3l, (const float4*)scaleF, (const float4*)shiftF, Nn * 64);
    // Layer 4 (transform-first): Y4 = [H3*Wr4^T, H3*Wo4^T + b4]; out = agg(Yrel)+Yroot (f32)
    gemm2<false><<<dim3(mB, 2), 256, 0, stream>>>(H3h, H3l, H3h, H3l,
                                                  wr4h, wr4l, wo4h, wo4l,
                                                  nullptr, b4, Y4h, Y4l,
                                                  Nn, 256, 128, 256, 0);
    aggregate2<2><<<aggGrid, TB, 0, stream>>>(Y4h, Y4l, 256, 16, rowptr, col, wv,
                                              Y4h + 128, Y4l + 128, nullptr, nullptr,
                                              (float*)d_out, 128, Nn);
}

// Round 7
// 893.952 us; speedup vs baseline: 1.8737x; 1.8737x over previous
//
#include <hip/hip_runtime.h>

#define F_IN 144
typedef __attribute__((ext_vector_type(8))) short short8v;
typedef __attribute__((ext_vector_type(8))) unsigned short ushort8v;
typedef __attribute__((ext_vector_type(4))) float f32x4;
typedef unsigned short u16;

// ---------------- bf16 hi/lo helpers ----------------
__device__ __forceinline__ u16 bf16rn(float x) {
    union { float f; unsigned u; } a; a.f = x;
    return (u16)((a.u + 0x7FFFu + ((a.u >> 16) & 1u)) >> 16);
}
__device__ __forceinline__ float bf16tof(u16 h) {
    union { float f; unsigned u; } a; a.u = ((unsigned)h) << 16;
    return a.f;
}
__device__ __forceinline__ void gload_lds16(const u16* g, u16* s) {
    __builtin_amdgcn_global_load_lds(
        (const __attribute__((address_space(1))) void*)g,
        (__attribute__((address_space(3))) void*)s, 16, 0, 0);
}

// ---------------- utility ----------------
__global__ void zero_i32(int* __restrict__ p, int n) {
    int i = blockIdx.x * blockDim.x + threadIdx.x;
    if (i < n) p[i] = 0;
}
__global__ void zero_f32(float* __restrict__ p, int n) {
    int i = blockIdx.x * blockDim.x + threadIdx.x;
    if (i < n) p[i] = 0.f;
}
__global__ void copy_i32(const int* __restrict__ a, int* __restrict__ b, int n) {
    int i = blockIdx.x * blockDim.x + threadIdx.x;
    if (i < n) b[i] = a[i];
}
__global__ void conv_hl(const float* __restrict__ src, u16* __restrict__ dh,
                        u16* __restrict__ dl, int n) {
    int i = blockIdx.x * 256 + threadIdx.x;
    if (i < n) {
        float v = src[i];
        u16 h = bf16rn(v);
        dh[i] = h;
        dl[i] = bf16rn(v - bf16tof(h));
    }
}

// ---------------- CSR build ----------------
__global__ void count_edges(const int* __restrict__ dst, int* __restrict__ counts, int E) {
    int e = blockIdx.x * blockDim.x + threadIdx.x;
    if (e < E) atomicAdd(&counts[dst[e]], 1);
}

__global__ __launch_bounds__(1024) void scan_counts(const int* __restrict__ counts,
                                                    int* __restrict__ rowptr, int N) {
    __shared__ int part[1024];
    int t = threadIdx.x;
    int chunk = (N + 1023) >> 10;
    int beg = t * chunk;
    int end = min(beg + chunk, N);
    int s = 0;
    for (int i = beg; i < end; ++i) s += counts[i];
    part[t] = s;
    __syncthreads();
    for (int off = 1; off < 1024; off <<= 1) {
        int v = (t >= off) ? part[t - off] : 0;
        __syncthreads();
        part[t] += v;
        __syncthreads();
    }
    int run = (t == 0) ? 0 : part[t - 1];
    for (int i = beg; i < end; ++i) { rowptr[i] = run; run += counts[i]; }
    if (end == N) rowptr[N] = run;
}

__global__ void fill_edges(const int* __restrict__ src, const int* __restrict__ dst,
                           const float* __restrict__ ea, int* __restrict__ fillhead,
                           int* __restrict__ col, float* __restrict__ wv, int E) {
    int e = blockIdx.x * blockDim.x + threadIdx.x;
    if (e < E) {
        int d = dst[e];
        int pos = atomicAdd(&fillhead[d], 1);
        col[pos] = src[e];
        wv[pos]  = ea[e];
    }
}

// ---------------- aggregation: lane-split hi/lo, one wave per node ----------------
// MODE 0: out = agg (hi/lo planes). MODE 1: out = agg + root (hi/lo planes).
template<int MODE>
__global__ __launch_bounds__(256) void aggregate2(
    const u16* __restrict__ Sh, const u16* __restrict__ Sl, int SS, int NC,
    const int* __restrict__ rowptr, const int* __restrict__ col,
    const float* __restrict__ wv,
    const u16* __restrict__ Rh, const u16* __restrict__ Rl,
    u16* __restrict__ Dh, u16* __restrict__ Dl,
    int F, int N)
{
    int wid = (int)((blockIdx.x * 256 + threadIdx.x) >> 6);
    if (wid >= N) return;
    int lane = threadIdx.x & 63;
    int half = lane >> 5;     // 0: hi plane, 1: lo plane
    int cl   = lane & 31;     // 8-feature chunk index
    float acc[8] = {};
    int beg = rowptr[wid], end = rowptr[wid + 1];
    if (cl < NC) {
        const u16* S = half ? Sl : Sh;
        for (int e = beg; e < end; ++e) {
            float wgt = wv[e];
            ushort8v v = *(const ushort8v*)&S[(size_t)col[e] * SS + (cl << 3)];
#pragma unroll
            for (int r = 0; r < 8; ++r) acc[r] = fmaf(wgt, bf16tof(v[r]), acc[r]);
        }
        if (MODE >= 1) {
            const u16* R = half ? Rl : Rh;
            ushort8v v = *(const ushort8v*)&R[(size_t)wid * SS + (cl << 3)];
#pragma unroll
            for (int r = 0; r < 8; ++r) acc[r] += bf16tof(v[r]);
        }
    }
#pragma unroll
    for (int r = 0; r < 8; ++r) acc[r] += __shfl_xor(acc[r], 32);
    if (cl < NC) {
        if (half == 0) {
            ushort8v o;
#pragma unroll
            for (int r = 0; r < 8; ++r) o[r] = bf16rn(acc[r]);
            *(ushort8v*)&Dh[(size_t)wid * F + (cl << 3)] = o;
        } else {
            ushort8v o;
#pragma unroll
            for (int r = 0; r < 8; ++r) {
                u16 h = bf16rn(acc[r]);
                o[r] = bf16rn(acc[r] - bf16tof(h));
            }
            *(ushort8v*)&Dl[(size_t)wid * F + (cl << 3)] = o;
        }
    }
}

// ---- final aggregate: 2 nodes per wave (F=128, 16 chunks), f32 out = agg + root ----
__global__ __launch_bounds__(256) void aggregate_out2(
    const u16* __restrict__ Sh, const u16* __restrict__ Sl, int SS,
    const int* __restrict__ rowptr, const int* __restrict__ col,
    const float* __restrict__ wv,
    const u16* __restrict__ Rh, const u16* __restrict__ Rl,
    float* __restrict__ Df, int N)
{
    int wav = (int)((blockIdx.x * 256 + threadIdx.x) >> 6);
    int lane = threadIdx.x & 63;
    int wid  = wav * 2 + (lane >> 5);    // node
    if (wid >= N) return;
    int half = (lane >> 4) & 1;          // 0: hi plane, 1: lo plane
    int cl   = lane & 15;                // chunk (8 feats), 16 chunks = 128
    float acc[8] = {};
    int beg = rowptr[wid], end = rowptr[wid + 1];
    const u16* S = half ? Sl : Sh;
    for (int e = beg; e < end; ++e) {
        float wgt = wv[e];
        ushort8v v = *(const ushort8v*)&S[(size_t)col[e] * SS + (cl << 3)];
#pragma unroll
        for (int r = 0; r < 8; ++r) acc[r] = fmaf(wgt, bf16tof(v[r]), acc[r]);
    }
    const u16* R = half ? Rl : Rh;
    ushort8v v = *(const ushort8v*)&R[(size_t)wid * SS + (cl << 3)];
#pragma unroll
    for (int r = 0; r < 8; ++r) acc[r] += bf16tof(v[r]);
#pragma unroll
    for (int r = 0; r < 8; ++r) acc[r] += __shfl_xor(acc[r], 16);  // combine hi+lo
    float4 o = half ? make_float4(acc[4], acc[5], acc[6], acc[7])
                    : make_float4(acc[0], acc[1], acc[2], acc[3]);
    *(float4*)&Df[(size_t)wid * 128 + (cl << 3) + half * 4] = o;
}

// ---------------- split-bf16 MFMA GEMM (round-3 core + hoisted staging) ----------
// DUALK=true : A = [A1|A2] along K (KK=2*K1), B = [B1|B2] along K.
// DUALK=false: A = A1 (KK=K1), B rows: r<NR1 -> B1[r], else B2[r-NR1]. NR1 % 128 == 0
//              so each 128-col block maps to exactly one source (uniform select).
// 3-term split product: C = Ah*Bh + Ah*Bl + Al*Bh (~fp24). Output hi/lo planes.
// 128x128 tile, 4 waves (wave w stages plane w), 32KB LDS single-buffered,
// XOR chunk swizzle on global source + ds_read (both sides, G21).
// Staging addresses hoisted: cp = lc ^ ((lr>>1)&3) is K-step- and i-invariant
// (r = i*16+lr -> (r>>1)&3 == (lr>>1)&3); per-lane rowoff[8] precomputed,
// per step just one base select + (rowoff + kk0).
#define GBM 128
#define GBN 128

template<bool DUALK>
__global__ __launch_bounds__(256) void gemm3(
    const u16* __restrict__ A1h, const u16* __restrict__ A1l,
    const u16* __restrict__ A2h, const u16* __restrict__ A2l,
    const u16* __restrict__ B1h, const u16* __restrict__ B1l,
    const u16* __restrict__ B2h, const u16* __restrict__ B2l,
    const float* __restrict__ biasA, const float* __restrict__ biasB,
    u16* __restrict__ Ch, u16* __restrict__ Cl,
    int M, int K1, int NR1, int ldc, int doRelu)
{
    __shared__ u16 lds[16384];          // 32 KB: Ah | Al | Bh | Bl (4096 u16 each)
    u16* sAh = lds;
    u16* sAl = lds + 4096;
    u16* sBh = lds + 8192;
    u16* sBl = lds + 12288;

    const int tid = threadIdx.x;
    const int l = tid & 63, w = tid >> 6;
    const int wm = w >> 1, wn = w & 1;
    const int lane15 = l & 15, slot = l >> 4;
    const int row0 = blockIdx.x * GBM;
    const int col0 = blockIdx.y * GBN;
    const int KK = DUALK ? 2 * K1 : K1;

    // ---- staging precompute: wave w stages plane w (0:Ah 1:Al 2:Bh 3:Bl) ----
    const bool isA = (w < 2);
    const int lr = l >> 2, lc = l & 3;
    const int cpk = (lc ^ ((lr >> 1) & 3)) << 3;   // swizzled source chunk offset (u16)
    const u16 *bp1, *bp2;
    if (isA) {
        bp1 = (w == 0) ? A1h : A1l;
        bp2 = ((w == 0) ? A2h : A2l) - K1;         // pre-shifted for k >= K1
    } else if (DUALK) {
        bp1 = (w == 2) ? B1h : B1l;
        bp2 = ((w == 2) ? B2h : B2l) - K1;
    } else {
        bool sec = (col0 >= NR1);                  // uniform per block (NR1 % 128 == 0)
        bp1 = sec ? ((w == 2) ? B2h : B2l) : ((w == 2) ? B1h : B1l);
        bp2 = bp1;
    }
    int rowoff[8];
#pragma unroll
    for (int i = 0; i < 8; ++i) {
        int r = i * 16 + lr;
        int g;
        if (isA)       g = min(row0 + r, M - 1);
        else if (DUALK) g = col0 + r;
        else            g = col0 + r - ((col0 >= NR1) ? NR1 : 0);
        rowoff[i] = g * K1 + cpk;
    }
    u16* sdst = lds + (w << 12);

    f32x4 acc[4][4] = {};

    for (int kk0 = 0; kk0 < KK; kk0 += 32) {
        __syncthreads();  // prior compute done before LDS overwrite
        {
            const u16* bp = (DUALK && (kk0 + cpk >= K1)) ? bp2 : bp1;
#pragma unroll
            for (int i = 0; i < 8; ++i)
                gload_lds16(bp + rowoff[i] + kk0, sdst + i * 512);
        }
        __syncthreads();  // compiler drains vmcnt before barrier

        short8v ah[4], al[4];
#pragma unroll
        for (int bi = 0; bi < 4; ++bi) {
            int r = wm * 64 + bi * 16 + lane15;
            int j = slot ^ ((r >> 1) & 3);
            ah[bi] = *(const short8v*)&sAh[r * 32 + j * 8];
            al[bi] = *(const short8v*)&sAl[r * 32 + j * 8];
        }
#pragma unroll
        for (int bj = 0; bj < 4; ++bj) {
            int c = wn * 64 + bj * 16 + lane15;
            int j = slot ^ ((c >> 1) & 3);
            short8v bh = *(const short8v*)&sBh[c * 32 + j * 8];
            short8v bl = *(const short8v*)&sBl[c * 32 + j * 8];
#pragma unroll
            for (int bi = 0; bi < 4; ++bi) {
                acc[bi][bj] = __builtin_amdgcn_mfma_f32_16x16x32_bf16(ah[bi], bh, acc[bi][bj], 0, 0, 0);
                acc[bi][bj] = __builtin_amdgcn_mfma_f32_16x16x32_bf16(ah[bi], bl, acc[bi][bj], 0, 0, 0);
                acc[bi][bj] = __builtin_amdgcn_mfma_f32_16x16x32_bf16(al[bi], bh, acc[bi][bj], 0, 0, 0);
            }
        }
    }

    // ---- epilogue: C/D layout col=lane&15, row=slot*4+q ----
#pragma unroll
    for (int bj = 0; bj < 4; ++bj) {
        int cc = col0 + wn * 64 + bj * 16 + lane15;
        float bv = (cc < NR1) ? (biasA ? biasA[cc] : 0.f)
                              : (biasB ? biasB[cc - NR1] : 0.f);
#pragma unroll
        for (int bi = 0; bi < 4; ++bi) {
            int rbase = row0 + wm * 64 + bi * 16 + slot * 4;
#pragma unroll
            for (int q = 0; q < 4; ++q) {
                int rr = rbase + q;
                if (rr < M) {
                    float o = acc[bi][bj][q] + bv;
                    if (doRelu) o = fmaxf(o, 0.f);
                    u16 h = bf16rn(o);
                    Ch[(size_t)rr * ldc + cc] = h;
                    Cl[(size_t)rr * ldc + cc] = bf16rn(o - bf16tof(h));
                }
            }
        }
    }
}

// ---------------- GraphNorm (F = 256) on hi/lo storage ----------------
__global__ __launch_bounds__(256) void colstats_hl(const u16* __restrict__ Hh,
                                                   const u16* __restrict__ Hl,
                                                   float* __restrict__ sums,
                                                   float* __restrict__ sqs, int N) {
    int f = threadIdx.x;
    float s = 0.f, q = 0.f;
    for (int i = blockIdx.x; i < N; i += gridDim.x) {
        float v = bf16tof(Hh[(size_t)i * 256 + f]) + bf16tof(Hl[(size_t)i * 256 + f]);
        s += v;
        q = fmaf(v, v, q);
    }
    atomicAdd(&sums[f], s);
    atomicAdd(&sqs[f], q);
}

__global__ void norm_prep(const float* __restrict__ sums, const float* __restrict__ sqs,
                          const float* __restrict__ gw, const float* __restrict__ gb,
                          const float* __restrict__ gms, float* __restrict__ scaleF,
                          float* __restrict__ shiftF, float invN) {
    int f = threadIdx.x;  // 256 threads
    float mu  = sums[f] * invN;
    float ex2 = sqs[f] * invN;
    float a   = gms[f] * mu;
    float var = ex2 - 2.f * a * mu + a * a;
    float inv = rsqrtf(var + 1e-5f);
    float sc  = gw[f] * inv;
    scaleF[f] = sc;
    shiftF[f] = gb[f] - a * sc;
}

__global__ __launch_bounds__(256) void norm_apply_hl(
    ushort4* __restrict__ Hh, ushort4* __restrict__ Hl,
    const float4* __restrict__ scaleF, const float4* __restrict__ shiftF, int n4) {
    int i = blockIdx.x * 256 + threadIdx.x;
    if (i >= n4) return;
    int f4 = i & 63;
    ushort4 h = Hh[i], lo = Hl[i];
    float4 sc = scaleF[f4], sh = shiftF[f4];
    float vx = fmaxf(fmaf(bf16tof(h.x) + bf16tof(lo.x), sc.x, sh.x), 0.f);
    float vy = fmaxf(fmaf(bf16tof(h.y) + bf16tof(lo.y), sc.y, sh.y), 0.f);
    float vz = fmaxf(fmaf(bf16tof(h.z) + bf16tof(lo.z), sc.z, sh.z), 0.f);
    float vw = fmaxf(fmaf(bf16tof(h.w) + bf16tof(lo.w), sc.w, sh.w), 0.f);
    ushort4 oh, ol;
    oh.x = bf16rn(vx); ol.x = bf16rn(vx - bf16tof(oh.x));
    oh.y = bf16rn(vy); ol.y = bf16rn(vy - bf16tof(oh.y));
    oh.z = bf16rn(vz); ol.z = bf16rn(vz - bf16tof(oh.z));
    oh.w = bf16rn(vw); ol.w = bf16rn(vw - bf16tof(oh.w));
    Hh[i] = oh;
    Hl[i] = ol;
}

// ---------------- launch ----------------
extern "C" void kernel_launch(void* const* d_in, const int* in_sizes, int n_in,
                              void* d_out, int out_size, void* d_ws, size_t ws_size,
                              hipStream_t stream) {
    const float* x   = (const float*)d_in[0];
    const int*   ei  = (const int*)d_in[1];
    const float* ea  = (const float*)d_in[2];
    const float* Wr1 = (const float*)d_in[3];
    const float* b1  = (const float*)d_in[4];
    const float* Wo1 = (const float*)d_in[5];
    const float* Wr2 = (const float*)d_in[6];
    const float* b2  = (const float*)d_in[7];
    const float* Wo2 = (const float*)d_in[8];
    const float* Wr3 = (const float*)d_in[9];
    const float* b3  = (const float*)d_in[10];
    const float* Wo3 = (const float*)d_in[11];
    const float* Wr4 = (const float*)d_in[12];
    const float* b4  = (const float*)d_in[13];
    const float* Wo4 = (const float*)d_in[14];
    const float* gw  = (const float*)d_in[15];
    const float* gb  = (const float*)d_in[16];
    const float* gms = (const float*)d_in[17];

    const int Nn = in_sizes[0] / F_IN;   // 50000
    const int E  = in_sizes[1] / 2;      // 400000
    const int* src = ei;
    const int* dst = ei + E;

    char* wp = (char*)d_ws;
    auto alloc = [&](size_t bytes) -> void* {
        void* p = (void*)wp;
        wp += (bytes + 255) & ~(size_t)255;
        return p;
    };
    int*   counts   = (int*)alloc((size_t)Nn * 4);
    int*   rowptr   = (int*)alloc((size_t)(Nn + 1) * 4);
    int*   fillhead = (int*)alloc((size_t)Nn * 4);
    int*   col      = (int*)alloc((size_t)E * 4);
    float* wv       = (float*)alloc((size_t)E * 4);
    float* stats    = (float*)alloc(1024 * 4);
    float* sums = stats, *sqs = stats + 256, *scaleF = stats + 512, *shiftF = stats + 768;
    // weights hi/lo
    u16* wr1h = (u16*)alloc(2u * 256 * 144); u16* wr1l = (u16*)alloc(2u * 256 * 144);
    u16* wo1h = (u16*)alloc(2u * 256 * 144); u16* wo1l = (u16*)alloc(2u * 256 * 144);
    u16* wr2h = (u16*)alloc(2u * 512 * 256); u16* wr2l = (u16*)alloc(2u * 512 * 256);
    u16* wo2h = (u16*)alloc(2u * 512 * 256); u16* wo2l = (u16*)alloc(2u * 512 * 256);
    u16* wr3h = (u16*)alloc(2u * 256 * 512); u16* wr3l = (u16*)alloc(2u * 256 * 512);
    u16* wo3h = (u16*)alloc(2u * 256 * 512); u16* wo3l = (u16*)alloc(2u * 256 * 512);
    u16* wr4h = (u16*)alloc(2u * 128 * 256); u16* wr4l = (u16*)alloc(2u * 128 * 256);
    u16* wo4h = (u16*)alloc(2u * 128 * 256); u16* wo4l = (u16*)alloc(2u * 128 * 256);

    // ---- lifetime-packed big region (u16 units), Nn*2336*2 B = 233.6 MB (proven r6) --
    // live:  X[0,288) | AGG[288,800) | H1[800,1312) | H2[1312,2336)   (per node)
    // reuse: Y3 -> [0,1024)    (X+AGG+H1 dead after GEMM2)
    //        H3 -> [1312,1824) (H2 dead after GEMM3)
    //        Y4 -> [0,512)     (Y3 dead after L3 aggregate)
    u16* big = (u16*)alloc((size_t)Nn * 2336 * 2);
    const size_t NS = (size_t)Nn;
    u16* Xh  = big;               u16* Xl  = big + NS * 144;
    u16* AGh = big + NS * 288;    u16* AGl = big + NS * 544;
    u16* H1h = big + NS * 800;    u16* H1l = big + NS * 1056;
    u16* H2h = big + NS * 1312;   u16* H2l = big + NS * 1824;
    u16* Y3h = big;               u16* Y3l = big + NS * 512;
    u16* H3h = big + NS * 1312;   u16* H3l = big + NS * 1568;
    u16* Y4h = big;               u16* Y4l = big + NS * 256;

    const int TB = 256;
    // CSR build
    zero_i32<<<(Nn + TB - 1) / TB, TB, 0, stream>>>(counts, Nn);
    count_edges<<<(E + TB - 1) / TB, TB, 0, stream>>>(dst, counts, E);
    scan_counts<<<1, 1024, 0, stream>>>(counts, rowptr, Nn);
    copy_i32<<<(Nn + TB - 1) / TB, TB, 0, stream>>>(rowptr, fillhead, Nn);
    fill_edges<<<(E + TB - 1) / TB, TB, 0, stream>>>(src, dst, ea, fillhead, col, wv, E);

    // conversions
    int nx = Nn * F_IN;
    conv_hl<<<(nx + 255) / 256, 256, 0, stream>>>(x, Xh, Xl, nx);
    struct WC { const float* s; u16* h; u16* l; int n; } wc[8] = {
        {Wr1, wr1h, wr1l, 256 * 144}, {Wo1, wo1h, wo1l, 256 * 144},
        {Wr2, wr2h, wr2l, 512 * 256}, {Wo2, wo2h, wo2l, 512 * 256},
        {Wr3, wr3h, wr3l, 256 * 512}, {Wo3, wo3h, wo3l, 256 * 512},
        {Wr4, wr4h, wr4l, 128 * 256}, {Wo4, wo4h, wo4l, 128 * 256}};
    for (int i = 0; i < 8; ++i)
        conv_hl<<<(wc[i].n + 255) / 256, 256, 0, stream>>>(wc[i].s, wc[i].h, wc[i].l, wc[i].n);

    int aggGrid = (Nn + 3) / 4;
    int mB = (Nn + GBM - 1) / GBM;  // 391

    // Layer 1 (aggregate-first): agg(x) ; [agg|x] * [Wr1|Wo1]^T + b1, relu -> H1
    aggregate2<0><<<aggGrid, TB, 0, stream>>>(Xh, Xl, 144, 18, rowptr, col, wv,
                                              nullptr, nullptr, AGh, AGl, 144, Nn);
    gemm3<true><<<dim3(mB, 2), 256, 0, stream>>>(AGh, AGl, Xh, Xl,
                                                 wr1h, wr1l, wo1h, wo1l,
                                                 b1, nullptr, H1h, H1l,
                                                 Nn, 144, 256, 256, 1);
    // Layer 2 (aggregate-first): 256 -> 512, relu -> H2
    aggregate2<0><<<aggGrid, TB, 0, stream>>>(H1h, H1l, 256, 32, rowptr, col, wv,
                                              nullptr, nullptr, AGh, AGl, 256, Nn);
    gemm3<true><<<dim3(mB, 4), 256, 0, stream>>>(AGh, AGl, H1h, H1l,
                                                 wr2h, wr2l, wo2h, wo2l,
                                                 b2, nullptr, H2h, H2l,
                                                 Nn, 256, 512, 512, 1);
    // Layer 3 (transform-first): Y3 = [H2*Wr3^T | H2*Wo3^T + b3]; H3 = agg(Yrel)+Yroot
    gemm3<false><<<dim3(mB, 4), 256, 0, stream>>>(H2h, H2l, H2h, H2l,
                                                  wr3h, wr3l, wo3h, wo3l,
                                                  nullptr, b3, Y3h, Y3l,
                                                  Nn, 512, 256, 512, 0);
    aggregate2<1><<<aggGrid, TB, 0, stream>>>(Y3h, Y3l, 512, 32, rowptr, col, wv,
                                              Y3h + 256, Y3l + 256, H3h, H3l, 256, Nn);
    // GraphNorm + relu in place on H3
    zero_f32<<<2, TB, 0, stream>>>(stats, 512);
    colstats_hl<<<256, TB, 0, stream>>>(H3h, H3l, sums, sqs, Nn);
    norm_prep<<<1, 256, 0, stream>>>(sums, sqs, gw, gb, gms, scaleF, shiftF, 1.0f / Nn);
    norm_apply_hl<<<(Nn * 64 + TB - 1) / TB, TB, 0, stream>>>(
        (ushort4*)H3h, (ushort4*)H3l, (const float4*)scaleF, (const float4*)shiftF, Nn * 64);
    // Layer 4 (transform-first): Y4 = [H3*Wr4^T | H3*Wo4^T + b4]; out = agg(Yrel)+Yroot
    gemm3<false><<<dim3(mB, 2), 256, 0, stream>>>(H3h, H3l, H3h, H3l,
                                                  wr4h, wr4l, wo4h, wo4l,
                                                  nullptr, b4, Y4h, Y4l,
                                                  Nn, 256, 128, 256, 0);
    aggregate_out2<<<(Nn / 2 + 3) / 4, TB, 0, stream>>>(Y4h, Y4l, 256, rowptr, col, wv,
                                                        Y4h + 128, Y4l + 128,
                                                        (float*)d_out, Nn);
}

// Round 8
// 664.191 us; speedup vs baseline: 2.5218x; 1.3459x over previous
//
#include <hip/hip_runtime.h>

#define F_IN 144
typedef __attribute__((ext_vector_type(8))) short short8v;
typedef __attribute__((ext_vector_type(8))) unsigned short ushort8v;
typedef __attribute__((ext_vector_type(4))) float f32x4;
typedef unsigned short u16;

// ---------------- bf16 helpers ----------------
__device__ __forceinline__ u16 bf16rn(float x) {
    union { float f; unsigned u; } a; a.f = x;
    return (u16)((a.u + 0x7FFFu + ((a.u >> 16) & 1u)) >> 16);
}
__device__ __forceinline__ float bf16tof(u16 h) {
    union { float f; unsigned u; } a; a.u = ((unsigned)h) << 16;
    return a.f;
}
__device__ __forceinline__ void gload_lds16(const u16* g, u16* s) {
    __builtin_amdgcn_global_load_lds(
        (const __attribute__((address_space(1))) void*)g,
        (__attribute__((address_space(3))) void*)s, 16, 0, 0);
}

// ---------------- utility ----------------
__global__ void zero_i32(int* __restrict__ p, int n) {
    int i = blockIdx.x * blockDim.x + threadIdx.x;
    if (i < n) p[i] = 0;
}
__global__ void zero_f32(float* __restrict__ p, int n) {
    int i = blockIdx.x * blockDim.x + threadIdx.x;
    if (i < n) p[i] = 0.f;
}
__global__ void copy_i32(const int* __restrict__ a, int* __restrict__ b, int n) {
    int i = blockIdx.x * blockDim.x + threadIdx.x;
    if (i < n) b[i] = a[i];
}
// weights: f32 -> bf16 hi/lo (fp24)
__global__ void conv_hl(const float* __restrict__ src, u16* __restrict__ dh,
                        u16* __restrict__ dl, int n) {
    int i = blockIdx.x * 256 + threadIdx.x;
    if (i < n) {
        float v = src[i];
        u16 h = bf16rn(v);
        dh[i] = h;
        dl[i] = bf16rn(v - bf16tof(h));
    }
}
// activations: f32 -> bf16
__global__ void conv_bf(const float* __restrict__ src, u16* __restrict__ d, int n) {
    int i = blockIdx.x * 256 + threadIdx.x;
    if (i < n) d[i] = bf16rn(src[i]);
}

// ---------------- CSR build ----------------
__global__ void count_edges(const int* __restrict__ dst, int* __restrict__ counts, int E) {
    int e = blockIdx.x * blockDim.x + threadIdx.x;
    if (e < E) atomicAdd(&counts[dst[e]], 1);
}

__global__ __launch_bounds__(1024) void scan_counts(const int* __restrict__ counts,
                                                    int* __restrict__ rowptr, int N) {
    __shared__ int part[1024];
    int t = threadIdx.x;
    int chunk = (N + 1023) >> 10;
    int beg = t * chunk;
    int end = min(beg + chunk, N);
    int s = 0;
    for (int i = beg; i < end; ++i) s += counts[i];
    part[t] = s;
    __syncthreads();
    for (int off = 1; off < 1024; off <<= 1) {
        int v = (t >= off) ? part[t - off] : 0;
        __syncthreads();
        part[t] += v;
        __syncthreads();
    }
    int run = (t == 0) ? 0 : part[t - 1];
    for (int i = beg; i < end; ++i) { rowptr[i] = run; run += counts[i]; }
    if (end == N) rowptr[N] = run;
}

__global__ void fill_edges(const int* __restrict__ src, const int* __restrict__ dst,
                           const float* __restrict__ ea, int* __restrict__ fillhead,
                           int* __restrict__ col, float* __restrict__ wv, int E) {
    int e = blockIdx.x * blockDim.x + threadIdx.x;
    if (e < E) {
        int d = dst[e];
        int pos = atomicAdd(&fillhead[d], 1);
        col[pos] = src[e];
        wv[pos]  = ea[e];
    }
}

// ------------- single-plane aggregation, NPW nodes per wave -------------
// MODE 0: D = agg(S). MODE 1: D = agg(S) + R (root). bf16 in/out, f32 accum.
template<int NC, int NPW, int MODE>
__global__ __launch_bounds__(256) void aggregate_sp(
    const u16* __restrict__ S, int SS,
    const int* __restrict__ rowptr, const int* __restrict__ col,
    const float* __restrict__ wv,
    const u16* __restrict__ R,
    u16* __restrict__ D, int FD, int N)
{
    int wav  = (int)((blockIdx.x * 256 + threadIdx.x) >> 6);
    int lane = threadIdx.x & 63;
    int sub  = lane / NC;
    int cl   = lane % NC;
    int wid  = wav * NPW + sub;
    if (sub >= NPW || wid >= N) return;
    float acc[8] = {};
    int beg = rowptr[wid], end = rowptr[wid + 1];
    for (int e = beg; e < end; ++e) {
        float wgt = wv[e];
        ushort8v v = *(const ushort8v*)&S[(size_t)col[e] * SS + (cl << 3)];
#pragma unroll
        for (int r = 0; r < 8; ++r) acc[r] = fmaf(wgt, bf16tof(v[r]), acc[r]);
    }
    if (MODE >= 1) {
        ushort8v v = *(const ushort8v*)&R[(size_t)wid * SS + (cl << 3)];
#pragma unroll
        for (int r = 0; r < 8; ++r) acc[r] += bf16tof(v[r]);
    }
    ushort8v o;
#pragma unroll
    for (int r = 0; r < 8; ++r) o[r] = bf16rn(acc[r]);
    *(ushort8v*)&D[(size_t)wid * FD + (cl << 3)] = o;
}

// ---- final aggregate: Y4 fp24 (hi/lo), 2 nodes per wave, f32 out = agg + root ----
__global__ __launch_bounds__(256) void aggregate_out2(
    const u16* __restrict__ Sh, const u16* __restrict__ Sl, int SS,
    const int* __restrict__ rowptr, const int* __restrict__ col,
    const float* __restrict__ wv,
    const u16* __restrict__ Rh, const u16* __restrict__ Rl,
    float* __restrict__ Df, int N)
{
    int wav = (int)((blockIdx.x * 256 + threadIdx.x) >> 6);
    int lane = threadIdx.x & 63;
    int wid  = wav * 2 + (lane >> 5);
    if (wid >= N) return;
    int half = (lane >> 4) & 1;          // 0: hi plane, 1: lo plane
    int cl   = lane & 15;
    float acc[8] = {};
    int beg = rowptr[wid], end = rowptr[wid + 1];
    const u16* S = half ? Sl : Sh;
    for (int e = beg; e < end; ++e) {
        float wgt = wv[e];
        ushort8v v = *(const ushort8v*)&S[(size_t)col[e] * SS + (cl << 3)];
#pragma unroll
        for (int r = 0; r < 8; ++r) acc[r] = fmaf(wgt, bf16tof(v[r]), acc[r]);
    }
    const u16* R = half ? Rl : Rh;
    ushort8v v = *(const ushort8v*)&R[(size_t)wid * SS + (cl << 3)];
#pragma unroll
    for (int r = 0; r < 8; ++r) acc[r] += bf16tof(v[r]);
#pragma unroll
    for (int r = 0; r < 8; ++r) acc[r] += __shfl_xor(acc[r], 16);
    float4 o = half ? make_float4(acc[4], acc[5], acc[6], acc[7])
                    : make_float4(acc[0], acc[1], acc[2], acc[3]);
    *(float4*)&Df[(size_t)wid * 128 + (cl << 3) + half * 4] = o;
}

// ------- MFMA GEMM: A bf16 (1 plane), B fp24 (hi/lo), 2-term product -------
// C = A*(Bh+Bl)^T (+bias). DUALK=true: A=[A1|A2], B=[B1|B2] along K (KK=2*K1).
// DUALK=false: A=A1 (KK=K1); B rows r<NR1 -> B1[r] else B2[r-NR1] (NR1 % 128 == 0).
// 128x128 tile, 4 waves, 24KB LDS (A|Bh|Bl), 2-barrier K-loop, XOR chunk swizzle
// on global source + ds_read (both sides). Staging: 6x16B chunks/thread, hoisted.
// Output: Ch bf16; Cl optional residual plane (fp24).
#define GBM 128
#define GBN 128

template<bool DUALK>
__global__ __launch_bounds__(256) void gemm4(
    const u16* __restrict__ A1, const u16* __restrict__ A2,
    const u16* __restrict__ B1h, const u16* __restrict__ B1l,
    const u16* __restrict__ B2h, const u16* __restrict__ B2l,
    const float* __restrict__ biasA, const float* __restrict__ biasB,
    u16* __restrict__ Ch, u16* __restrict__ Cl,
    int M, int K1, int NR1, int ldc, int doRelu)
{
    __shared__ u16 lds[12288];   // A[0,4096) Bh[4096,8192) Bl[8192,12288)

    const int tid = threadIdx.x;
    const int l = tid & 63, w = tid >> 6;
    const int wm = w >> 1, wn = w & 1;
    const int lane15 = l & 15, slot = l >> 4;
    const int row0 = blockIdx.x * GBM;
    const int col0 = blockIdx.y * GBN;
    const int KK = DUALK ? 2 * K1 : K1;

    // ---- staging precompute: 1536 chunks (3 planes x 512), 6 per thread ----
    const u16* q1[6]; const u16* q2[6]; int lim[6]; u16* dstb[6];
#pragma unroll
    for (int i = 0; i < 6; ++i) {
        int idx0  = i * 256 + (tid & ~63);      // wave-uniform
        int p     = idx0 >> 9;                  // plane 0:A 1:Bh 2:Bl
        int cbase = idx0 & 511;
        int c  = cbase + l;                     // per-lane chunk
        int rw = c >> 2, ch = c & 3;
        int cpk = (ch ^ ((rw >> 1) & 3)) << 3;  // swizzled source k-offset (u16)
        lim[i]  = K1 - cpk;
        dstb[i] = lds + (p << 12) + (cbase << 3);
        const u16 *b1, *b2; int g;
        if (p == 0) {
            b1 = A1; b2 = A2 - K1;
            g = min(row0 + rw, M - 1);
        } else {
            const u16* h1 = (p == 1) ? B1h : B1l;
            const u16* h2 = (p == 1) ? B2h : B2l;
            if (DUALK) { b1 = h1; b2 = h2 - K1; g = col0 + rw; }
            else {
                bool sec = (col0 >= NR1);
                b1 = sec ? h2 : h1; b2 = b1;
                g = col0 + rw - (sec ? NR1 : 0);
            }
        }
        q1[i] = b1 + g * K1 + cpk;
        q2[i] = b2 + g * K1 + cpk;
    }

    f32x4 acc[4][4] = {};

    for (int kk0 = 0; kk0 < KK; kk0 += 32) {
        __syncthreads();  // prior compute done before LDS overwrite
#pragma unroll
        for (int i = 0; i < 6; ++i) {
            const u16* src = (DUALK && kk0 >= lim[i]) ? q2[i] : q1[i];
            gload_lds16(src + kk0, dstb[i]);
        }
        __syncthreads();  // compiler drains vmcnt before barrier

        short8v av[4];
#pragma unroll
        for (int bi = 0; bi < 4; ++bi) {
            int r = wm * 64 + bi * 16 + lane15;
            int j = slot ^ ((r >> 1) & 3);
            av[bi] = *(const short8v*)&lds[r * 32 + j * 8];
        }
#pragma unroll
        for (int bj = 0; bj < 4; ++bj) {
            int c = wn * 64 + bj * 16 + lane15;
            int j = slot ^ ((c >> 1) & 3);
            short8v bh = *(const short8v*)&lds[4096 + c * 32 + j * 8];
            short8v bl = *(const short8v*)&lds[8192 + c * 32 + j * 8];
#pragma unroll
            for (int bi = 0; bi < 4; ++bi) {
                acc[bi][bj] = __builtin_amdgcn_mfma_f32_16x16x32_bf16(av[bi], bh, acc[bi][bj], 0, 0, 0);
                acc[bi][bj] = __builtin_amdgcn_mfma_f32_16x16x32_bf16(av[bi], bl, acc[bi][bj], 0, 0, 0);
            }
        }
    }

    // ---- epilogue: C/D layout col=lane&15, row=slot*4+q ----
#pragma unroll
    for (int bj = 0; bj < 4; ++bj) {
        int cc = col0 + wn * 64 + bj * 16 + lane15;
        float bv = (cc < NR1) ? (biasA ? biasA[cc] : 0.f)
                              : (biasB ? biasB[cc - NR1] : 0.f);
#pragma unroll
        for (int bi = 0; bi < 4; ++bi) {
            int rbase = row0 + wm * 64 + bi * 16 + slot * 4;
#pragma unroll
            for (int q = 0; q < 4; ++q) {
                int rr = rbase + q;
                if (rr < M) {
                    float o = acc[bi][bj][q] + bv;
                    if (doRelu) o = fmaxf(o, 0.f);
                    u16 h = bf16rn(o);
                    Ch[(size_t)rr * ldc + cc] = h;
                    if (Cl) Cl[(size_t)rr * ldc + cc] = bf16rn(o - bf16tof(h));
                }
            }
        }
    }
}

// ---------------- GraphNorm (F = 256) single-plane ----------------
__global__ __launch_bounds__(256) void colstats_sp(const u16* __restrict__ H,
                                                   float* __restrict__ sums,
                                                   float* __restrict__ sqs, int N) {
    int f = threadIdx.x;
    float s = 0.f, q = 0.f;
    for (int i = blockIdx.x; i < N; i += gridDim.x) {
        float v = bf16tof(H[(size_t)i * 256 + f]);
        s += v;
        q = fmaf(v, v, q);
    }
    atomicAdd(&sums[f], s);
    atomicAdd(&sqs[f], q);
}

__global__ void norm_prep(const float* __restrict__ sums, const float* __restrict__ sqs,
                          const float* __restrict__ gw, const float* __restrict__ gb,
                          const float* __restrict__ gms, float* __restrict__ scaleF,
                          float* __restrict__ shiftF, float invN) {
    int f = threadIdx.x;  // 256 threads
    float mu  = sums[f] * invN;
    float ex2 = sqs[f] * invN;
    float a   = gms[f] * mu;
    float var = ex2 - 2.f * a * mu + a * a;
    float inv = rsqrtf(var + 1e-5f);
    float sc  = gw[f] * inv;
    scaleF[f] = sc;
    shiftF[f] = gb[f] - a * sc;
}

__global__ __launch_bounds__(256) void norm_apply_sp(
    u16* __restrict__ H, const float* __restrict__ scaleF,
    const float* __restrict__ shiftF, int n8) {
    int i = blockIdx.x * 256 + threadIdx.x;
    if (i >= n8) return;
    int f0 = (i & 31) << 3;   // 256 feats = 32 chunks of 8
    ushort8v h = *(const ushort8v*)&H[(size_t)i * 8];
    ushort8v o;
#pragma unroll
    for (int r = 0; r < 8; ++r) {
        float v = fmaxf(fmaf(bf16tof(h[r]), scaleF[f0 + r], shiftF[f0 + r]), 0.f);
        o[r] = bf16rn(v);
    }
    *(ushort8v*)&H[(size_t)i * 8] = o;
}

// ---------------- launch ----------------
extern "C" void kernel_launch(void* const* d_in, const int* in_sizes, int n_in,
                              void* d_out, int out_size, void* d_ws, size_t ws_size,
                              hipStream_t stream) {
    const float* x   = (const float*)d_in[0];
    const int*   ei  = (const int*)d_in[1];
    const float* ea  = (const float*)d_in[2];
    const float* Wr1 = (const float*)d_in[3];
    const float* b1  = (const float*)d_in[4];
    const float* Wo1 = (const float*)d_in[5];
    const float* Wr2 = (const float*)d_in[6];
    const float* b2  = (const float*)d_in[7];
    const float* Wo2 = (const float*)d_in[8];
    const float* Wr3 = (const float*)d_in[9];
    const float* b3  = (const float*)d_in[10];
    const float* Wo3 = (const float*)d_in[11];
    const float* Wr4 = (const float*)d_in[12];
    const float* b4  = (const float*)d_in[13];
    const float* Wo4 = (const float*)d_in[14];
    const float* gw  = (const float*)d_in[15];
    const float* gb  = (const float*)d_in[16];
    const float* gms = (const float*)d_in[17];

    const int Nn = in_sizes[0] / F_IN;   // 50000
    const int E  = in_sizes[1] / 2;      // 400000
    const int* src = ei;
    const int* dst = ei + E;

    char* wp = (char*)d_ws;
    auto alloc = [&](size_t bytes) -> void* {
        void* p = (void*)wp;
        wp += (bytes + 255) & ~(size_t)255;
        return p;
    };
    int*   counts   = (int*)alloc((size_t)Nn * 4);
    int*   rowptr   = (int*)alloc((size_t)(Nn + 1) * 4);
    int*   fillhead = (int*)alloc((size_t)Nn * 4);
    int*   col      = (int*)alloc((size_t)E * 4);
    float* wv       = (float*)alloc((size_t)E * 4);
    float* stats    = (float*)alloc(1024 * 4);
    float* sums = stats, *sqs = stats + 256, *scaleF = stats + 512, *shiftF = stats + 768;
    // weights hi/lo (fp24)
    u16* wr1h = (u16*)alloc(2u * 256 * 144); u16* wr1l = (u16*)alloc(2u * 256 * 144);
    u16* wo1h = (u16*)alloc(2u * 256 * 144); u16* wo1l = (u16*)alloc(2u * 256 * 144);
    u16* wr2h = (u16*)alloc(2u * 512 * 256); u16* wr2l = (u16*)alloc(2u * 512 * 256);
    u16* wo2h = (u16*)alloc(2u * 512 * 256); u16* wo2l = (u16*)alloc(2u * 512 * 256);
    u16* wr3h = (u16*)alloc(2u * 256 * 512); u16* wr3l = (u16*)alloc(2u * 256 * 512);
    u16* wo3h = (u16*)alloc(2u * 256 * 512); u16* wo3l = (u16*)alloc(2u * 256 * 512);
    u16* wr4h = (u16*)alloc(2u * 128 * 256); u16* wr4l = (u16*)alloc(2u * 128 * 256);
    u16* wo4h = (u16*)alloc(2u * 128 * 256); u16* wo4l = (u16*)alloc(2u * 128 * 256);

    // ---- lifetime-packed region (u16 units), Nn*1168*2 B = 116.8 MB ----
    // live:  X[0,144) | AG[144,400) | H1[400,656) | H2[656,1168)
    // reuse: Y3  -> [0,512)    (X,AG,H1 dead after GEMM2)
    //        H3  -> [656,912)  (H2 dead after GEMM3)
    //        Y4h -> [0,256), Y4l -> [256,512)  (Y3 dead after L3 aggregate)
    u16* big = (u16*)alloc((size_t)Nn * 1168 * 2);
    const size_t NS = (size_t)Nn;
    u16* Xb  = big;
    u16* AG  = big + NS * 144;
    u16* H1  = big + NS * 400;
    u16* H2  = big + NS * 656;
    u16* Y3  = big;
    u16* H3  = big + NS * 656;
    u16* Y4h = big;
    u16* Y4l = big + NS * 256;

    const int TB = 256;
    // CSR build
    zero_i32<<<(Nn + TB - 1) / TB, TB, 0, stream>>>(counts, Nn);
    count_edges<<<(E + TB - 1) / TB, TB, 0, stream>>>(dst, counts, E);
    scan_counts<<<1, 1024, 0, stream>>>(counts, rowptr, Nn);
    copy_i32<<<(Nn + TB - 1) / TB, TB, 0, stream>>>(rowptr, fillhead, Nn);
    fill_edges<<<(E + TB - 1) / TB, TB, 0, stream>>>(src, dst, ea, fillhead, col, wv, E);

    // conversions
    int nx = Nn * F_IN;
    conv_bf<<<(nx + 255) / 256, 256, 0, stream>>>(x, Xb, nx);
    struct WC { const float* s; u16* h; u16* l; int n; } wc[8] = {
        {Wr1, wr1h, wr1l, 256 * 144}, {Wo1, wo1h, wo1l, 256 * 144},
        {Wr2, wr2h, wr2l, 512 * 256}, {Wo2, wo2h, wo2l, 512 * 256},
        {Wr3, wr3h, wr3l, 256 * 512}, {Wo3, wo3h, wo3l, 256 * 512},
        {Wr4, wr4h, wr4l, 128 * 256}, {Wo4, wo4h, wo4l, 128 * 256}};
    for (int i = 0; i < 8; ++i)
        conv_hl<<<(wc[i].n + 255) / 256, 256, 0, stream>>>(wc[i].s, wc[i].h, wc[i].l, wc[i].n);

    int mB = (Nn + GBM - 1) / GBM;              // 391
    int g3 = (((Nn + 2) / 3) + 3) / 4;          // 3 nodes/wave grids
    int g2 = (((Nn + 1) / 2) + 3) / 4;          // 2 nodes/wave grids

    // Layer 1 (aggregate-first): AG = agg(X); H1 = relu([AG|X]*[Wr1|Wo1]^T + b1)
    aggregate_sp<18, 3, 0><<<g3, TB, 0, stream>>>(Xb, 144, rowptr, col, wv,
                                                  nullptr, AG, 144, Nn);
    gemm4<true><<<dim3(mB, 2), 256, 0, stream>>>(AG, Xb, wr1h, wr1l, wo1h, wo1l,
                                                 b1, nullptr, H1, nullptr,
                                                 Nn, 144, 256, 256, 1);
    // Layer 2 (aggregate-first): AG = agg(H1); H2 = relu([AG|H1]*[Wr2|Wo2]^T + b2)
    aggregate_sp<32, 2, 0><<<g2, TB, 0, stream>>>(H1, 256, rowptr, col, wv,
                                                  nullptr, AG, 256, Nn);
    gemm4<true><<<dim3(mB, 4), 256, 0, stream>>>(AG, H1, wr2h, wr2l, wo2h, wo2l,
                                                 b2, nullptr, H2, nullptr,
                                                 Nn, 256, 512, 512, 1);
    // Layer 3 (transform-first): Y3 = [H2*Wr3^T | H2*Wo3^T + b3]; H3 = agg(Yrel)+Yroot
    gemm4<false><<<dim3(mB, 4), 256, 0, stream>>>(H2, H2, wr3h, wr3l, wo3h, wo3l,
                                                  nullptr, b3, Y3, nullptr,
                                                  Nn, 512, 256, 512, 0);
    aggregate_sp<32, 2, 1><<<g2, TB, 0, stream>>>(Y3, 512, rowptr, col, wv,
                                                  Y3 + 256, H3, 256, Nn);
    // GraphNorm + relu in place on H3
    zero_f32<<<2, TB, 0, stream>>>(stats, 512);
    colstats_sp<<<256, TB, 0, stream>>>(H3, sums, sqs, Nn);
    norm_prep<<<1, 256, 0, stream>>>(sums, sqs, gw, gb, gms, scaleF, shiftF, 1.0f / Nn);
    norm_apply_sp<<<(Nn * 32 + TB - 1) / TB, TB, 0, stream>>>(H3, scaleF, shiftF, Nn * 32);
    // Layer 4 (transform-first): Y4 = [H3*Wr4^T | H3*Wo4^T + b4] (fp24); out = agg+root
    gemm4<false><<<dim3(mB, 2), 256, 0, stream>>>(H3, H3, wr4h, wr4l, wo4h, wo4l,
                                                  nullptr, b4, Y4h, Y4l,
                                                  Nn, 256, 128, 256, 0);
    aggregate_out2<<<g2, TB, 0, stream>>>(Y4h, Y4l, 256, rowptr, col, wv,
                                          Y4h + 128, Y4l + 128,
                                          (float*)d_out, Nn);
}

// Round 9
// 634.685 us; speedup vs baseline: 2.6390x; 1.0465x over previous
//
#include <hip/hip_runtime.h>

#define F_IN 144
typedef __attribute__((ext_vector_type(8))) short short8v;
typedef __attribute__((ext_vector_type(8))) unsigned short ushort8v;
typedef __attribute__((ext_vector_type(4))) float f32x4;
typedef unsigned short u16;

// ---------------- bf16 helpers ----------------
__device__ __forceinline__ u16 bf16rn(float x) {
    union { float f; unsigned u; } a; a.f = x;
    return (u16)((a.u + 0x7FFFu + ((a.u >> 16) & 1u)) >> 16);
}
__device__ __forceinline__ float bf16tof(u16 h) {
    union { float f; unsigned u; } a; a.u = ((unsigned)h) << 16;
    return a.f;
}
__device__ __forceinline__ void gload_lds16(const u16* g, u16* s) {
    __builtin_amdgcn_global_load_lds(
        (const __attribute__((address_space(1))) void*)g,
        (__attribute__((address_space(3))) void*)s, 16, 0, 0);
}

// ---------------- utility ----------------
__global__ void zero_i32(int* __restrict__ p, int n) {
    int i = blockIdx.x * blockDim.x + threadIdx.x;
    if (i < n) p[i] = 0;
}
__global__ void zero_f32(float* __restrict__ p, int n) {
    int i = blockIdx.x * blockDim.x + threadIdx.x;
    if (i < n) p[i] = 0.f;
}
__global__ void copy_i32(const int* __restrict__ a, int* __restrict__ b, int n) {
    int i = blockIdx.x * blockDim.x + threadIdx.x;
    if (i < n) b[i] = a[i];
}
// weights: f32 -> bf16 hi/lo (fp24)
__global__ void conv_hl(const float* __restrict__ src, u16* __restrict__ dh,
                        u16* __restrict__ dl, int n) {
    int i = blockIdx.x * 256 + threadIdx.x;
    if (i < n) {
        float v = src[i];
        u16 h = bf16rn(v);
        dh[i] = h;
        dl[i] = bf16rn(v - bf16tof(h));
    }
}
// activations: f32 -> bf16
__global__ void conv_bf(const float* __restrict__ src, u16* __restrict__ d, int n) {
    int i = blockIdx.x * 256 + threadIdx.x;
    if (i < n) d[i] = bf16rn(src[i]);
}

// ---------------- CSR build ----------------
__global__ void count_edges(const int* __restrict__ dst, int* __restrict__ counts, int E) {
    int e = blockIdx.x * blockDim.x + threadIdx.x;
    if (e < E) atomicAdd(&counts[dst[e]], 1);
}

__global__ __launch_bounds__(1024) void scan_counts(const int* __restrict__ counts,
                                                    int* __restrict__ rowptr, int N) {
    __shared__ int part[1024];
    int t = threadIdx.x;
    int chunk = (N + 1023) >> 10;
    int beg = t * chunk;
    int end = min(beg + chunk, N);
    int s = 0;
    for (int i = beg; i < end; ++i) s += counts[i];
    part[t] = s;
    __syncthreads();
    for (int off = 1; off < 1024; off <<= 1) {
        int v = (t >= off) ? part[t - off] : 0;
        __syncthreads();
        part[t] += v;
        __syncthreads();
    }
    int run = (t == 0) ? 0 : part[t - 1];
    for (int i = beg; i < end; ++i) { rowptr[i] = run; run += counts[i]; }
    if (end == N) rowptr[N] = run;
}

__global__ void fill_edges(const int* __restrict__ src, const int* __restrict__ dst,
                           const float* __restrict__ ea, int* __restrict__ fillhead,
                           int* __restrict__ col, float* __restrict__ wv, int E) {
    int e = blockIdx.x * blockDim.x + threadIdx.x;
    if (e < E) {
        int d = dst[e];
        int pos = atomicAdd(&fillhead[d], 1);
        col[pos] = src[e];
        wv[pos]  = ea[e];
    }
}

// ------------- single-plane aggregation, NPW nodes per wave -------------
// MODE 0: D = agg(S). MODE 1: D = agg(S) + R (root). bf16 in/out, f32 accum.
template<int NC, int NPW, int MODE>
__global__ __launch_bounds__(256) void aggregate_sp(
    const u16* __restrict__ S, int SS,
    const int* __restrict__ rowptr, const int* __restrict__ col,
    const float* __restrict__ wv,
    const u16* __restrict__ R,
    u16* __restrict__ D, int FD, int N)
{
    int wav  = (int)((blockIdx.x * 256 + threadIdx.x) >> 6);
    int lane = threadIdx.x & 63;
    int sub  = lane / NC;
    int cl   = lane % NC;
    int wid  = wav * NPW + sub;
    if (sub >= NPW || wid >= N) return;
    float acc[8] = {};
    int beg = rowptr[wid], end = rowptr[wid + 1];
    for (int e = beg; e < end; ++e) {
        float wgt = wv[e];
        ushort8v v = *(const ushort8v*)&S[(size_t)col[e] * SS + (cl << 3)];
#pragma unroll
        for (int r = 0; r < 8; ++r) acc[r] = fmaf(wgt, bf16tof(v[r]), acc[r]);
    }
    if (MODE >= 1) {
        ushort8v v = *(const ushort8v*)&R[(size_t)wid * SS + (cl << 3)];
#pragma unroll
        for (int r = 0; r < 8; ++r) acc[r] += bf16tof(v[r]);
    }
    ushort8v o;
#pragma unroll
    for (int r = 0; r < 8; ++r) o[r] = bf16rn(acc[r]);
    *(ushort8v*)&D[(size_t)wid * FD + (cl << 3)] = o;
}

// ---- final aggregate: Y4 fp24 (hi/lo), 2 nodes per wave, f32 out = agg + root ----
__global__ __launch_bounds__(256) void aggregate_out2(
    const u16* __restrict__ Sh, const u16* __restrict__ Sl, int SS,
    const int* __restrict__ rowptr, const int* __restrict__ col,
    const float* __restrict__ wv,
    const u16* __restrict__ Rh, const u16* __restrict__ Rl,
    float* __restrict__ Df, int N)
{
    int wav = (int)((blockIdx.x * 256 + threadIdx.x) >> 6);
    int lane = threadIdx.x & 63;
    int wid  = wav * 2 + (lane >> 5);
    if (wid >= N) return;
    int half = (lane >> 4) & 1;          // 0: hi plane, 1: lo plane
    int cl   = lane & 15;
    float acc[8] = {};
    int beg = rowptr[wid], end = rowptr[wid + 1];
    const u16* S = half ? Sl : Sh;
    for (int e = beg; e < end; ++e) {
        float wgt = wv[e];
        ushort8v v = *(const ushort8v*)&S[(size_t)col[e] * SS + (cl << 3)];
#pragma unroll
        for (int r = 0; r < 8; ++r) acc[r] = fmaf(wgt, bf16tof(v[r]), acc[r]);
    }
    const u16* R = half ? Rl : Rh;
    ushort8v v = *(const ushort8v*)&R[(size_t)wid * SS + (cl << 3)];
#pragma unroll
    for (int r = 0; r < 8; ++r) acc[r] += bf16tof(v[r]);
#pragma unroll
    for (int r = 0; r < 8; ++r) acc[r] += __shfl_xor(acc[r], 16);
    float4 o = half ? make_float4(acc[4], acc[5], acc[6], acc[7])
                    : make_float4(acc[0], acc[1], acc[2], acc[3]);
    *(float4*)&Df[(size_t)wid * 128 + (cl << 3) + half * 4] = o;
}

// ------- MFMA GEMM: A bf16, B fp24 (hi/lo), 2-term, double-buffered -------
// C = A*(Bh+Bl)^T (+bias). DUALK=true: A=[A1|A2], B=[B1|B2] along K (KK=2*K1).
// DUALK=false: A=A1 (KK=K1); B rows r<NR1 -> B1[r] else B2[r-NR1] (NR1 % 128 == 0).
// 128x128 tile, 4 waves. LDS = 2 x 24KB buffers (A|Bh|Bl planes, 4096 u16 each).
// Per step: ds_read frags of cur (lgkm only; cur drained at prior barrier) ->
// issue stage of nxt (reads precede writes: no forced vmcnt) -> MFMA ->
// ONE __syncthreads (its implicit vmcnt(0) lands after the compute phase).
// Grid: blockIdx.x = col-block (consecutive blocks share A panel -> L2/L3 reuse),
// blockIdx.y = row-block. XOR chunk swizzle on global source + ds_read (G21).
#define GBM 128
#define GBN 128

template<bool DUALK>
__global__ __launch_bounds__(256) void gemm5(
    const u16* __restrict__ A1, const u16* __restrict__ A2,
    const u16* __restrict__ B1h, const u16* __restrict__ B1l,
    const u16* __restrict__ B2h, const u16* __restrict__ B2l,
    const float* __restrict__ biasA, const float* __restrict__ biasB,
    u16* __restrict__ Ch, u16* __restrict__ Cl,
    int M, int K1, int NR1, int ldc, int doRelu)
{
    __shared__ u16 lds[24576];   // 2 buffers x 12288 u16 (A | Bh | Bl)

    const int tid = threadIdx.x;
    const int l = tid & 63, w = tid >> 6;
    const int wm = w >> 1, wn = w & 1;
    const int lane15 = l & 15, slot = l >> 4;
    const int row0 = blockIdx.y * GBM;
    const int col0 = blockIdx.x * GBN;
    const int KK = DUALK ? 2 * K1 : K1;
    const int nsteps = KK / 32;

    // ---- staging precompute: 1536 chunks (3 planes x 512), 6 per thread ----
    const u16* q1[6]; const u16* q2[6]; int lim[6]; int dstoff[6];
#pragma unroll
    for (int i = 0; i < 6; ++i) {
        int idx0  = i * 256 + (tid & ~63);      // wave-uniform
        int p     = idx0 >> 9;                  // plane 0:A 1:Bh 2:Bl
        int cbase = idx0 & 511;
        int c  = cbase + l;                     // per-lane chunk
        int rw = c >> 2, ch = c & 3;
        int cpk = (ch ^ ((rw >> 1) & 3)) << 3;  // swizzled source k-offset (u16)
        lim[i]    = K1 - cpk;
        dstoff[i] = (p << 12) + (cbase << 3);
        const u16 *b1, *b2; int g;
        if (p == 0) {
            b1 = A1; b2 = A2 - K1;
            g = min(row0 + rw, M - 1);
        } else {
            const u16* h1 = (p == 1) ? B1h : B1l;
            const u16* h2 = (p == 1) ? B2h : B2l;
            if (DUALK) { b1 = h1; b2 = h2 - K1; g = col0 + rw; }
            else {
                bool sec = (col0 >= NR1);
                b1 = sec ? h2 : h1; b2 = b1;
                g = col0 + rw - (sec ? NR1 : 0);
            }
        }
        q1[i] = b1 + g * K1 + cpk;
        q2[i] = b2 + g * K1 + cpk;
    }

    f32x4 acc[4][4] = {};

    // prologue: stage tile 0 into buffer 0 (kk0 = 0 always < lim)
#pragma unroll
    for (int i = 0; i < 6; ++i) gload_lds16(q1[i], lds + dstoff[i]);
    __syncthreads();

    int cur = 0;
    for (int step = 0; step < nsteps; ++step) {
        const u16* cb = lds + cur * 12288;
        // ---- 1. ds_read all fragments of cur into registers ----
        short8v av[4], bh[4], bl[4];
#pragma unroll
        for (int bi = 0; bi < 4; ++bi) {
            int r = wm * 64 + bi * 16 + lane15;
            int j = slot ^ ((r >> 1) & 3);
            av[bi] = *(const short8v*)&cb[r * 32 + j * 8];
        }
#pragma unroll
        for (int bj = 0; bj < 4; ++bj) {
            int c = wn * 64 + bj * 16 + lane15;
            int j = slot ^ ((c >> 1) & 3);
            bh[bj] = *(const short8v*)&cb[4096 + c * 32 + j * 8];
            bl[bj] = *(const short8v*)&cb[8192 + c * 32 + j * 8];
        }
        // ---- 2. issue next tile's stage into nxt (flies under the MFMAs) ----
        if (step + 1 < nsteps) {
            int kk0 = (step + 1) * 32;
            u16* nb = lds + (cur ^ 1) * 12288;
#pragma unroll
            for (int i = 0; i < 6; ++i) {
                const u16* src = (DUALK && kk0 >= lim[i]) ? q2[i] : q1[i];
                gload_lds16(src + kk0, nb + dstoff[i]);
            }
        }
        // ---- 3. MFMA (register-only; waits lgkmcnt for the ds_reads) ----
#pragma unroll
        for (int bj = 0; bj < 4; ++bj)
#pragma unroll
            for (int bi = 0; bi < 4; ++bi) {
                acc[bi][bj] = __builtin_amdgcn_mfma_f32_16x16x32_bf16(av[bi], bh[bj], acc[bi][bj], 0, 0, 0);
                acc[bi][bj] = __builtin_amdgcn_mfma_f32_16x16x32_bf16(av[bi], bl[bj], acc[bi][bj], 0, 0, 0);
            }
        // ---- 4. one barrier: drains this step's stage loads after compute ----
        __syncthreads();
        cur ^= 1;
    }

    // ---- epilogue: C/D layout col=lane&15, row=slot*4+q ----
#pragma unroll
    for (int bj = 0; bj < 4; ++bj) {
        int cc = col0 + wn * 64 + bj * 16 + lane15;
        float bv = (cc < NR1) ? (biasA ? biasA[cc] : 0.f)
                              : (biasB ? biasB[cc - NR1] : 0.f);
#pragma unroll
        for (int bi = 0; bi < 4; ++bi) {
            int rbase = row0 + wm * 64 + bi * 16 + slot * 4;
#pragma unroll
            for (int q = 0; q < 4; ++q) {
                int rr = rbase + q;
                if (rr < M) {
                    float o = acc[bi][bj][q] + bv;
                    if (doRelu) o = fmaxf(o, 0.f);
                    u16 h = bf16rn(o);
                    Ch[(size_t)rr * ldc + cc] = h;
                    if (Cl) Cl[(size_t)rr * ldc + cc] = bf16rn(o - bf16tof(h));
                }
            }
        }
    }
}

// ---------------- GraphNorm (F = 256) single-plane ----------------
__global__ __launch_bounds__(256) void colstats_sp(const u16* __restrict__ H,
                                                   float* __restrict__ sums,
                                                   float* __restrict__ sqs, int N) {
    int f = threadIdx.x;
    float s = 0.f, q = 0.f;
    for (int i = blockIdx.x; i < N; i += gridDim.x) {
        float v = bf16tof(H[(size_t)i * 256 + f]);
        s += v;
        q = fmaf(v, v, q);
    }
    atomicAdd(&sums[f], s);
    atomicAdd(&sqs[f], q);
}

__global__ void norm_prep(const float* __restrict__ sums, const float* __restrict__ sqs,
                          const float* __restrict__ gw, const float* __restrict__ gb,
                          const float* __restrict__ gms, float* __restrict__ scaleF,
                          float* __restrict__ shiftF, float invN) {
    int f = threadIdx.x;  // 256 threads
    float mu  = sums[f] * invN;
    float ex2 = sqs[f] * invN;
    float a   = gms[f] * mu;
    float var = ex2 - 2.f * a * mu + a * a;
    float inv = rsqrtf(var + 1e-5f);
    float sc  = gw[f] * inv;
    scaleF[f] = sc;
    shiftF[f] = gb[f] - a * sc;
}

__global__ __launch_bounds__(256) void norm_apply_sp(
    u16* __restrict__ H, const float* __restrict__ scaleF,
    const float* __restrict__ shiftF, int n8) {
    int i = blockIdx.x * 256 + threadIdx.x;
    if (i >= n8) return;
    int f0 = (i & 31) << 3;   // 256 feats = 32 chunks of 8
    ushort8v h = *(const ushort8v*)&H[(size_t)i * 8];
    ushort8v o;
#pragma unroll
    for (int r = 0; r < 8; ++r) {
        float v = fmaxf(fmaf(bf16tof(h[r]), scaleF[f0 + r], shiftF[f0 + r]), 0.f);
        o[r] = bf16rn(v);
    }
    *(ushort8v*)&H[(size_t)i * 8] = o;
}

// ---------------- launch ----------------
extern "C" void kernel_launch(void* const* d_in, const int* in_sizes, int n_in,
                              void* d_out, int out_size, void* d_ws, size_t ws_size,
                              hipStream_t stream) {
    const float* x   = (const float*)d_in[0];
    const int*   ei  = (const int*)d_in[1];
    const float* ea  = (const float*)d_in[2];
    const float* Wr1 = (const float*)d_in[3];
    const float* b1  = (const float*)d_in[4];
    const float* Wo1 = (const float*)d_in[5];
    const float* Wr2 = (const float*)d_in[6];
    const float* b2  = (const float*)d_in[7];
    const float* Wo2 = (const float*)d_in[8];
    const float* Wr3 = (const float*)d_in[9];
    const float* b3  = (const float*)d_in[10];
    const float* Wo3 = (const float*)d_in[11];
    const float* Wr4 = (const float*)d_in[12];
    const float* b4  = (const float*)d_in[13];
    const float* Wo4 = (const float*)d_in[14];
    const float* gw  = (const float*)d_in[15];
    const float* gb  = (const float*)d_in[16];
    const float* gms = (const float*)d_in[17];

    const int Nn = in_sizes[0] / F_IN;   // 50000
    const int E  = in_sizes[1] / 2;      // 400000
    const int* src = ei;
    const int* dst = ei + E;

    char* wp = (char*)d_ws;
    auto alloc = [&](size_t bytes) -> void* {
        void* p = (void*)wp;
        wp += (bytes + 255) & ~(size_t)255;
        return p;
    };
    int*   counts   = (int*)alloc((size_t)Nn * 4);
    int*   rowptr   = (int*)alloc((size_t)(Nn + 1) * 4);
    int*   fillhead = (int*)alloc((size_t)Nn * 4);
    int*   col      = (int*)alloc((size_t)E * 4);
    float* wv       = (float*)alloc((size_t)E * 4);
    float* stats    = (float*)alloc(1024 * 4);
    float* sums = stats, *sqs = stats + 256, *scaleF = stats + 512, *shiftF = stats + 768;
    // weights hi/lo (fp24)
    u16* wr1h = (u16*)alloc(2u * 256 * 144); u16* wr1l = (u16*)alloc(2u * 256 * 144);
    u16* wo1h = (u16*)alloc(2u * 256 * 144); u16* wo1l = (u16*)alloc(2u * 256 * 144);
    u16* wr2h = (u16*)alloc(2u * 512 * 256); u16* wr2l = (u16*)alloc(2u * 512 * 256);
    u16* wo2h = (u16*)alloc(2u * 512 * 256); u16* wo2l = (u16*)alloc(2u * 512 * 256);
    u16* wr3h = (u16*)alloc(2u * 256 * 512); u16* wr3l = (u16*)alloc(2u * 256 * 512);
    u16* wo3h = (u16*)alloc(2u * 256 * 512); u16* wo3l = (u16*)alloc(2u * 256 * 512);
    u16* wr4h = (u16*)alloc(2u * 128 * 256); u16* wr4l = (u16*)alloc(2u * 128 * 256);
    u16* wo4h = (u16*)alloc(2u * 128 * 256); u16* wo4l = (u16*)alloc(2u * 128 * 256);

    // ---- lifetime-packed region (u16 units), Nn*1168*2 B = 116.8 MB ----
    // live:  X[0,144) | AG[144,400) | H1[400,656) | H2[656,1168)
    // reuse: Y3  -> [0,512)    (X,AG,H1 dead after GEMM2)
    //        H3  -> [656,912)  (H2 dead after GEMM3)
    //        Y4h -> [0,256), Y4l -> [256,512)  (Y3 dead after L3 aggregate)
    u16* big = (u16*)alloc((size_t)Nn * 1168 * 2);
    const size_t NS = (size_t)Nn;
    u16* Xb  = big;
    u16* AG  = big + NS * 144;
    u16* H1  = big + NS * 400;
    u16* H2  = big + NS * 656;
    u16* Y3  = big;
    u16* H3  = big + NS * 656;
    u16* Y4h = big;
    u16* Y4l = big + NS * 256;

    const int TB = 256;
    // CSR build
    zero_i32<<<(Nn + TB - 1) / TB, TB, 0, stream>>>(counts, Nn);
    count_edges<<<(E + TB - 1) / TB, TB, 0, stream>>>(dst, counts, E);
    scan_counts<<<1, 1024, 0, stream>>>(counts, rowptr, Nn);
    copy_i32<<<(Nn + TB - 1) / TB, TB, 0, stream>>>(rowptr, fillhead, Nn);
    fill_edges<<<(E + TB - 1) / TB, TB, 0, stream>>>(src, dst, ea, fillhead, col, wv, E);

    // conversions
    int nx = Nn * F_IN;
    conv_bf<<<(nx + 255) / 256, 256, 0, stream>>>(x, Xb, nx);
    struct WC { const float* s; u16* h; u16* l; int n; } wc[8] = {
        {Wr1, wr1h, wr1l, 256 * 144}, {Wo1, wo1h, wo1l, 256 * 144},
        {Wr2, wr2h, wr2l, 512 * 256}, {Wo2, wo2h, wo2l, 512 * 256},
        {Wr3, wr3h, wr3l, 256 * 512}, {Wo3, wo3h, wo3l, 256 * 512},
        {Wr4, wr4h, wr4l, 128 * 256}, {Wo4, wo4h, wo4l, 128 * 256}};
    for (int i = 0; i < 8; ++i)
        conv_hl<<<(wc[i].n + 255) / 256, 256, 0, stream>>>(wc[i].s, wc[i].h, wc[i].l, wc[i].n);

    int mB = (Nn + GBM - 1) / GBM;              // 391
    int g3 = (((Nn + 2) / 3) + 3) / 4;          // 3 nodes/wave grids
    int g2 = (((Nn + 1) / 2) + 3) / 4;          // 2 nodes/wave grids

    // Layer 1 (aggregate-first): AG = agg(X); H1 = relu([AG|X]*[Wr1|Wo1]^T + b1)
    aggregate_sp<18, 3, 0><<<g3, TB, 0, stream>>>(Xb, 144, rowptr, col, wv,
                                                  nullptr, AG, 144, Nn);
    gemm5<true><<<dim3(2, mB), 256, 0, stream>>>(AG, Xb, wr1h, wr1l, wo1h, wo1l,
                                                 b1, nullptr, H1, nullptr,
                                                 Nn, 144, 256, 256, 1);
    // Layer 2 (aggregate-first): AG = agg(H1); H2 = relu([AG|H1]*[Wr2|Wo2]^T + b2)
    aggregate_sp<32, 2, 0><<<g2, TB, 0, stream>>>(H1, 256, rowptr, col, wv,
                                                  nullptr, AG, 256, Nn);
    gemm5<true><<<dim3(4, mB), 256, 0, stream>>>(AG, H1, wr2h, wr2l, wo2h, wo2l,
                                                 b2, nullptr, H2, nullptr,
                                                 Nn, 256, 512, 512, 1);
    // Layer 3 (transform-first): Y3 = [H2*Wr3^T | H2*Wo3^T + b3]; H3 = agg(Yrel)+Yroot
    gemm5<false><<<dim3(4, mB), 256, 0, stream>>>(H2, H2, wr3h, wr3l, wo3h, wo3l,
                                                  nullptr, b3, Y3, nullptr,
                                                  Nn, 512, 256, 512, 0);
    aggregate_sp<32, 2, 1><<<g2, TB, 0, stream>>>(Y3, 512, rowptr, col, wv,
                                                  Y3 + 256, H3, 256, Nn);
    // GraphNorm + relu in place on H3
    zero_f32<<<2, TB, 0, stream>>>(stats, 512);
    colstats_sp<<<256, TB, 0, stream>>>(H3, sums, sqs, Nn);
    norm_prep<<<1, 256, 0, stream>>>(sums, sqs, gw, gb, gms, scaleF, shiftF, 1.0f / Nn);
    norm_apply_sp<<<(Nn * 32 + TB - 1) / TB, TB, 0, stream>>>(H3, scaleF, shiftF, Nn * 32);
    // Layer 4 (transform-first): Y4 = [H3*Wr4^T | H3*Wo4^T + b4] (fp24); out = agg+root
    gemm5<false><<<dim3(2, mB), 256, 0, stream>>>(H3, H3, wr4h, wr4l, wo4h, wo4l,
                                                  nullptr, b4, Y4h, Y4l,
                                                  Nn, 256, 128, 256, 0);
    aggregate_out2<<<g2, TB, 0, stream>>>(Y4h, Y4l, 256, rowptr, col, wv,
                                          Y4h + 128, Y4l + 128,
                                          (float*)d_out, Nn);
}

// Round 10
// 599.414 us; speedup vs baseline: 2.7943x; 1.0588x over previous
//
#include <hip/hip_runtime.h>

#define F_IN 144
typedef __attribute__((ext_vector_type(8))) short short8v;
typedef __attribute__((ext_vector_type(8))) unsigned short ushort8v;
typedef __attribute__((ext_vector_type(4))) float f32x4;
typedef unsigned short u16;

// ---------------- bf16 helpers ----------------
__device__ __forceinline__ u16 bf16rn(float x) {
    union { float f; unsigned u; } a; a.f = x;
    return (u16)((a.u + 0x7FFFu + ((a.u >> 16) & 1u)) >> 16);
}
__device__ __forceinline__ float bf16tof(u16 h) {
    union { float f; unsigned u; } a; a.u = ((unsigned)h) << 16;
    return a.f;
}
__device__ __forceinline__ void gload_lds16(const u16* g, u16* s) {
    __builtin_amdgcn_global_load_lds(
        (const __attribute__((address_space(1))) void*)g,
        (__attribute__((address_space(3))) void*)s, 16, 0, 0);
}

// ---------------- utility ----------------
__global__ void zero_i32(int* __restrict__ p, int n) {
    int i = blockIdx.x * blockDim.x + threadIdx.x;
    if (i < n) p[i] = 0;
}
__global__ void zero_f32(float* __restrict__ p, int n) {
    int i = blockIdx.x * blockDim.x + threadIdx.x;
    if (i < n) p[i] = 0.f;
}
__global__ void copy_i32(const int* __restrict__ a, int* __restrict__ b, int n) {
    int i = blockIdx.x * blockDim.x + threadIdx.x;
    if (i < n) b[i] = a[i];
}
// weights: f32 -> bf16 hi/lo (fp24)
__global__ void conv_hl(const float* __restrict__ src, u16* __restrict__ dh,
                        u16* __restrict__ dl, int n) {
    int i = blockIdx.x * 256 + threadIdx.x;
    if (i < n) {
        float v = src[i];
        u16 h = bf16rn(v);
        dh[i] = h;
        dl[i] = bf16rn(v - bf16tof(h));
    }
}
// activations: f32 -> bf16
__global__ void conv_bf(const float* __restrict__ src, u16* __restrict__ d, int n) {
    int i = blockIdx.x * 256 + threadIdx.x;
    if (i < n) d[i] = bf16rn(src[i]);
}

// ---------------- CSR build ----------------
__global__ void count_edges(const int* __restrict__ dst, int* __restrict__ counts, int E) {
    int e = blockIdx.x * blockDim.x + threadIdx.x;
    if (e < E) atomicAdd(&counts[dst[e]], 1);
}

__global__ __launch_bounds__(1024) void scan_counts(const int* __restrict__ counts,
                                                    int* __restrict__ rowptr, int N) {
    __shared__ int part[1024];
    int t = threadIdx.x;
    int chunk = (N + 1023) >> 10;
    int beg = t * chunk;
    int end = min(beg + chunk, N);
    int s = 0;
    for (int i = beg; i < end; ++i) s += counts[i];
    part[t] = s;
    __syncthreads();
    for (int off = 1; off < 1024; off <<= 1) {
        int v = (t >= off) ? part[t - off] : 0;
        __syncthreads();
        part[t] += v;
        __syncthreads();
    }
    int run = (t == 0) ? 0 : part[t - 1];
    for (int i = beg; i < end; ++i) { rowptr[i] = run; run += counts[i]; }
    if (end == N) rowptr[N] = run;
}

__global__ void fill_edges(const int* __restrict__ src, const int* __restrict__ dst,
                           const float* __restrict__ ea, int* __restrict__ fillhead,
                           int* __restrict__ col, float* __restrict__ wv, int E) {
    int e = blockIdx.x * blockDim.x + threadIdx.x;
    if (e < E) {
        int d = dst[e];
        int pos = atomicAdd(&fillhead[d], 1);
        col[pos] = src[e];
        wv[pos]  = ea[e];
    }
}

// ------------- single-plane aggregation, NPW nodes per wave -------------
// MODE 0: D = agg(S). MODE 1: D = agg(S) + R (root). bf16 in/out, f32 accum.
// Edge loop unrolled x2 with dual accumulators (2 gathers in flight).
template<int NC, int NPW, int MODE>
__global__ __launch_bounds__(256) void aggregate_sp(
    const u16* __restrict__ S, int SS,
    const int* __restrict__ rowptr, const int* __restrict__ col,
    const float* __restrict__ wv,
    const u16* __restrict__ R,
    u16* __restrict__ D, int FD, int N)
{
    int wav  = (int)((blockIdx.x * 256 + threadIdx.x) >> 6);
    int lane = threadIdx.x & 63;
    int sub  = lane / NC;
    int cl   = lane % NC;
    int wid  = wav * NPW + sub;
    if (sub >= NPW || wid >= N) return;
    float acc0[8] = {}, acc1[8] = {};
    int beg = rowptr[wid], end = rowptr[wid + 1];
    int e = beg;
    for (; e + 2 <= end; e += 2) {
        float w0 = wv[e], w1 = wv[e + 1];
        int   c0 = col[e], c1 = col[e + 1];
        ushort8v v0 = *(const ushort8v*)&S[(size_t)c0 * SS + (cl << 3)];
        ushort8v v1 = *(const ushort8v*)&S[(size_t)c1 * SS + (cl << 3)];
#pragma unroll
        for (int r = 0; r < 8; ++r) {
            acc0[r] = fmaf(w0, bf16tof(v0[r]), acc0[r]);
            acc1[r] = fmaf(w1, bf16tof(v1[r]), acc1[r]);
        }
    }
    if (e < end) {
        float w0 = wv[e];
        ushort8v v0 = *(const ushort8v*)&S[(size_t)col[e] * SS + (cl << 3)];
#pragma unroll
        for (int r = 0; r < 8; ++r) acc0[r] = fmaf(w0, bf16tof(v0[r]), acc0[r]);
    }
#pragma unroll
    for (int r = 0; r < 8; ++r) acc0[r] += acc1[r];
    if (MODE >= 1) {
        ushort8v v = *(const ushort8v*)&R[(size_t)wid * SS + (cl << 3)];
#pragma unroll
        for (int r = 0; r < 8; ++r) acc0[r] += bf16tof(v[r]);
    }
    ushort8v o;
#pragma unroll
    for (int r = 0; r < 8; ++r) o[r] = bf16rn(acc0[r]);
    *(ushort8v*)&D[(size_t)wid * FD + (cl << 3)] = o;
}

// ------- MFMA GEMM: A bf16, B fp24 (hi/lo), 2-term, double-buffered -------
// C = A*(Bh+Bl)^T (+bias). DUALK=true: A=[A1|A2], B=[B1|B2] along K (KK=2*K1).
// DUALK=false: A=A1 (KK=K1); B rows r<NR1 -> B1[r] else B2[r-NR1] (NR1 % 128 == 0).
// 128x128 tile, 4 waves. LDS = 2 x 24KB buffers (A|Bh|Bl planes, 4096 u16 each).
// Per step: ds_read frags of cur -> issue stage of nxt -> MFMA -> ONE barrier
// (implicit vmcnt(0) lands after the compute). Bijective XCD-chunk swizzle (m204)
// so col-blocks sharing an A row-panel land on one XCD's L2.
// Output: Cf (f32) if non-null, else Ch bf16 (+ optional Cl residual plane).
#define GBM 128
#define GBN 128

template<bool DUALK>
__global__ __launch_bounds__(256) void gemm5(
    const u16* __restrict__ A1, const u16* __restrict__ A2,
    const u16* __restrict__ B1h, const u16* __restrict__ B1l,
    const u16* __restrict__ B2h, const u16* __restrict__ B2l,
    const float* __restrict__ biasA, const float* __restrict__ biasB,
    float* __restrict__ Cf, u16* __restrict__ Ch, u16* __restrict__ Cl,
    int M, int K1, int NR1, int ldc, int doRelu)
{
    __shared__ u16 lds[24576];   // 2 buffers x 12288 u16 (A | Bh | Bl)

    const int tid = threadIdx.x;
    const int l = tid & 63, w = tid >> 6;
    const int wm = w >> 1, wn = w & 1;
    const int lane15 = l & 15, slot = l >> 4;

    // ---- bijective XCD-chunk swizzle: same-XCD blocks get consecutive tiles ----
    const int nwg = gridDim.x * gridDim.y;
    const int bid = blockIdx.y * gridDim.x + blockIdx.x;
    const int q = nwg >> 3, r8 = nwg & 7;
    const int xcd = bid & 7, v = bid >> 3;
    const int sw = (xcd < r8) ? xcd * (q + 1) + v : r8 * (q + 1) + (xcd - r8) * q + v;
    const int row0 = (sw / gridDim.x) * GBM;
    const int col0 = (sw % gridDim.x) * GBN;

    const int KK = DUALK ? 2 * K1 : K1;
    const int nsteps = KK / 32;

    // ---- staging precompute: 1536 chunks (3 planes x 512), 6 per thread ----
    const u16* q1[6]; const u16* q2[6]; int lim[6]; int dstoff[6];
#pragma unroll
    for (int i = 0; i < 6; ++i) {
        int idx0  = i * 256 + (tid & ~63);      // wave-uniform
        int p     = idx0 >> 9;                  // plane 0:A 1:Bh 2:Bl
        int cbase = idx0 & 511;
        int c  = cbase + l;                     // per-lane chunk
        int rw = c >> 2, ch = c & 3;
        int cpk = (ch ^ ((rw >> 1) & 3)) << 3;  // swizzled source k-offset (u16)
        lim[i]    = K1 - cpk;
        dstoff[i] = (p << 12) + (cbase << 3);
        const u16 *b1, *b2; int g;
        if (p == 0) {
            b1 = A1; b2 = A2 - K1;
            g = min(row0 + rw, M - 1);
        } else {
            const u16* h1 = (p == 1) ? B1h : B1l;
            const u16* h2 = (p == 1) ? B2h : B2l;
            if (DUALK) { b1 = h1; b2 = h2 - K1; g = col0 + rw; }
            else {
                bool sec = (col0 >= NR1);
                b1 = sec ? h2 : h1; b2 = b1;
                g = col0 + rw - (sec ? NR1 : 0);
            }
        }
        q1[i] = b1 + g * K1 + cpk;
        q2[i] = b2 + g * K1 + cpk;
    }

    f32x4 acc[4][4] = {};

    // prologue: stage tile 0 into buffer 0 (kk0 = 0 always < lim)
#pragma unroll
    for (int i = 0; i < 6; ++i) gload_lds16(q1[i], lds + dstoff[i]);
    __syncthreads();

    int cur = 0;
    for (int step = 0; step < nsteps; ++step) {
        const u16* cb = lds + cur * 12288;
        // ---- 1. ds_read all fragments of cur into registers ----
        short8v av[4], bh[4], bl[4];
#pragma unroll
        for (int bi = 0; bi < 4; ++bi) {
            int r = wm * 64 + bi * 16 + lane15;
            int j = slot ^ ((r >> 1) & 3);
            av[bi] = *(const short8v*)&cb[r * 32 + j * 8];
        }
#pragma unroll
        for (int bj = 0; bj < 4; ++bj) {
            int c = wn * 64 + bj * 16 + lane15;
            int j = slot ^ ((c >> 1) & 3);
            bh[bj] = *(const short8v*)&cb[4096 + c * 32 + j * 8];
            bl[bj] = *(const short8v*)&cb[8192 + c * 32 + j * 8];
        }
        // ---- 2. issue next tile's stage into nxt (flies under the MFMAs) ----
        if (step + 1 < nsteps) {
            int kk0 = (step + 1) * 32;
            u16* nb = lds + (cur ^ 1) * 12288;
#pragma unroll
            for (int i = 0; i < 6; ++i) {
                const u16* src = (DUALK && kk0 >= lim[i]) ? q2[i] : q1[i];
                gload_lds16(src + kk0, nb + dstoff[i]);
            }
        }
        // ---- 3. MFMA (register-only; waits lgkmcnt for the ds_reads) ----
#pragma unroll
        for (int bj = 0; bj < 4; ++bj)
#pragma unroll
            for (int bi = 0; bi < 4; ++bi) {
                acc[bi][bj] = __builtin_amdgcn_mfma_f32_16x16x32_bf16(av[bi], bh[bj], acc[bi][bj], 0, 0, 0);
                acc[bi][bj] = __builtin_amdgcn_mfma_f32_16x16x32_bf16(av[bi], bl[bj], acc[bi][bj], 0, 0, 0);
            }
        // ---- 4. one barrier: drains this step's stage loads after compute ----
        __syncthreads();
        cur ^= 1;
    }

    // ---- epilogue: C/D layout col=lane&15, row=slot*4+q ----
#pragma unroll
    for (int bj = 0; bj < 4; ++bj) {
        int cc = col0 + wn * 64 + bj * 16 + lane15;
        float bv = (cc < NR1) ? (biasA ? biasA[cc] : 0.f)
                              : (biasB ? biasB[cc - NR1] : 0.f);
#pragma unroll
        for (int bi = 0; bi < 4; ++bi) {
            int rbase = row0 + wm * 64 + bi * 16 + slot * 4;
#pragma unroll
            for (int qq = 0; qq < 4; ++qq) {
                int rr = rbase + qq;
                if (rr < M) {
                    float o = acc[bi][bj][qq] + bv;
                    if (doRelu) o = fmaxf(o, 0.f);
                    if (Cf) {
                        Cf[(size_t)rr * ldc + cc] = o;
                    } else {
                        u16 h = bf16rn(o);
                        Ch[(size_t)rr * ldc + cc] = h;
                        if (Cl) Cl[(size_t)rr * ldc + cc] = bf16rn(o - bf16tof(h));
                    }
                }
            }
        }
    }
}

// ---------------- GraphNorm (F = 256) single-plane ----------------
__global__ __launch_bounds__(256) void colstats_sp(const u16* __restrict__ H,
                                                   float* __restrict__ sums,
                                                   float* __restrict__ sqs, int N) {
    int f = threadIdx.x;
    float s = 0.f, q = 0.f;
    for (int i = blockIdx.x; i < N; i += gridDim.x) {
        float v = bf16tof(H[(size_t)i * 256 + f]);
        s += v;
        q = fmaf(v, v, q);
    }
    atomicAdd(&sums[f], s);
    atomicAdd(&sqs[f], q);
}

__global__ void norm_prep(const float* __restrict__ sums, const float* __restrict__ sqs,
                          const float* __restrict__ gw, const float* __restrict__ gb,
                          const float* __restrict__ gms, float* __restrict__ scaleF,
                          float* __restrict__ shiftF, float invN) {
    int f = threadIdx.x;  // 256 threads
    float mu  = sums[f] * invN;
    float ex2 = sqs[f] * invN;
    float a   = gms[f] * mu;
    float var = ex2 - 2.f * a * mu + a * a;
    float inv = rsqrtf(var + 1e-5f);
    float sc  = gw[f] * inv;
    scaleF[f] = sc;
    shiftF[f] = gb[f] - a * sc;
}

__global__ __launch_bounds__(256) void norm_apply_sp(
    u16* __restrict__ H, const float* __restrict__ scaleF,
    const float* __restrict__ shiftF, int n8) {
    int i = blockIdx.x * 256 + threadIdx.x;
    if (i >= n8) return;
    int f0 = (i & 31) << 3;   // 256 feats = 32 chunks of 8
    ushort8v h = *(const ushort8v*)&H[(size_t)i * 8];
    ushort8v o;
#pragma unroll
    for (int r = 0; r < 8; ++r) {
        float v = fmaxf(fmaf(bf16tof(h[r]), scaleF[f0 + r], shiftF[f0 + r]), 0.f);
        o[r] = bf16rn(v);
    }
    *(ushort8v*)&H[(size_t)i * 8] = o;
}

// ---------------- launch ----------------
extern "C" void kernel_launch(void* const* d_in, const int* in_sizes, int n_in,
                              void* d_out, int out_size, void* d_ws, size_t ws_size,
                              hipStream_t stream) {
    const float* x   = (const float*)d_in[0];
    const int*   ei  = (const int*)d_in[1];
    const float* ea  = (const float*)d_in[2];
    const float* Wr1 = (const float*)d_in[3];
    const float* b1  = (const float*)d_in[4];
    const float* Wo1 = (const float*)d_in[5];
    const float* Wr2 = (const float*)d_in[6];
    const float* b2  = (const float*)d_in[7];
    const float* Wo2 = (const float*)d_in[8];
    const float* Wr3 = (const float*)d_in[9];
    const float* b3  = (const float*)d_in[10];
    const float* Wo3 = (const float*)d_in[11];
    const float* Wr4 = (const float*)d_in[12];
    const float* b4  = (const float*)d_in[13];
    const float* Wo4 = (const float*)d_in[14];
    const float* gw  = (const float*)d_in[15];
    const float* gb  = (const float*)d_in[16];
    const float* gms = (const float*)d_in[17];

    const int Nn = in_sizes[0] / F_IN;   // 50000
    const int E  = in_sizes[1] / 2;      // 400000
    const int* src = ei;
    const int* dst = ei + E;

    char* wp = (char*)d_ws;
    auto alloc = [&](size_t bytes) -> void* {
        void* p = (void*)wp;
        wp += (bytes + 255) & ~(size_t)255;
        return p;
    };
    int*   counts   = (int*)alloc((size_t)Nn * 4);
    int*   rowptr   = (int*)alloc((size_t)(Nn + 1) * 4);
    int*   fillhead = (int*)alloc((size_t)Nn * 4);
    int*   col      = (int*)alloc((size_t)E * 4);
    float* wv       = (float*)alloc((size_t)E * 4);
    float* stats    = (float*)alloc(1024 * 4);
    float* sums = stats, *sqs = stats + 256, *scaleF = stats + 512, *shiftF = stats + 768;
    // weights hi/lo (fp24)
    u16* wr1h = (u16*)alloc(2u * 256 * 144); u16* wr1l = (u16*)alloc(2u * 256 * 144);
    u16* wo1h = (u16*)alloc(2u * 256 * 144); u16* wo1l = (u16*)alloc(2u * 256 * 144);
    u16* wr2h = (u16*)alloc(2u * 512 * 256); u16* wr2l = (u16*)alloc(2u * 512 * 256);
    u16* wo2h = (u16*)alloc(2u * 512 * 256); u16* wo2l = (u16*)alloc(2u * 512 * 256);
    u16* wr3h = (u16*)alloc(2u * 256 * 512); u16* wr3l = (u16*)alloc(2u * 256 * 512);
    u16* wo3h = (u16*)alloc(2u * 256 * 512); u16* wo3l = (u16*)alloc(2u * 256 * 512);
    u16* wr4h = (u16*)alloc(2u * 128 * 256); u16* wr4l = (u16*)alloc(2u * 128 * 256);
    u16* wo4h = (u16*)alloc(2u * 128 * 256); u16* wo4l = (u16*)alloc(2u * 128 * 256);

    // ---- lifetime-packed region (u16 units), Nn*1168*2 B = 116.8 MB ----
    // live:  X[0,144) | AG[144,400) | H1[400,656) | H2[656,1168)
    // reuse: Y3  -> [0,512)    (X,AG,H1 dead after GEMM2)
    //        H3  -> [656,912)  (H2 dead after GEMM3)
    //        AG4 -> [144,400)  (Y3 dead after L3 aggregate; AG slot reused)
    u16* big = (u16*)alloc((size_t)Nn * 1168 * 2);
    const size_t NS = (size_t)Nn;
    u16* Xb  = big;
    u16* AG  = big + NS * 144;
    u16* H1  = big + NS * 400;
    u16* H2  = big + NS * 656;
    u16* Y3  = big;
    u16* H3  = big + NS * 656;

    const int TB = 256;
    // CSR build
    zero_i32<<<(Nn + TB - 1) / TB, TB, 0, stream>>>(counts, Nn);
    count_edges<<<(E + TB - 1) / TB, TB, 0, stream>>>(dst, counts, E);
    scan_counts<<<1, 1024, 0, stream>>>(counts, rowptr, Nn);
    copy_i32<<<(Nn + TB - 1) / TB, TB, 0, stream>>>(rowptr, fillhead, Nn);
    fill_edges<<<(E + TB - 1) / TB, TB, 0, stream>>>(src, dst, ea, fillhead, col, wv, E);

    // conversions
    int nx = Nn * F_IN;
    conv_bf<<<(nx + 255) / 256, 256, 0, stream>>>(x, Xb, nx);
    struct WC { const float* s; u16* h; u16* l; int n; } wc[8] = {
        {Wr1, wr1h, wr1l, 256 * 144}, {Wo1, wo1h, wo1l, 256 * 144},
        {Wr2, wr2h, wr2l, 512 * 256}, {Wo2, wo2h, wo2l, 512 * 256},
        {Wr3, wr3h, wr3l, 256 * 512}, {Wo3, wo3h, wo3l, 256 * 512},
        {Wr4, wr4h, wr4l, 128 * 256}, {Wo4, wo4h, wo4l, 128 * 256}};
    for (int i = 0; i < 8; ++i)
        conv_hl<<<(wc[i].n + 255) / 256, 256, 0, stream>>>(wc[i].s, wc[i].h, wc[i].l, wc[i].n);

    int mB = (Nn + GBM - 1) / GBM;              // 391
    int g3 = (((Nn + 2) / 3) + 3) / 4;          // 3 nodes/wave grids
    int g2 = (((Nn + 1) / 2) + 3) / 4;          // 2 nodes/wave grids

    // Layer 1 (aggregate-first): AG = agg(X); H1 = relu([AG|X]*[Wr1|Wo1]^T + b1)
    aggregate_sp<18, 3, 0><<<g3, TB, 0, stream>>>(Xb, 144, rowptr, col, wv,
                                                  nullptr, AG, 144, Nn);
    gemm5<true><<<dim3(2, mB), 256, 0, stream>>>(AG, Xb, wr1h, wr1l, wo1h, wo1l,
                                                 b1, nullptr, nullptr, H1, nullptr,
                                                 Nn, 144, 256, 256, 1);
    // Layer 2 (aggregate-first): AG = agg(H1); H2 = relu([AG|H1]*[Wr2|Wo2]^T + b2)
    aggregate_sp<32, 2, 0><<<g2, TB, 0, stream>>>(H1, 256, rowptr, col, wv,
                                                  nullptr, AG, 256, Nn);
    gemm5<true><<<dim3(4, mB), 256, 0, stream>>>(AG, H1, wr2h, wr2l, wo2h, wo2l,
                                                 b2, nullptr, nullptr, H2, nullptr,
                                                 Nn, 256, 512, 512, 1);
    // Layer 3 (transform-first): Y3 = [H2*Wr3^T | H2*Wo3^T + b3]; H3 = agg(Yrel)+Yroot
    gemm5<false><<<dim3(4, mB), 256, 0, stream>>>(H2, H2, wr3h, wr3l, wo3h, wo3l,
                                                  nullptr, b3, nullptr, Y3, nullptr,
                                                  Nn, 512, 256, 512, 0);
    aggregate_sp<32, 2, 1><<<g2, TB, 0, stream>>>(Y3, 512, rowptr, col, wv,
                                                  Y3 + 256, H3, 256, Nn);
    // GraphNorm + relu in place on H3
    zero_f32<<<2, TB, 0, stream>>>(stats, 512);
    colstats_sp<<<256, TB, 0, stream>>>(H3, sums, sqs, Nn);
    norm_prep<<<1, 256, 0, stream>>>(sums, sqs, gw, gb, gms, scaleF, shiftF, 1.0f / Nn);
    norm_apply_sp<<<(Nn * 32 + TB - 1) / TB, TB, 0, stream>>>(H3, scaleF, shiftF, Nn * 32);
    // Layer 4 (aggregate-first): AG = agg(H3); out = [AG|H3]*[Wr4|Wo4]^T + b4 (f32)
    aggregate_sp<32, 2, 0><<<g2, TB, 0, stream>>>(H3, 256, rowptr, col, wv,
                                                  nullptr, AG, 256, Nn);
    gemm5<true><<<dim3(1, mB), 256, 0, stream>>>(AG, H3, wr4h, wr4l, wo4h, wo4l,
                                                 b4, nullptr, (float*)d_out, nullptr, nullptr,
                                                 Nn, 256, 128, 128, 0);
}

// Round 11
// 562.265 us; speedup vs baseline: 2.9789x; 1.0661x over previous
//
#include <hip/hip_runtime.h>

#define F_IN 144
typedef __attribute__((ext_vector_type(8))) short short8v;
typedef __attribute__((ext_vector_type(8))) unsigned short ushort8v;
typedef __attribute__((ext_vector_type(4))) float f32x4;
typedef unsigned short u16;

// ---------------- bf16 helpers ----------------
__device__ __forceinline__ u16 bf16rn(float x) {
    union { float f; unsigned u; } a; a.f = x;
    return (u16)((a.u + 0x7FFFu + ((a.u >> 16) & 1u)) >> 16);
}
__device__ __forceinline__ float bf16tof(u16 h) {
    union { float f; unsigned u; } a; a.u = ((unsigned)h) << 16;
    return a.f;
}
__device__ __forceinline__ void gload_lds16(const u16* g, u16* s) {
    __builtin_amdgcn_global_load_lds(
        (const __attribute__((address_space(1))) void*)g,
        (__attribute__((address_space(3))) void*)s, 16, 0, 0);
}

// ---------------- utility ----------------
__global__ void zero_i32(int* __restrict__ p, int n) {
    int i = blockIdx.x * blockDim.x + threadIdx.x;
    if (i < n) p[i] = 0;
}
__global__ void zero_f32(float* __restrict__ p, int n) {
    int i = blockIdx.x * blockDim.x + threadIdx.x;
    if (i < n) p[i] = 0.f;
}
__global__ void copy_i32(const int* __restrict__ a, int* __restrict__ b, int n) {
    int i = blockIdx.x * blockDim.x + threadIdx.x;
    if (i < n) b[i] = a[i];
}
// weights: f32 -> bf16 hi/lo (fp24)
__global__ void conv_hl(const float* __restrict__ src, u16* __restrict__ dh,
                        u16* __restrict__ dl, int n) {
    int i = blockIdx.x * 256 + threadIdx.x;
    if (i < n) {
        float v = src[i];
        u16 h = bf16rn(v);
        dh[i] = h;
        dl[i] = bf16rn(v - bf16tof(h));
    }
}
// f32 -> bf16 single plane
__global__ void conv_bf(const float* __restrict__ src, u16* __restrict__ d, int n) {
    int i = blockIdx.x * 256 + threadIdx.x;
    if (i < n) d[i] = bf16rn(src[i]);
}

// ---------------- CSR build ----------------
__global__ void count_edges(const int* __restrict__ dst, int* __restrict__ counts, int E) {
    int e = blockIdx.x * blockDim.x + threadIdx.x;
    if (e < E) atomicAdd(&counts[dst[e]], 1);
}

__global__ __launch_bounds__(1024) void scan_counts(const int* __restrict__ counts,
                                                    int* __restrict__ rowptr, int N) {
    __shared__ int part[1024];
    int t = threadIdx.x;
    int chunk = (N + 1023) >> 10;
    int beg = t * chunk;
    int end = min(beg + chunk, N);
    int s = 0;
    for (int i = beg; i < end; ++i) s += counts[i];
    part[t] = s;
    __syncthreads();
    for (int off = 1; off < 1024; off <<= 1) {
        int v = (t >= off) ? part[t - off] : 0;
        __syncthreads();
        part[t] += v;
        __syncthreads();
    }
    int run = (t == 0) ? 0 : part[t - 1];
    for (int i = beg; i < end; ++i) { rowptr[i] = run; run += counts[i]; }
    if (end == N) rowptr[N] = run;
}

__global__ void fill_edges(const int* __restrict__ src, const int* __restrict__ dst,
                           const float* __restrict__ ea, int* __restrict__ fillhead,
                           int* __restrict__ col, float* __restrict__ wv, int E) {
    int e = blockIdx.x * blockDim.x + threadIdx.x;
    if (e < E) {
        int d = dst[e];
        int pos = atomicAdd(&fillhead[d], 1);
        col[pos] = src[e];
        wv[pos]  = ea[e];
    }
}

// ------------- single-plane aggregation, NPW nodes per wave -------------
// MODE 0: D = agg(S). MODE 1: D = agg(S) + R (root). bf16 in/out, f32 accum.
// Edge loop unrolled x4 (4 independent gathers in flight).
template<int NC, int NPW, int MODE>
__global__ __launch_bounds__(256) void aggregate_sp(
    const u16* __restrict__ S, int SS,
    const int* __restrict__ rowptr, const int* __restrict__ col,
    const float* __restrict__ wv,
    const u16* __restrict__ R,
    u16* __restrict__ D, int FD, int N)
{
    int wav  = (int)((blockIdx.x * 256 + threadIdx.x) >> 6);
    int lane = threadIdx.x & 63;
    int sub  = lane / NC;
    int cl   = lane % NC;
    int wid  = wav * NPW + sub;
    if (sub >= NPW || wid >= N) return;
    float acc0[8] = {}, acc1[8] = {}, acc2[8] = {}, acc3[8] = {};
    int beg = rowptr[wid], end = rowptr[wid + 1];
    int e = beg;
    for (; e + 4 <= end; e += 4) {
        float w0 = wv[e], w1 = wv[e + 1], w2 = wv[e + 2], w3 = wv[e + 3];
        int   c0 = col[e], c1 = col[e + 1], c2 = col[e + 2], c3 = col[e + 3];
        ushort8v v0 = *(const ushort8v*)&S[(size_t)c0 * SS + (cl << 3)];
        ushort8v v1 = *(const ushort8v*)&S[(size_t)c1 * SS + (cl << 3)];
        ushort8v v2 = *(const ushort8v*)&S[(size_t)c2 * SS + (cl << 3)];
        ushort8v v3 = *(const ushort8v*)&S[(size_t)c3 * SS + (cl << 3)];
#pragma unroll
        for (int r = 0; r < 8; ++r) {
            acc0[r] = fmaf(w0, bf16tof(v0[r]), acc0[r]);
            acc1[r] = fmaf(w1, bf16tof(v1[r]), acc1[r]);
            acc2[r] = fmaf(w2, bf16tof(v2[r]), acc2[r]);
            acc3[r] = fmaf(w3, bf16tof(v3[r]), acc3[r]);
        }
    }
    for (; e < end; ++e) {
        float w0 = wv[e];
        ushort8v v0 = *(const ushort8v*)&S[(size_t)col[e] * SS + (cl << 3)];
#pragma unroll
        for (int r = 0; r < 8; ++r) acc0[r] = fmaf(w0, bf16tof(v0[r]), acc0[r]);
    }
#pragma unroll
    for (int r = 0; r < 8; ++r) acc0[r] += (acc1[r] + acc2[r]) + acc3[r];
    if (MODE >= 1) {
        ushort8v v = *(const ushort8v*)&R[(size_t)wid * SS + (cl << 3)];
#pragma unroll
        for (int r = 0; r < 8; ++r) acc0[r] += bf16tof(v[r]);
    }
    ushort8v o;
#pragma unroll
    for (int r = 0; r < 8; ++r) o[r] = bf16rn(acc0[r]);
    *(ushort8v*)&D[(size_t)wid * FD + (cl << 3)] = o;
}

// ------- MFMA GEMM: A bf16, B = BT planes (1: bf16, 2: fp24 hi/lo) -------
// C = A*(sum of B planes)^T (+bias). DUALK=true: A=[A1|A2], B=[B1|B2] along K.
// DUALK=false: A=A1 (KK=K1); B rows r<NR1 -> B1[r] else B2[r-NR1] (NR1 % 128 == 0).
// 128x128 tile, 4 waves. LDS = 2 x (1+BT)*8KB buffers. Per step: ds_read frags of
// cur -> issue stage of nxt (reads precede writes: no forced vmcnt) -> MFMA ->
// ONE __syncthreads (implicit vmcnt(0) lands after compute). Bijective XCD-chunk
// swizzle (m204). Output: Cf (f32) if non-null, else Ch bf16 (+ optional Cl plane).
#define GBM 128
#define GBN 128

template<bool DUALK, int BT>
__global__ __launch_bounds__(256) void gemm6(
    const u16* __restrict__ A1, const u16* __restrict__ A2,
    const u16* __restrict__ B1h, const u16* __restrict__ B1l,
    const u16* __restrict__ B2h, const u16* __restrict__ B2l,
    const float* __restrict__ biasA, const float* __restrict__ biasB,
    float* __restrict__ Cf, u16* __restrict__ Ch, u16* __restrict__ Cl,
    int M, int K1, int NR1, int ldc, int doRelu)
{
    constexpr int NP = 1 + BT;            // LDS planes: A, Bh[, Bl]
    constexpr int NCH = 2 * NP;           // staged chunks per thread
    constexpr int BUF = NP * 4096;        // u16 per buffer
    __shared__ u16 lds[2 * BUF];

    const int tid = threadIdx.x;
    const int l = tid & 63, w = tid >> 6;
    const int wm = w >> 1, wn = w & 1;
    const int lane15 = l & 15, slot = l >> 4;

    // ---- bijective XCD-chunk swizzle (m204) ----
    const int nwg = gridDim.x * gridDim.y;
    const int bid = blockIdx.y * gridDim.x + blockIdx.x;
    const int q = nwg >> 3, r8 = nwg & 7;
    const int xcd = bid & 7, v = bid >> 3;
    const int sw = (xcd < r8) ? xcd * (q + 1) + v : r8 * (q + 1) + (xcd - r8) * q + v;
    const int row0 = (sw / gridDim.x) * GBM;
    const int col0 = (sw % gridDim.x) * GBN;

    const int KK = DUALK ? 2 * K1 : K1;
    const int nsteps = KK / 32;

    // ---- staging precompute: NP planes x 512 chunks, NCH per thread ----
    const u16* q1[NCH]; const u16* q2[NCH]; int lim[NCH]; int dstoff[NCH];
#pragma unroll
    for (int i = 0; i < NCH; ++i) {
        int idx0  = i * 256 + (tid & ~63);      // wave-uniform
        int p     = idx0 >> 9;                  // plane 0:A 1:Bh 2:Bl
        int cbase = idx0 & 511;
        int c  = cbase + l;                     // per-lane chunk
        int rw = c >> 2, ch = c & 3;
        int cpk = (ch ^ ((rw >> 1) & 3)) << 3;  // swizzled source k-offset (u16)
        lim[i]    = K1 - cpk;
        dstoff[i] = (p << 12) + (cbase << 3);
        const u16 *b1, *b2; int g;
        if (p == 0) {
            b1 = A1; b2 = A2 - K1;
            g = min(row0 + rw, M - 1);
        } else {
            const u16* h1 = (p == 1) ? B1h : B1l;
            const u16* h2 = (p == 1) ? B2h : B2l;
            if (DUALK) { b1 = h1; b2 = h2 - K1; g = col0 + rw; }
            else {
                bool sec = (col0 >= NR1);
                b1 = sec ? h2 : h1; b2 = b1;
                g = col0 + rw - (sec ? NR1 : 0);
            }
        }
        q1[i] = b1 + g * K1 + cpk;
        q2[i] = b2 + g * K1 + cpk;
    }

    f32x4 acc[4][4] = {};

    // prologue: stage tile 0 into buffer 0
#pragma unroll
    for (int i = 0; i < NCH; ++i) gload_lds16(q1[i], lds + dstoff[i]);
    __syncthreads();

    int cur = 0;
    for (int step = 0; step < nsteps; ++step) {
        const u16* cb = lds + cur * BUF;
        // ---- 1. ds_read all fragments of cur into registers ----
        short8v av[4], bh[4], bl[4];
#pragma unroll
        for (int bi = 0; bi < 4; ++bi) {
            int r = wm * 64 + bi * 16 + lane15;
            int j = slot ^ ((r >> 1) & 3);
            av[bi] = *(const short8v*)&cb[r * 32 + j * 8];
        }
#pragma unroll
        for (int bj = 0; bj < 4; ++bj) {
            int c = wn * 64 + bj * 16 + lane15;
            int j = slot ^ ((c >> 1) & 3);
            bh[bj] = *(const short8v*)&cb[4096 + c * 32 + j * 8];
            if (BT == 2) bl[bj] = *(const short8v*)&cb[8192 + c * 32 + j * 8];
        }
        // ---- 2. issue next tile's stage into nxt (flies under the MFMAs) ----
        if (step + 1 < nsteps) {
            int kk0 = (step + 1) * 32;
            u16* nb = lds + (cur ^ 1) * BUF;
#pragma unroll
            for (int i = 0; i < NCH; ++i) {
                const u16* src = (DUALK && kk0 >= lim[i]) ? q2[i] : q1[i];
                gload_lds16(src + kk0, nb + dstoff[i]);
            }
        }
        // ---- 3. MFMA (register-only; waits lgkmcnt for the ds_reads) ----
#pragma unroll
        for (int bj = 0; bj < 4; ++bj)
#pragma unroll
            for (int bi = 0; bi < 4; ++bi) {
                acc[bi][bj] = __builtin_amdgcn_mfma_f32_16x16x32_bf16(av[bi], bh[bj], acc[bi][bj], 0, 0, 0);
                if (BT == 2)
                    acc[bi][bj] = __builtin_amdgcn_mfma_f32_16x16x32_bf16(av[bi], bl[bj], acc[bi][bj], 0, 0, 0);
            }
        // ---- 4. one barrier: drains this step's stage loads after compute ----
        __syncthreads();
        cur ^= 1;
    }

    // ---- epilogue: C/D layout col=lane&15, row=slot*4+q ----
#pragma unroll
    for (int bj = 0; bj < 4; ++bj) {
        int cc = col0 + wn * 64 + bj * 16 + lane15;
        float bv = (cc < NR1) ? (biasA ? biasA[cc] : 0.f)
                              : (biasB ? biasB[cc - NR1] : 0.f);
#pragma unroll
        for (int bi = 0; bi < 4; ++bi) {
            int rbase = row0 + wm * 64 + bi * 16 + slot * 4;
#pragma unroll
            for (int qq = 0; qq < 4; ++qq) {
                int rr = rbase + qq;
                if (rr < M) {
                    float o = acc[bi][bj][qq] + bv;
                    if (doRelu) o = fmaxf(o, 0.f);
                    if (Cf) {
                        Cf[(size_t)rr * ldc + cc] = o;
                    } else {
                        u16 h = bf16rn(o);
                        Ch[(size_t)rr * ldc + cc] = h;
                        if (Cl) Cl[(size_t)rr * ldc + cc] = bf16rn(o - bf16tof(h));
                    }
                }
            }
        }
    }
}

// ---------------- GraphNorm (F = 256) single-plane ----------------
__global__ __launch_bounds__(256) void colstats_sp(const u16* __restrict__ H,
                                                   float* __restrict__ sums,
                                                   float* __restrict__ sqs, int N) {
    int f = threadIdx.x;
    float s = 0.f, q = 0.f;
    for (int i = blockIdx.x; i < N; i += gridDim.x) {
        float v = bf16tof(H[(size_t)i * 256 + f]);
        s += v;
        q = fmaf(v, v, q);
    }
    atomicAdd(&sums[f], s);
    atomicAdd(&sqs[f], q);
}

__global__ void norm_prep(const float* __restrict__ sums, const float* __restrict__ sqs,
                          const float* __restrict__ gw, const float* __restrict__ gb,
                          const float* __restrict__ gms, float* __restrict__ scaleF,
                          float* __restrict__ shiftF, float invN) {
    int f = threadIdx.x;  // 256 threads
    float mu  = sums[f] * invN;
    float ex2 = sqs[f] * invN;
    float a   = gms[f] * mu;
    float var = ex2 - 2.f * a * mu + a * a;
    float inv = rsqrtf(var + 1e-5f);
    float sc  = gw[f] * inv;
    scaleF[f] = sc;
    shiftF[f] = gb[f] - a * sc;
}

__global__ __launch_bounds__(256) void norm_apply_sp(
    u16* __restrict__ H, const float* __restrict__ scaleF,
    const float* __restrict__ shiftF, int n8) {
    int i = blockIdx.x * 256 + threadIdx.x;
    if (i >= n8) return;
    int f0 = (i & 31) << 3;   // 256 feats = 32 chunks of 8
    ushort8v h = *(const ushort8v*)&H[(size_t)i * 8];
    ushort8v o;
#pragma unroll
    for (int r = 0; r < 8; ++r) {
        float v = fmaxf(fmaf(bf16tof(h[r]), scaleF[f0 + r], shiftF[f0 + r]), 0.f);
        o[r] = bf16rn(v);
    }
    *(ushort8v*)&H[(size_t)i * 8] = o;
}

// ---------------- launch ----------------
extern "C" void kernel_launch(void* const* d_in, const int* in_sizes, int n_in,
                              void* d_out, int out_size, void* d_ws, size_t ws_size,
                              hipStream_t stream) {
    const float* x   = (const float*)d_in[0];
    const int*   ei  = (const int*)d_in[1];
    const float* ea  = (const float*)d_in[2];
    const float* Wr1 = (const float*)d_in[3];
    const float* b1  = (const float*)d_in[4];
    const float* Wo1 = (const float*)d_in[5];
    const float* Wr2 = (const float*)d_in[6];
    const float* b2  = (const float*)d_in[7];
    const float* Wo2 = (const float*)d_in[8];
    const float* Wr3 = (const float*)d_in[9];
    const float* b3  = (const float*)d_in[10];
    const float* Wo3 = (const float*)d_in[11];
    const float* Wr4 = (const float*)d_in[12];
    const float* b4  = (const float*)d_in[13];
    const float* Wo4 = (const float*)d_in[14];
    const float* gw  = (const float*)d_in[15];
    const float* gb  = (const float*)d_in[16];
    const float* gms = (const float*)d_in[17];

    const int Nn = in_sizes[0] / F_IN;   // 50000
    const int E  = in_sizes[1] / 2;      // 400000
    const int* src = ei;
    const int* dst = ei + E;

    char* wp = (char*)d_ws;
    auto alloc = [&](size_t bytes) -> void* {
        void* p = (void*)wp;
        wp += (bytes + 255) & ~(size_t)255;
        return p;
    };
    int*   counts   = (int*)alloc((size_t)Nn * 4);
    int*   rowptr   = (int*)alloc((size_t)(Nn + 1) * 4);
    int*   fillhead = (int*)alloc((size_t)Nn * 4);
    int*   col      = (int*)alloc((size_t)E * 4);
    float* wv       = (float*)alloc((size_t)E * 4);
    float* stats    = (float*)alloc(1024 * 4);
    float* sums = stats, *sqs = stats + 256, *scaleF = stats + 512, *shiftF = stats + 768;
    // weights: L1-L3 single bf16 plane, L4 fp24 hi/lo
    u16* wr1 = (u16*)alloc(2u * 256 * 144);
    u16* wo1 = (u16*)alloc(2u * 256 * 144);
    u16* wr2 = (u16*)alloc(2u * 512 * 256);
    u16* wo2 = (u16*)alloc(2u * 512 * 256);
    u16* wr3 = (u16*)alloc(2u * 256 * 512);
    u16* wo3 = (u16*)alloc(2u * 256 * 512);
    u16* wr4h = (u16*)alloc(2u * 128 * 256); u16* wr4l = (u16*)alloc(2u * 128 * 256);
    u16* wo4h = (u16*)alloc(2u * 128 * 256); u16* wo4l = (u16*)alloc(2u * 128 * 256);

    // ---- lifetime-packed region (u16 units), Nn*1168*2 B = 116.8 MB ----
    // live:  X[0,144) | AG[144,400) | H1[400,656) | H2[656,1168)
    // reuse: Y3  -> [0,512)    (X,AG,H1 dead after GEMM2)
    //        H3  -> [656,912)  (H2 dead after GEMM3)
    //        AG4 -> [144,400)  (Y3 dead after L3 aggregate; AG slot reused)
    u16* big = (u16*)alloc((size_t)Nn * 1168 * 2);
    const size_t NS = (size_t)Nn;
    u16* Xb  = big;
    u16* AG  = big + NS * 144;
    u16* H1  = big + NS * 400;
    u16* H2  = big + NS * 656;
    u16* Y3  = big;
    u16* H3  = big + NS * 656;

    const int TB = 256;
    // CSR build
    zero_i32<<<(Nn + TB - 1) / TB, TB, 0, stream>>>(counts, Nn);
    count_edges<<<(E + TB - 1) / TB, TB, 0, stream>>>(dst, counts, E);
    scan_counts<<<1, 1024, 0, stream>>>(counts, rowptr, Nn);
    copy_i32<<<(Nn + TB - 1) / TB, TB, 0, stream>>>(rowptr, fillhead, Nn);
    fill_edges<<<(E + TB - 1) / TB, TB, 0, stream>>>(src, dst, ea, fillhead, col, wv, E);

    // conversions
    int nx = Nn * F_IN;
    conv_bf<<<(nx + 255) / 256, 256, 0, stream>>>(x, Xb, nx);
    struct BC { const float* s; u16* d; int n; } bc[6] = {
        {Wr1, wr1, 256 * 144}, {Wo1, wo1, 256 * 144},
        {Wr2, wr2, 512 * 256}, {Wo2, wo2, 512 * 256},
        {Wr3, wr3, 256 * 512}, {Wo3, wo3, 256 * 512}};
    for (int i = 0; i < 6; ++i)
        conv_bf<<<(bc[i].n + 255) / 256, 256, 0, stream>>>(bc[i].s, bc[i].d, bc[i].n);
    conv_hl<<<(128 * 256 + 255) / 256, 256, 0, stream>>>(Wr4, wr4h, wr4l, 128 * 256);
    conv_hl<<<(128 * 256 + 255) / 256, 256, 0, stream>>>(Wo4, wo4h, wo4l, 128 * 256);

    int mB = (Nn + GBM - 1) / GBM;              // 391
    int g3 = (((Nn + 2) / 3) + 3) / 4;          // 3 nodes/wave grids
    int g2 = (((Nn + 1) / 2) + 3) / 4;          // 2 nodes/wave grids

    // Layer 1 (aggregate-first): AG = agg(X); H1 = relu([AG|X]*[Wr1|Wo1]^T + b1)
    aggregate_sp<18, 3, 0><<<g3, TB, 0, stream>>>(Xb, 144, rowptr, col, wv,
                                                  nullptr, AG, 144, Nn);
    gemm6<true, 1><<<dim3(2, mB), 256, 0, stream>>>(AG, Xb, wr1, nullptr, wo1, nullptr,
                                                    b1, nullptr, nullptr, H1, nullptr,
                                                    Nn, 144, 256, 256, 1);
    // Layer 2 (aggregate-first): AG = agg(H1); H2 = relu([AG|H1]*[Wr2|Wo2]^T + b2)
    aggregate_sp<32, 2, 0><<<g2, TB, 0, stream>>>(H1, 256, rowptr, col, wv,
                                                  nullptr, AG, 256, Nn);
    gemm6<true, 1><<<dim3(4, mB), 256, 0, stream>>>(AG, H1, wr2, nullptr, wo2, nullptr,
                                                    b2, nullptr, nullptr, H2, nullptr,
                                                    Nn, 256, 512, 512, 1);
    // Layer 3 (transform-first): Y3 = [H2*Wr3^T | H2*Wo3^T + b3]; H3 = agg(Yrel)+Yroot
    gemm6<false, 1><<<dim3(4, mB), 256, 0, stream>>>(H2, H2, wr3, nullptr, wo3, nullptr,
                                                     nullptr, b3, nullptr, Y3, nullptr,
                                                     Nn, 512, 256, 512, 0);
    aggregate_sp<32, 2, 1><<<g2, TB, 0, stream>>>(Y3, 512, rowptr, col, wv,
                                                  Y3 + 256, H3, 256, Nn);
    // GraphNorm + relu in place on H3
    zero_f32<<<2, TB, 0, stream>>>(stats, 512);
    colstats_sp<<<256, TB, 0, stream>>>(H3, sums, sqs, Nn);
    norm_prep<<<1, 256, 0, stream>>>(sums, sqs, gw, gb, gms, scaleF, shiftF, 1.0f / Nn);
    norm_apply_sp<<<(Nn * 32 + TB - 1) / TB, TB, 0, stream>>>(H3, scaleF, shiftF, Nn * 32);
    // Layer 4 (aggregate-first, fp24 weights): AG = agg(H3);
    // out = [AG|H3]*[Wr4|Wo4]^T + b4 (f32)
    aggregate_sp<32, 2, 0><<<g2, TB, 0, stream>>>(H3, 256, rowptr, col, wv,
                                                  nullptr, AG, 256, Nn);
    gemm6<true, 2><<<dim3(1, mB), 256, 0, stream>>>(AG, H3, wr4h, wr4l, wo4h, wo4l,
                                                    b4, nullptr, (float*)d_out, nullptr, nullptr,
                                                    Nn, 256, 128, 128, 0);
}

// Round 12
// 496.068 us; speedup vs baseline: 3.3765x; 1.1334x over previous
//
#include <hip/hip_runtime.h>

#define F_IN 144
typedef __attribute__((ext_vector_type(8))) short short8v;
typedef __attribute__((ext_vector_type(8))) unsigned short ushort8v;
typedef __attribute__((ext_vector_type(4))) float f32x4;
typedef unsigned short u16;

// ---------------- bf16 helpers ----------------
__device__ __forceinline__ u16 bf16rn(float x) {
    union { float f; unsigned u; } a; a.f = x;
    return (u16)((a.u + 0x7FFFu + ((a.u >> 16) & 1u)) >> 16);
}
__device__ __forceinline__ float bf16tof(u16 h) {
    union { float f; unsigned u; } a; a.u = ((unsigned)h) << 16;
    return a.f;
}
__device__ __forceinline__ void gload_lds16(const u16* g, u16* s) {
    __builtin_amdgcn_global_load_lds(
        (const __attribute__((address_space(1))) void*)g,
        (__attribute__((address_space(3))) void*)s, 16, 0, 0);
}

// ---------------- utility ----------------
__global__ void zero_i32(int* __restrict__ p, int n) {
    int i = blockIdx.x * blockDim.x + threadIdx.x;
    if (i < n) p[i] = 0;
}
__global__ void zero_f32(float* __restrict__ p, int n) {
    int i = blockIdx.x * blockDim.x + threadIdx.x;
    if (i < n) p[i] = 0.f;
}
// weights: f32 -> bf16 hi/lo (fp24)
__global__ void conv_hl(const float* __restrict__ src, u16* __restrict__ dh,
                        u16* __restrict__ dl, int n) {
    int i = blockIdx.x * 256 + threadIdx.x;
    if (i < n) {
        float v = src[i];
        u16 h = bf16rn(v);
        dh[i] = h;
        dl[i] = bf16rn(v - bf16tof(h));
    }
}
// f32 -> bf16 single plane
__global__ void conv_bf(const float* __restrict__ src, u16* __restrict__ d, int n) {
    int i = blockIdx.x * 256 + threadIdx.x;
    if (i < n) d[i] = bf16rn(src[i]);
}

// ---------------- CSR build ----------------
__global__ void count_edges(const int* __restrict__ dst, int* __restrict__ counts, int E) {
    int e = blockIdx.x * blockDim.x + threadIdx.x;
    if (e < E) atomicAdd(&counts[dst[e]], 1);
}

// 3-pass parallel exclusive scan (2048 elements per block)
#define SCB 2048
__global__ __launch_bounds__(256) void scan_partial(const int* __restrict__ counts,
                                                    int* __restrict__ rowptr,
                                                    int* __restrict__ bsum, int N) {
    __shared__ int ls[256];
    int t = threadIdx.x;
    int base = blockIdx.x * SCB + t * 8;
    int v[8]; int s = 0;
#pragma unroll
    for (int j = 0; j < 8; ++j) {
        int i = base + j;
        v[j] = (i < N) ? counts[i] : 0;
        s += v[j];
    }
    ls[t] = s;
    __syncthreads();
    for (int off = 1; off < 256; off <<= 1) {
        int x = (t >= off) ? ls[t - off] : 0;
        __syncthreads();
        ls[t] += x;
        __syncthreads();
    }
    int run = (t == 0) ? 0 : ls[t - 1];
#pragma unroll
    for (int j = 0; j < 8; ++j) {
        int i = base + j;
        if (i < N) rowptr[i] = run;
        run += v[j];
    }
    if (t == 255) bsum[blockIdx.x] = ls[255];
}

__global__ __launch_bounds__(256) void scan_tops(const int* __restrict__ bsum,
                                                 int* __restrict__ boff, int nb) {
    __shared__ int ls[256];
    int t = threadIdx.x;
    ls[t] = (t < nb) ? bsum[t] : 0;
    __syncthreads();
    for (int off = 1; off < 256; off <<= 1) {
        int x = (t >= off) ? ls[t - off] : 0;
        __syncthreads();
        ls[t] += x;
        __syncthreads();
    }
    boff[t] = (t == 0) ? 0 : ls[t - 1];   // exclusive block prefix
}

__global__ void scan_add(int* __restrict__ rowptr, int* __restrict__ fillhead,
                         const int* __restrict__ boff, int N, int E) {
    int i = blockIdx.x * 256 + threadIdx.x;
    if (i < N) {
        int r = rowptr[i] + boff[i >> 11];   // SCB = 2048 = 1<<11
        rowptr[i] = r;
        fillhead[i] = r;
    }
    if (i == N) rowptr[N] = E;
}

__global__ void fill_edges(const int* __restrict__ src, const int* __restrict__ dst,
                           const float* __restrict__ ea, int* __restrict__ fillhead,
                           int* __restrict__ col, float* __restrict__ wv, int E) {
    int e = blockIdx.x * blockDim.x + threadIdx.x;
    if (e < E) {
        int d = dst[e];
        int pos = atomicAdd(&fillhead[d], 1);
        col[pos] = src[e];
        wv[pos]  = ea[e];
    }
}

// ------------- single-plane aggregation, NPW nodes per wave -------------
// MODE 0: D = agg(S) (bf16). MODE 1: D = agg(S) + R (bf16). MODE 2: Df = agg(S) + R (f32).
// Edge loop unrolled x4 (4 independent gathers in flight).
template<int NC, int NPW, int MODE>
__global__ __launch_bounds__(256) void aggregate_sp(
    const u16* __restrict__ S, int SS,
    const int* __restrict__ rowptr, const int* __restrict__ col,
    const float* __restrict__ wv,
    const u16* __restrict__ R,
    u16* __restrict__ D, float* __restrict__ Df, int FD, int N)
{
    int wav  = (int)((blockIdx.x * 256 + threadIdx.x) >> 6);
    int lane = threadIdx.x & 63;
    int sub  = lane / NC;
    int cl   = lane % NC;
    int wid  = wav * NPW + sub;
    if (sub >= NPW || wid >= N) return;
    float acc0[8] = {}, acc1[8] = {}, acc2[8] = {}, acc3[8] = {};
    int beg = rowptr[wid], end = rowptr[wid + 1];
    int e = beg;
    for (; e + 4 <= end; e += 4) {
        float w0 = wv[e], w1 = wv[e + 1], w2 = wv[e + 2], w3 = wv[e + 3];
        int   c0 = col[e], c1 = col[e + 1], c2 = col[e + 2], c3 = col[e + 3];
        ushort8v v0 = *(const ushort8v*)&S[(size_t)c0 * SS + (cl << 3)];
        ushort8v v1 = *(const ushort8v*)&S[(size_t)c1 * SS + (cl << 3)];
        ushort8v v2 = *(const ushort8v*)&S[(size_t)c2 * SS + (cl << 3)];
        ushort8v v3 = *(const ushort8v*)&S[(size_t)c3 * SS + (cl << 3)];
#pragma unroll
        for (int r = 0; r < 8; ++r) {
            acc0[r] = fmaf(w0, bf16tof(v0[r]), acc0[r]);
            acc1[r] = fmaf(w1, bf16tof(v1[r]), acc1[r]);
            acc2[r] = fmaf(w2, bf16tof(v2[r]), acc2[r]);
            acc3[r] = fmaf(w3, bf16tof(v3[r]), acc3[r]);
        }
    }
    for (; e < end; ++e) {
        float w0 = wv[e];
        ushort8v v0 = *(const ushort8v*)&S[(size_t)col[e] * SS + (cl << 3)];
#pragma unroll
        for (int r = 0; r < 8; ++r) acc0[r] = fmaf(w0, bf16tof(v0[r]), acc0[r]);
    }
#pragma unroll
    for (int r = 0; r < 8; ++r) acc0[r] += (acc1[r] + acc2[r]) + acc3[r];
    if (MODE >= 1) {
        ushort8v v = *(const ushort8v*)&R[(size_t)wid * SS + (cl << 3)];
#pragma unroll
        for (int r = 0; r < 8; ++r) acc0[r] += bf16tof(v[r]);
    }
    if (MODE == 2) {
        float* o = &Df[(size_t)wid * FD + (cl << 3)];
        *(float4*)o       = make_float4(acc0[0], acc0[1], acc0[2], acc0[3]);
        *(float4*)(o + 4) = make_float4(acc0[4], acc0[5], acc0[6], acc0[7]);
    } else {
        ushort8v o;
#pragma unroll
        for (int r = 0; r < 8; ++r) o[r] = bf16rn(acc0[r]);
        *(ushort8v*)&D[(size_t)wid * FD + (cl << 3)] = o;
    }
}

// ------- MFMA GEMM: A bf16, B = BT planes (1: bf16, 2: fp24 hi/lo) -------
// C = A*(sum of B planes)^T (+bias). DUALK=true: A=[A1|A2], B=[B1|B2] along K.
// DUALK=false: A=A1 (KK=K1); B rows r<NR1 -> B1[r] else B2[r-NR1] (NR1 % 128 == 0).
// 128x128 tile, 4 waves. LDS = 2 x (1+BT)*8KB buffers. Per step: ds_read frags of
// cur -> issue stage of nxt (reads precede writes: no forced vmcnt) -> MFMA ->
// ONE __syncthreads (implicit vmcnt(0) lands after compute). Bijective XCD-chunk
// swizzle (m204). Output: Cf (f32) if non-null, else Ch bf16 (+ optional Cl plane).
#define GBM 128
#define GBN 128

template<bool DUALK, int BT>
__global__ __launch_bounds__(256) void gemm6(
    const u16* __restrict__ A1, const u16* __restrict__ A2,
    const u16* __restrict__ B1h, const u16* __restrict__ B1l,
    const u16* __restrict__ B2h, const u16* __restrict__ B2l,
    const float* __restrict__ biasA, const float* __restrict__ biasB,
    float* __restrict__ Cf, u16* __restrict__ Ch, u16* __restrict__ Cl,
    int M, int K1, int NR1, int ldc, int doRelu)
{
    constexpr int NP = 1 + BT;            // LDS planes: A, Bh[, Bl]
    constexpr int NCH = 2 * NP;           // staged chunks per thread
    constexpr int BUF = NP * 4096;        // u16 per buffer
    __shared__ u16 lds[2 * BUF];

    const int tid = threadIdx.x;
    const int l = tid & 63, w = tid >> 6;
    const int wm = w >> 1, wn = w & 1;
    const int lane15 = l & 15, slot = l >> 4;

    // ---- bijective XCD-chunk swizzle (m204) ----
    const int nwg = gridDim.x * gridDim.y;
    const int bid = blockIdx.y * gridDim.x + blockIdx.x;
    const int q = nwg >> 3, r8 = nwg & 7;
    const int xcd = bid & 7, v = bid >> 3;
    const int sw = (xcd < r8) ? xcd * (q + 1) + v : r8 * (q + 1) + (xcd - r8) * q + v;
    const int row0 = (sw / gridDim.x) * GBM;
    const int col0 = (sw % gridDim.x) * GBN;

    const int KK = DUALK ? 2 * K1 : K1;
    const int nsteps = KK / 32;

    // ---- staging precompute: NP planes x 512 chunks, NCH per thread ----
    const u16* q1[NCH]; const u16* q2[NCH]; int lim[NCH]; int dstoff[NCH];
#pragma unroll
    for (int i = 0; i < NCH; ++i) {
        int idx0  = i * 256 + (tid & ~63);      // wave-uniform
        int p     = idx0 >> 9;                  // plane 0:A 1:Bh 2:Bl
        int cbase = idx0 & 511;
        int c  = cbase + l;                     // per-lane chunk
        int rw = c >> 2, ch = c & 3;
        int cpk = (ch ^ ((rw >> 1) & 3)) << 3;  // swizzled source k-offset (u16)
        lim[i]    = K1 - cpk;
        dstoff[i] = (p << 12) + (cbase << 3);
        const u16 *b1, *b2; int g;
        if (p == 0) {
            b1 = A1; b2 = A2 - K1;
            g = min(row0 + rw, M - 1);
        } else {
            const u16* h1 = (p == 1) ? B1h : B1l;
            const u16* h2 = (p == 1) ? B2h : B2l;
            if (DUALK) { b1 = h1; b2 = h2 - K1; g = col0 + rw; }
            else {
                bool sec = (col0 >= NR1);
                b1 = sec ? h2 : h1; b2 = b1;
                g = col0 + rw - (sec ? NR1 : 0);
            }
        }
        q1[i] = b1 + g * K1 + cpk;
        q2[i] = b2 + g * K1 + cpk;
    }

    f32x4 acc[4][4] = {};

    // prologue: stage tile 0 into buffer 0
#pragma unroll
    for (int i = 0; i < NCH; ++i) gload_lds16(q1[i], lds + dstoff[i]);
    __syncthreads();

    int cur = 0;
    for (int step = 0; step < nsteps; ++step) {
        const u16* cb = lds + cur * BUF;
        // ---- 1. ds_read all fragments of cur into registers ----
        short8v av[4], bh[4], bl[4];
#pragma unroll
        for (int bi = 0; bi < 4; ++bi) {
            int r = wm * 64 + bi * 16 + lane15;
            int j = slot ^ ((r >> 1) & 3);
            av[bi] = *(const short8v*)&cb[r * 32 + j * 8];
        }
#pragma unroll
        for (int bj = 0; bj < 4; ++bj) {
            int c = wn * 64 + bj * 16 + lane15;
            int j = slot ^ ((c >> 1) & 3);
            bh[bj] = *(const short8v*)&cb[4096 + c * 32 + j * 8];
            if (BT == 2) bl[bj] = *(const short8v*)&cb[8192 + c * 32 + j * 8];
        }
        // ---- 2. issue next tile's stage into nxt (flies under the MFMAs) ----
        if (step + 1 < nsteps) {
            int kk0 = (step + 1) * 32;
            u16* nb = lds + (cur ^ 1) * BUF;
#pragma unroll
            for (int i = 0; i < NCH; ++i) {
                const u16* src = (DUALK && kk0 >= lim[i]) ? q2[i] : q1[i];
                gload_lds16(src + kk0, nb + dstoff[i]);
            }
        }
        // ---- 3. MFMA (register-only; waits lgkmcnt for the ds_reads) ----
#pragma unroll
        for (int bj = 0; bj < 4; ++bj)
#pragma unroll
            for (int bi = 0; bi < 4; ++bi) {
                acc[bi][bj] = __builtin_amdgcn_mfma_f32_16x16x32_bf16(av[bi], bh[bj], acc[bi][bj], 0, 0, 0);
                if (BT == 2)
                    acc[bi][bj] = __builtin_amdgcn_mfma_f32_16x16x32_bf16(av[bi], bl[bj], acc[bi][bj], 0, 0, 0);
            }
        // ---- 4. one barrier: drains this step's stage loads after compute ----
        __syncthreads();
        cur ^= 1;
    }

    // ---- epilogue: C/D layout col=lane&15, row=slot*4+q ----
#pragma unroll
    for (int bj = 0; bj < 4; ++bj) {
        int cc = col0 + wn * 64 + bj * 16 + lane15;
        float bv = (cc < NR1) ? (biasA ? biasA[cc] : 0.f)
                              : (biasB ? biasB[cc - NR1] : 0.f);
#pragma unroll
        for (int bi = 0; bi < 4; ++bi) {
            int rbase = row0 + wm * 64 + bi * 16 + slot * 4;
#pragma unroll
            for (int qq = 0; qq < 4; ++qq) {
                int rr = rbase + qq;
                if (rr < M) {
                    float o = acc[bi][bj][qq] + bv;
                    if (doRelu) o = fmaxf(o, 0.f);
                    if (Cf) {
                        Cf[(size_t)rr * ldc + cc] = o;
                    } else {
                        u16 h = bf16rn(o);
                        Ch[(size_t)rr * ldc + cc] = h;
                        if (Cl) Cl[(size_t)rr * ldc + cc] = bf16rn(o - bf16tof(h));
                    }
                }
            }
        }
    }
}

// ---------------- GraphNorm (F = 256) single-plane ----------------
__global__ __launch_bounds__(256) void colstats_sp(const u16* __restrict__ H,
                                                   float* __restrict__ sums,
                                                   float* __restrict__ sqs, int N) {
    int f = threadIdx.x;
    float s = 0.f, q = 0.f;
    for (int i = blockIdx.x; i < N; i += gridDim.x) {
        float v = bf16tof(H[(size_t)i * 256 + f]);
        s += v;
        q = fmaf(v, v, q);
    }
    atomicAdd(&sums[f], s);
    atomicAdd(&sqs[f], q);
}

__global__ void norm_prep(const float* __restrict__ sums, const float* __restrict__ sqs,
                          const float* __restrict__ gw, const float* __restrict__ gb,
                          const float* __restrict__ gms, float* __restrict__ scaleF,
                          float* __restrict__ shiftF, float invN) {
    int f = threadIdx.x;  // 256 threads
    float mu  = sums[f] * invN;
    float ex2 = sqs[f] * invN;
    float a   = gms[f] * mu;
    float var = ex2 - 2.f * a * mu + a * a;
    float inv = rsqrtf(var + 1e-5f);
    float sc  = gw[f] * inv;
    scaleF[f] = sc;
    shiftF[f] = gb[f] - a * sc;
}

__global__ __launch_bounds__(256) void norm_apply_sp(
    u16* __restrict__ H, const float* __restrict__ scaleF,
    const float* __restrict__ shiftF, int n8) {
    int i = blockIdx.x * 256 + threadIdx.x;
    if (i >= n8) return;
    int f0 = (i & 31) << 3;   // 256 feats = 32 chunks of 8
    ushort8v h = *(const ushort8v*)&H[(size_t)i * 8];
    ushort8v o;
#pragma unroll
    for (int r = 0; r < 8; ++r) {
        float v = fmaxf(fmaf(bf16tof(h[r]), scaleF[f0 + r], shiftF[f0 + r]), 0.f);
        o[r] = bf16rn(v);
    }
    *(ushort8v*)&H[(size_t)i * 8] = o;
}

// ---------------- launch ----------------
extern "C" void kernel_launch(void* const* d_in, const int* in_sizes, int n_in,
                              void* d_out, int out_size, void* d_ws, size_t ws_size,
                              hipStream_t stream) {
    const float* x   = (const float*)d_in[0];
    const int*   ei  = (const int*)d_in[1];
    const float* ea  = (const float*)d_in[2];
    const float* Wr1 = (const float*)d_in[3];
    const float* b1  = (const float*)d_in[4];
    const float* Wo1 = (const float*)d_in[5];
    const float* Wr2 = (const float*)d_in[6];
    const float* b2  = (const float*)d_in[7];
    const float* Wo2 = (const float*)d_in[8];
    const float* Wr3 = (const float*)d_in[9];
    const float* b3  = (const float*)d_in[10];
    const float* Wo3 = (const float*)d_in[11];
    const float* Wr4 = (const float*)d_in[12];
    const float* b4  = (const float*)d_in[13];
    const float* Wo4 = (const float*)d_in[14];
    const float* gw  = (const float*)d_in[15];
    const float* gb  = (const float*)d_in[16];
    const float* gms = (const float*)d_in[17];

    const int Nn = in_sizes[0] / F_IN;   // 50000
    const int E  = in_sizes[1] / 2;      // 400000
    const int* src = ei;
    const int* dst = ei + E;

    char* wp = (char*)d_ws;
    auto alloc = [&](size_t bytes) -> void* {
        void* p = (void*)wp;
        wp += (bytes + 255) & ~(size_t)255;
        return p;
    };
    int*   counts   = (int*)alloc((size_t)Nn * 4);
    int*   rowptr   = (int*)alloc((size_t)(Nn + 1) * 4);
    int*   fillhead = (int*)alloc((size_t)Nn * 4);
    int*   col      = (int*)alloc((size_t)E * 4);
    float* wv       = (float*)alloc((size_t)E * 4);
    float* stats    = (float*)alloc(1024 * 4);
    float* sums = stats, *sqs = stats + 256, *scaleF = stats + 512, *shiftF = stats + 768;
    int*   bsum     = (int*)alloc(256 * 4);
    int*   boff     = (int*)alloc(256 * 4);
    // weights: L1-L3 single bf16 plane, L4 fp24 hi/lo
    u16* wr1 = (u16*)alloc(2u * 256 * 144);
    u16* wo1 = (u16*)alloc(2u * 256 * 144);
    u16* wr2 = (u16*)alloc(2u * 512 * 256);
    u16* wo2 = (u16*)alloc(2u * 512 * 256);
    u16* wr3 = (u16*)alloc(2u * 256 * 512);
    u16* wo3 = (u16*)alloc(2u * 256 * 512);
    u16* wr4h = (u16*)alloc(2u * 128 * 256); u16* wr4l = (u16*)alloc(2u * 128 * 256);
    u16* wo4h = (u16*)alloc(2u * 128 * 256); u16* wo4l = (u16*)alloc(2u * 128 * 256);

    // ---- lifetime-packed region (u16 units), Nn*1168*2 B = 116.8 MB ----
    // live:  X[0,144) | AG[144,400) | H1[400,656) | H2[656,1168)
    // reuse: Y3 -> [0,512)    (X,AG,H1 dead after GEMM2)
    //        H3 -> [656,912)  (H2 dead after GEMM3)
    //        Y4 -> [0,256)    (Y3 dead after L3 aggregate)
    u16* big = (u16*)alloc((size_t)Nn * 1168 * 2);
    const size_t NS = (size_t)Nn;
    u16* Xb  = big;
    u16* AG  = big + NS * 144;
    u16* H1  = big + NS * 400;
    u16* H2  = big + NS * 656;
    u16* Y3  = big;
    u16* H3  = big + NS * 656;
    u16* Y4  = big;

    const int TB = 256;
    // CSR build (parallel scan)
    int nbScan = (Nn + SCB - 1) / SCB;   // 25
    zero_i32<<<(Nn + TB - 1) / TB, TB, 0, stream>>>(counts, Nn);
    count_edges<<<(E + TB - 1) / TB, TB, 0, stream>>>(dst, counts, E);
    scan_partial<<<nbScan, TB, 0, stream>>>(counts, rowptr, bsum, Nn);
    scan_tops<<<1, TB, 0, stream>>>(bsum, boff, nbScan);
    scan_add<<<(Nn + 1 + TB - 1) / TB, TB, 0, stream>>>(rowptr, fillhead, boff, Nn, E);
    fill_edges<<<(E + TB - 1) / TB, TB, 0, stream>>>(src, dst, ea, fillhead, col, wv, E);

    // conversions
    int nx = Nn * F_IN;
    conv_bf<<<(nx + 255) / 256, 256, 0, stream>>>(x, Xb, nx);
    struct BC { const float* s; u16* d; int n; } bc[6] = {
        {Wr1, wr1, 256 * 144}, {Wo1, wo1, 256 * 144},
        {Wr2, wr2, 512 * 256}, {Wo2, wo2, 512 * 256},
        {Wr3, wr3, 256 * 512}, {Wo3, wo3, 256 * 512}};
    for (int i = 0; i < 6; ++i)
        conv_bf<<<(bc[i].n + 255) / 256, 256, 0, stream>>>(bc[i].s, bc[i].d, bc[i].n);
    conv_hl<<<(128 * 256 + 255) / 256, 256, 0, stream>>>(Wr4, wr4h, wr4l, 128 * 256);
    conv_hl<<<(128 * 256 + 255) / 256, 256, 0, stream>>>(Wo4, wo4h, wo4l, 128 * 256);

    int mB = (Nn + GBM - 1) / GBM;              // 391
    int g3 = (((Nn + 2) / 3) + 3) / 4;          // 3 nodes/wave grids
    int g2 = (((Nn + 1) / 2) + 3) / 4;          // 2 nodes/wave grids
    int g4 = (((Nn + 3) / 4) + 3) / 4;          // 4 nodes/wave grids

    // Layer 1 (aggregate-first): AG = agg(X); H1 = relu([AG|X]*[Wr1|Wo1]^T + b1)
    aggregate_sp<18, 3, 0><<<g3, TB, 0, stream>>>(Xb, 144, rowptr, col, wv,
                                                  nullptr, AG, nullptr, 144, Nn);
    gemm6<true, 1><<<dim3(2, mB), 256, 0, stream>>>(AG, Xb, wr1, nullptr, wo1, nullptr,
                                                    b1, nullptr, nullptr, H1, nullptr,
                                                    Nn, 144, 256, 256, 1);
    // Layer 2 (aggregate-first): AG = agg(H1); H2 = relu([AG|H1]*[Wr2|Wo2]^T + b2)
    aggregate_sp<32, 2, 0><<<g2, TB, 0, stream>>>(H1, 256, rowptr, col, wv,
                                                  nullptr, AG, nullptr, 256, Nn);
    gemm6<true, 1><<<dim3(4, mB), 256, 0, stream>>>(AG, H1, wr2, nullptr, wo2, nullptr,
                                                    b2, nullptr, nullptr, H2, nullptr,
                                                    Nn, 256, 512, 512, 1);
    // Layer 3 (transform-first): Y3 = [H2*Wr3^T | H2*Wo3^T + b3]; H3 = agg(Yrel)+Yroot
    gemm6<false, 1><<<dim3(4, mB), 256, 0, stream>>>(H2, H2, wr3, nullptr, wo3, nullptr,
                                                     nullptr, b3, nullptr, Y3, nullptr,
                                                     Nn, 512, 256, 512, 0);
    aggregate_sp<32, 2, 1><<<g2, TB, 0, stream>>>(Y3, 512, rowptr, col, wv,
                                                  Y3 + 256, H3, nullptr, 256, Nn);
    // GraphNorm + relu in place on H3
    zero_f32<<<2, TB, 0, stream>>>(stats, 512);
    colstats_sp<<<256, TB, 0, stream>>>(H3, sums, sqs, Nn);
    norm_prep<<<1, 256, 0, stream>>>(sums, sqs, gw, gb, gms, scaleF, shiftF, 1.0f / Nn);
    norm_apply_sp<<<(Nn * 32 + TB - 1) / TB, TB, 0, stream>>>(H3, scaleF, shiftF, Nn * 32);
    // Layer 4 (transform-first, fp24 weights): Y4 = [H3*Wr4^T | H3*Wo4^T + b4] (bf16);
    // out = agg(Y4rel) + Y4root (f32)
    gemm6<false, 2><<<dim3(2, mB), 256, 0, stream>>>(H3, H3, wr4h, wr4l, wo4h, wo4l,
                                                     nullptr, b4, nullptr, Y4, nullptr,
                                                     Nn, 256, 128, 256, 0);
    aggregate_sp<16, 4, 2><<<g4, TB, 0, stream>>>(Y4, 256, rowptr, col, wv,
                                                  Y4 + 128, nullptr, (float*)d_out, 128, Nn);
}

// Round 13
// 404.505 us; speedup vs baseline: 4.1408x; 1.2264x over previous
//
#include <hip/hip_runtime.h>

#define F_IN 144
typedef __attribute__((ext_vector_type(8))) short short8v;
typedef __attribute__((ext_vector_type(8))) unsigned short ushort8v;
typedef __attribute__((ext_vector_type(4))) float f32x4;
typedef unsigned short u16;

// ---------------- bf16 helpers ----------------
__device__ __forceinline__ u16 bf16rn(float x) {
    union { float f; unsigned u; } a; a.f = x;
    return (u16)((a.u + 0x7FFFu + ((a.u >> 16) & 1u)) >> 16);
}
__device__ __forceinline__ float bf16tof(u16 h) {
    union { float f; unsigned u; } a; a.u = ((unsigned)h) << 16;
    return a.f;
}
__device__ __forceinline__ void gload_lds16(const u16* g, u16* s) {
    __builtin_amdgcn_global_load_lds(
        (const __attribute__((address_space(1))) void*)g,
        (__attribute__((address_space(3))) void*)s, 16, 0, 0);
}

// ---------------- utility ----------------
__global__ void zero_i32(int* __restrict__ p, int n) {
    int i = blockIdx.x * blockDim.x + threadIdx.x;
    if (i < n) p[i] = 0;
}
__global__ void zero_f32(float* __restrict__ p, int n) {
    int i = blockIdx.x * blockDim.x + threadIdx.x;
    if (i < n) p[i] = 0.f;
}
// weights: f32 -> bf16 hi/lo (fp24)
__global__ void conv_hl(const float* __restrict__ src, u16* __restrict__ dh,
                        u16* __restrict__ dl, int n) {
    int i = blockIdx.x * 256 + threadIdx.x;
    if (i < n) {
        float v = src[i];
        u16 h = bf16rn(v);
        dh[i] = h;
        dl[i] = bf16rn(v - bf16tof(h));
    }
}
// f32 -> bf16 single plane
__global__ void conv_bf(const float* __restrict__ src, u16* __restrict__ d, int n) {
    int i = blockIdx.x * 256 + threadIdx.x;
    if (i < n) d[i] = bf16rn(src[i]);
}

// ---------------- CSR build ----------------
__global__ void count_edges(const int* __restrict__ dst, int* __restrict__ counts, int E) {
    int e = blockIdx.x * blockDim.x + threadIdx.x;
    if (e < E) atomicAdd(&counts[dst[e]], 1);
}

// 3-pass parallel exclusive scan (2048 elements per block)
#define SCB 2048
__global__ __launch_bounds__(256) void scan_partial(const int* __restrict__ counts,
                                                    int* __restrict__ rowptr,
                                                    int* __restrict__ bsum, int N) {
    __shared__ int ls[256];
    int t = threadIdx.x;
    int base = blockIdx.x * SCB + t * 8;
    int v[8]; int s = 0;
#pragma unroll
    for (int j = 0; j < 8; ++j) {
        int i = base + j;
        v[j] = (i < N) ? counts[i] : 0;
        s += v[j];
    }
    ls[t] = s;
    __syncthreads();
    for (int off = 1; off < 256; off <<= 1) {
        int x = (t >= off) ? ls[t - off] : 0;
        __syncthreads();
        ls[t] += x;
        __syncthreads();
    }
    int run = (t == 0) ? 0 : ls[t - 1];
#pragma unroll
    for (int j = 0; j < 8; ++j) {
        int i = base + j;
        if (i < N) rowptr[i] = run;
        run += v[j];
    }
    if (t == 255) bsum[blockIdx.x] = ls[255];
}

__global__ __launch_bounds__(256) void scan_tops(const int* __restrict__ bsum,
                                                 int* __restrict__ boff, int nb) {
    __shared__ int ls[256];
    int t = threadIdx.x;
    ls[t] = (t < nb) ? bsum[t] : 0;
    __syncthreads();
    for (int off = 1; off < 256; off <<= 1) {
        int x = (t >= off) ? ls[t - off] : 0;
        __syncthreads();
        ls[t] += x;
        __syncthreads();
    }
    boff[t] = (t == 0) ? 0 : ls[t - 1];   // exclusive block prefix
}

__global__ void scan_add(int* __restrict__ rowptr, int* __restrict__ fillhead,
                         const int* __restrict__ boff, int N, int E) {
    int i = blockIdx.x * 256 + threadIdx.x;
    if (i < N) {
        int r = rowptr[i] + boff[i >> 11];   // SCB = 2048 = 1<<11
        rowptr[i] = r;
        fillhead[i] = r;
    }
    if (i == N) rowptr[N] = E;
}

__global__ void fill_edges(const int* __restrict__ src, const int* __restrict__ dst,
                           const float* __restrict__ ea, int* __restrict__ fillhead,
                           int* __restrict__ col, float* __restrict__ wv, int E) {
    int e = blockIdx.x * blockDim.x + threadIdx.x;
    if (e < E) {
        int d = dst[e];
        int pos = atomicAdd(&fillhead[d], 1);
        col[pos] = src[e];
        wv[pos]  = ea[e];
    }
}

// ------------- single-plane aggregation, NPW nodes per wave -------------
// MODE 0: D = agg(S) (bf16). MODE 1: D = agg(S) + R (bf16). MODE 2: Df = agg(S) + R (f32).
// Edge loop unrolled x4 (4 independent gathers in flight).
template<int NC, int NPW, int MODE>
__global__ __launch_bounds__(256) void aggregate_sp(
    const u16* __restrict__ S, int SS,
    const int* __restrict__ rowptr, const int* __restrict__ col,
    const float* __restrict__ wv,
    const u16* __restrict__ R,
    u16* __restrict__ D, float* __restrict__ Df, int FD, int N)
{
    int wav  = (int)((blockIdx.x * 256 + threadIdx.x) >> 6);
    int lane = threadIdx.x & 63;
    int sub  = lane / NC;
    int cl   = lane % NC;
    int wid  = wav * NPW + sub;
    if (sub >= NPW || wid >= N) return;
    float acc0[8] = {}, acc1[8] = {}, acc2[8] = {}, acc3[8] = {};
    int beg = rowptr[wid], end = rowptr[wid + 1];
    int e = beg;
    for (; e + 4 <= end; e += 4) {
        float w0 = wv[e], w1 = wv[e + 1], w2 = wv[e + 2], w3 = wv[e + 3];
        int   c0 = col[e], c1 = col[e + 1], c2 = col[e + 2], c3 = col[e + 3];
        ushort8v v0 = *(const ushort8v*)&S[(size_t)c0 * SS + (cl << 3)];
        ushort8v v1 = *(const ushort8v*)&S[(size_t)c1 * SS + (cl << 3)];
        ushort8v v2 = *(const ushort8v*)&S[(size_t)c2 * SS + (cl << 3)];
        ushort8v v3 = *(const ushort8v*)&S[(size_t)c3 * SS + (cl << 3)];
#pragma unroll
        for (int r = 0; r < 8; ++r) {
            acc0[r] = fmaf(w0, bf16tof(v0[r]), acc0[r]);
            acc1[r] = fmaf(w1, bf16tof(v1[r]), acc1[r]);
            acc2[r] = fmaf(w2, bf16tof(v2[r]), acc2[r]);
            acc3[r] = fmaf(w3, bf16tof(v3[r]), acc3[r]);
        }
    }
    for (; e < end; ++e) {
        float w0 = wv[e];
        ushort8v v0 = *(const ushort8v*)&S[(size_t)col[e] * SS + (cl << 3)];
#pragma unroll
        for (int r = 0; r < 8; ++r) acc0[r] = fmaf(w0, bf16tof(v0[r]), acc0[r]);
    }
#pragma unroll
    for (int r = 0; r < 8; ++r) acc0[r] += (acc1[r] + acc2[r]) + acc3[r];
    if (MODE >= 1) {
        ushort8v v = *(const ushort8v*)&R[(size_t)wid * SS + (cl << 3)];
#pragma unroll
        for (int r = 0; r < 8; ++r) acc0[r] += bf16tof(v[r]);
    }
    if (MODE == 2) {
        float* o = &Df[(size_t)wid * FD + (cl << 3)];
        *(float4*)o       = make_float4(acc0[0], acc0[1], acc0[2], acc0[3]);
        *(float4*)(o + 4) = make_float4(acc0[4], acc0[5], acc0[6], acc0[7]);
    } else {
        ushort8v o;
#pragma unroll
        for (int r = 0; r < 8; ++r) o[r] = bf16rn(acc0[r]);
        *(ushort8v*)&D[(size_t)wid * FD + (cl << 3)] = o;
    }
}

// ------- MFMA GEMM: A bf16, B = BT planes (1: bf16, 2: fp24 hi/lo) -------
// C = A*(sum of B planes)^T (+bias), bf16 out via LDS-coalesced epilogue.
// DUALK=true: A=[A1|A2], B=[B1|B2] along K (KK=2*K1).
// DUALK=false: A=A1 (KK=K1); B rows r<NR1 -> B1[r] else B2[r-NR1] (NR1 % 128 == 0).
// 128x128 tile, 4 waves. LDS = 3 x (1+BT)*8KB buffers, 3-deep pipeline:
// step t reads buf[t%3], issues stage of tile t+2 into buf[(t+2)%3], MFMAs, then
// s_waitcnt vmcnt(NCH) (only tile t+1's loads must land; t+2's stay in flight) +
// raw s_barrier + sched_barrier(0). Never vmcnt(0) in steady state (T3/T4).
// Bijective XCD-chunk swizzle (m204). Epilogue: acc -> LDS [128][132] -> 256B-row
// coalesced ushort8 stores (kills the 2.4x write amplification of scalar u16 stores).
#define GBM 128
#define GBN 128

template<bool DUALK, int BT>
__global__ __launch_bounds__(256) void gemm7(
    const u16* __restrict__ A1, const u16* __restrict__ A2,
    const u16* __restrict__ B1h, const u16* __restrict__ B1l,
    const u16* __restrict__ B2h, const u16* __restrict__ B2l,
    const float* __restrict__ biasA, const float* __restrict__ biasB,
    u16* __restrict__ Ch,
    int M, int K1, int NR1, int ldc, int doRelu)
{
    constexpr int NP  = 1 + BT;           // LDS planes: A, Bh[, Bl]
    constexpr int NCH = 2 * NP;           // staged chunks (loads) per thread per tile
    constexpr int BUF = NP * 4096;        // u16 per buffer
    __shared__ u16 lds[3 * BUF];          // BT=1: 48KB, BT=2: 72KB (>= 33792 epilogue tile)

    const int tid = threadIdx.x;
    const int l = tid & 63, w = tid >> 6;
    const int wm = w >> 1, wn = w & 1;
    const int lane15 = l & 15, slot = l >> 4;

    // ---- bijective XCD-chunk swizzle (m204) ----
    const int nwg = gridDim.x * gridDim.y;
    const int bid = blockIdx.y * gridDim.x + blockIdx.x;
    const int q = nwg >> 3, r8 = nwg & 7;
    const int xcd = bid & 7, v = bid >> 3;
    const int sw = (xcd < r8) ? xcd * (q + 1) + v : r8 * (q + 1) + (xcd - r8) * q + v;
    const int row0 = (sw / gridDim.x) * GBM;
    const int col0 = (sw % gridDim.x) * GBN;

    const int KK = DUALK ? 2 * K1 : K1;
    const int nsteps = KK / 32;

    // ---- staging precompute: NP planes x 512 chunks, NCH per thread ----
    const u16* q1[NCH]; const u16* q2[NCH]; int lim[NCH]; int dstoff[NCH];
#pragma unroll
    for (int i = 0; i < NCH; ++i) {
        int idx0  = i * 256 + (tid & ~63);      // wave-uniform
        int p     = idx0 >> 9;                  // plane 0:A 1:Bh 2:Bl
        int cbase = idx0 & 511;
        int c  = cbase + l;                     // per-lane chunk
        int rw = c >> 2, ch = c & 3;
        int cpk = (ch ^ ((rw >> 1) & 3)) << 3;  // swizzled source k-offset (u16)
        lim[i]    = K1 - cpk;
        dstoff[i] = (p << 12) + (cbase << 3);
        const u16 *b1, *b2; int g;
        if (p == 0) {
            b1 = A1; b2 = A2 - K1;
            g = min(row0 + rw, M - 1);
        } else {
            const u16* h1 = (p == 1) ? B1h : B1l;
            const u16* h2 = (p == 1) ? B2h : B2l;
            if (DUALK) { b1 = h1; b2 = h2 - K1; g = col0 + rw; }
            else {
                bool sec = (col0 >= NR1);
                b1 = sec ? h2 : h1; b2 = b1;
                g = col0 + rw - (sec ? NR1 : 0);
            }
        }
        q1[i] = b1 + g * K1 + cpk;
        q2[i] = b2 + g * K1 + cpk;
    }

    auto stage = [&](u16* base, int kk0) {
#pragma unroll
        for (int i = 0; i < NCH; ++i) {
            const u16* s = (DUALK && kk0 >= lim[i]) ? q2[i] : q1[i];
            gload_lds16(s + kk0, base + dstoff[i]);
        }
    };

    f32x4 acc[4][4] = {};

    // ---- prologue: stage tiles 0 and 1 ----
    stage(lds, 0);
    if (nsteps > 1) {
        stage(lds + BUF, 32);
        asm volatile("s_waitcnt vmcnt(%0)" :: "n"(NCH) : "memory");  // tile0 landed
    } else {
        asm volatile("s_waitcnt vmcnt(0)" ::: "memory");
    }
    __builtin_amdgcn_s_barrier();
    __builtin_amdgcn_sched_barrier(0);

    int ro = 0, so = 2 * BUF;   // read offset (t%3), stage offset ((t+2)%3)
    for (int step = 0; step < nsteps; ++step) {
        const u16* cb = lds + ro;
        // ---- 1. ds_read fragments of current tile ----
        short8v av[4], bh[4], bl[4];
#pragma unroll
        for (int bi = 0; bi < 4; ++bi) {
            int r = wm * 64 + bi * 16 + lane15;
            int j = slot ^ ((r >> 1) & 3);
            av[bi] = *(const short8v*)&cb[r * 32 + j * 8];
        }
#pragma unroll
        for (int bj = 0; bj < 4; ++bj) {
            int c = wn * 64 + bj * 16 + lane15;
            int j = slot ^ ((c >> 1) & 3);
            bh[bj] = *(const short8v*)&cb[4096 + c * 32 + j * 8];
            if (BT == 2) bl[bj] = *(const short8v*)&cb[8192 + c * 32 + j * 8];
        }
        // ---- 2. issue stage of tile t+2 (stays in flight across the barrier) ----
        if (step + 2 < nsteps) stage(lds + so, (step + 2) * 32);
        // ---- 3. MFMA ----
#pragma unroll
        for (int bj = 0; bj < 4; ++bj)
#pragma unroll
            for (int bi = 0; bi < 4; ++bi) {
                acc[bi][bj] = __builtin_amdgcn_mfma_f32_16x16x32_bf16(av[bi], bh[bj], acc[bi][bj], 0, 0, 0);
                if (BT == 2)
                    acc[bi][bj] = __builtin_amdgcn_mfma_f32_16x16x32_bf16(av[bi], bl[bj], acc[bi][bj], 0, 0, 0);
            }
        // ---- 4. counted wait: only tile t+1's loads must land; t+2's keep flying ----
        if (step + 1 < nsteps) {
            if (step + 2 < nsteps)
                asm volatile("s_waitcnt vmcnt(%0)" :: "n"(NCH) : "memory");
            else
                asm volatile("s_waitcnt vmcnt(0)" ::: "memory");
            __builtin_amdgcn_s_barrier();
            __builtin_amdgcn_sched_barrier(0);
        }
        ro += BUF; if (ro == 3 * BUF) ro = 0;
        so += BUF; if (so == 3 * BUF) so = 0;
    }

    // ---- epilogue: acc -> LDS tile [128][132] -> coalesced 256B-row stores ----
    __syncthreads();               // all waves done with K-loop LDS before reuse
    u16* ct = lds;                 // 128 x 132 u16 = 33792 B
#pragma unroll
    for (int bj = 0; bj < 4; ++bj) {
        int cc = wn * 64 + bj * 16 + lane15;
        int gc = col0 + cc;
        float bv = (gc < NR1) ? (biasA ? biasA[gc] : 0.f)
                              : (biasB ? biasB[gc - NR1] : 0.f);
#pragma unroll
        for (int bi = 0; bi < 4; ++bi) {
            int rb = wm * 64 + bi * 16 + slot * 4;
#pragma unroll
            for (int qq = 0; qq < 4; ++qq) {
                float o = acc[bi][bj][qq] + bv;
                if (doRelu) o = fmaxf(o, 0.f);
                ct[(rb + qq) * 132 + cc] = bf16rn(o);
            }
        }
    }
    __syncthreads();
#pragma unroll
    for (int it = 0; it < 8; ++it) {
        int row = it * 16 + (tid >> 4);
        int c16 = (tid & 15) * 8;
        int gr = row0 + row;
        if (gr < M) {
            ushort8v vv = *(const ushort8v*)&ct[row * 132 + c16];
            *(ushort8v*)&Ch[(size_t)gr * ldc + col0 + c16] = vv;
        }
    }
}

// ---------------- GraphNorm (F = 256) single-plane ----------------
__global__ __launch_bounds__(256) void colstats_sp(const u16* __restrict__ H,
                                                   float* __restrict__ sums,
                                                   float* __restrict__ sqs, int N) {
    int f = threadIdx.x;
    float s = 0.f, q = 0.f;
    for (int i = blockIdx.x; i < N; i += gridDim.x) {
        float v = bf16tof(H[(size_t)i * 256 + f]);
        s += v;
        q = fmaf(v, v, q);
    }
    atomicAdd(&sums[f], s);
    atomicAdd(&sqs[f], q);
}

__global__ void norm_prep(const float* __restrict__ sums, const float* __restrict__ sqs,
                          const float* __restrict__ gw, const float* __restrict__ gb,
                          const float* __restrict__ gms, float* __restrict__ scaleF,
                          float* __restrict__ shiftF, float invN) {
    int f = threadIdx.x;  // 256 threads
    float mu  = sums[f] * invN;
    float ex2 = sqs[f] * invN;
    float a   = gms[f] * mu;
    float var = ex2 - 2.f * a * mu + a * a;
    float inv = rsqrtf(var + 1e-5f);
    float sc  = gw[f] * inv;
    scaleF[f] = sc;
    shiftF[f] = gb[f] - a * sc;
}

__global__ __launch_bounds__(256) void norm_apply_sp(
    u16* __restrict__ H, const float* __restrict__ scaleF,
    const float* __restrict__ shiftF, int n8) {
    int i = blockIdx.x * 256 + threadIdx.x;
    if (i >= n8) return;
    int f0 = (i & 31) << 3;   // 256 feats = 32 chunks of 8
    ushort8v h = *(const ushort8v*)&H[(size_t)i * 8];
    ushort8v o;
#pragma unroll
    for (int r = 0; r < 8; ++r) {
        float v = fmaxf(fmaf(bf16tof(h[r]), scaleF[f0 + r], shiftF[f0 + r]), 0.f);
        o[r] = bf16rn(v);
    }
    *(ushort8v*)&H[(size_t)i * 8] = o;
}

// ---------------- launch ----------------
extern "C" void kernel_launch(void* const* d_in, const int* in_sizes, int n_in,
                              void* d_out, int out_size, void* d_ws, size_t ws_size,
                              hipStream_t stream) {
    const float* x   = (const float*)d_in[0];
    const int*   ei  = (const int*)d_in[1];
    const float* ea  = (const float*)d_in[2];
    const float* Wr1 = (const float*)d_in[3];
    const float* b1  = (const float*)d_in[4];
    const float* Wo1 = (const float*)d_in[5];
    const float* Wr2 = (const float*)d_in[6];
    const float* b2  = (const float*)d_in[7];
    const float* Wo2 = (const float*)d_in[8];
    const float* Wr3 = (const float*)d_in[9];
    const float* b3  = (const float*)d_in[10];
    const float* Wo3 = (const float*)d_in[11];
    const float* Wr4 = (const float*)d_in[12];
    const float* b4  = (const float*)d_in[13];
    const float* Wo4 = (const float*)d_in[14];
    const float* gw  = (const float*)d_in[15];
    const float* gb  = (const float*)d_in[16];
    const float* gms = (const float*)d_in[17];

    const int Nn = in_sizes[0] / F_IN;   // 50000
    const int E  = in_sizes[1] / 2;      // 400000
    const int* src = ei;
    const int* dst = ei + E;

    char* wp = (char*)d_ws;
    auto alloc = [&](size_t bytes) -> void* {
        void* p = (void*)wp;
        wp += (bytes + 255) & ~(size_t)255;
        return p;
    };
    int*   counts   = (int*)alloc((size_t)Nn * 4);
    int*   rowptr   = (int*)alloc((size_t)(Nn + 1) * 4);
    int*   fillhead = (int*)alloc((size_t)Nn * 4);
    int*   col      = (int*)alloc((size_t)E * 4);
    float* wv       = (float*)alloc((size_t)E * 4);
    float* stats    = (float*)alloc(1024 * 4);
    float* sums = stats, *sqs = stats + 256, *scaleF = stats + 512, *shiftF = stats + 768;
    int*   bsum     = (int*)alloc(256 * 4);
    int*   boff     = (int*)alloc(256 * 4);
    // weights: L1-L3 single bf16 plane, L4 fp24 hi/lo
    u16* wr1 = (u16*)alloc(2u * 256 * 144);
    u16* wo1 = (u16*)alloc(2u * 256 * 144);
    u16* wr2 = (u16*)alloc(2u * 512 * 256);
    u16* wo2 = (u16*)alloc(2u * 512 * 256);
    u16* wr3 = (u16*)alloc(2u * 256 * 512);
    u16* wo3 = (u16*)alloc(2u * 256 * 512);
    u16* wr4h = (u16*)alloc(2u * 128 * 256); u16* wr4l = (u16*)alloc(2u * 128 * 256);
    u16* wo4h = (u16*)alloc(2u * 128 * 256); u16* wo4l = (u16*)alloc(2u * 128 * 256);

    // ---- lifetime-packed region (u16 units), Nn*1168*2 B = 116.8 MB ----
    // live:  X[0,144) | AG[144,400) | H1[400,656) | H2[656,1168)
    // reuse: Y3 -> [0,512)    (X,AG,H1 dead after GEMM2)
    //        H3 -> [656,912)  (H2 dead after GEMM3)
    //        Y4 -> [0,256)    (Y3 dead after L3 aggregate)
    u16* big = (u16*)alloc((size_t)Nn * 1168 * 2);
    const size_t NS = (size_t)Nn;
    u16* Xb  = big;
    u16* AG  = big + NS * 144;
    u16* H1  = big + NS * 400;
    u16* H2  = big + NS * 656;
    u16* Y3  = big;
    u16* H3  = big + NS * 656;
    u16* Y4  = big;

    const int TB = 256;
    // CSR build (parallel scan)
    int nbScan = (Nn + SCB - 1) / SCB;   // 25
    zero_i32<<<(Nn + TB - 1) / TB, TB, 0, stream>>>(counts, Nn);
    count_edges<<<(E + TB - 1) / TB, TB, 0, stream>>>(dst, counts, E);
    scan_partial<<<nbScan, TB, 0, stream>>>(counts, rowptr, bsum, Nn);
    scan_tops<<<1, TB, 0, stream>>>(bsum, boff, nbScan);
    scan_add<<<(Nn + 1 + TB - 1) / TB, TB, 0, stream>>>(rowptr, fillhead, boff, Nn, E);
    fill_edges<<<(E + TB - 1) / TB, TB, 0, stream>>>(src, dst, ea, fillhead, col, wv, E);

    // conversions
    int nx = Nn * F_IN;
    conv_bf<<<(nx + 255) / 256, 256, 0, stream>>>(x, Xb, nx);
    struct BC { const float* s; u16* d; int n; } bc[6] = {
        {Wr1, wr1, 256 * 144}, {Wo1, wo1, 256 * 144},
        {Wr2, wr2, 512 * 256}, {Wo2, wo2, 512 * 256},
        {Wr3, wr3, 256 * 512}, {Wo3, wo3, 256 * 512}};
    for (int i = 0; i < 6; ++i)
        conv_bf<<<(bc[i].n + 255) / 256, 256, 0, stream>>>(bc[i].s, bc[i].d, bc[i].n);
    conv_hl<<<(128 * 256 + 255) / 256, 256, 0, stream>>>(Wr4, wr4h, wr4l, 128 * 256);
    conv_hl<<<(128 * 256 + 255) / 256, 256, 0, stream>>>(Wo4, wo4h, wo4l, 128 * 256);

    int mB = (Nn + GBM - 1) / GBM;              // 391
    int g3 = (((Nn + 2) / 3) + 3) / 4;          // 3 nodes/wave grids
    int g2 = (((Nn + 1) / 2) + 3) / 4;          // 2 nodes/wave grids
    int g4 = (((Nn + 3) / 4) + 3) / 4;          // 4 nodes/wave grids

    // Layer 1 (aggregate-first): AG = agg(X); H1 = relu([AG|X]*[Wr1|Wo1]^T + b1)
    aggregate_sp<18, 3, 0><<<g3, TB, 0, stream>>>(Xb, 144, rowptr, col, wv,
                                                  nullptr, AG, nullptr, 144, Nn);
    gemm7<true, 1><<<dim3(2, mB), 256, 0, stream>>>(AG, Xb, wr1, nullptr, wo1, nullptr,
                                                    b1, nullptr, H1,
                                                    Nn, 144, 256, 256, 1);
    // Layer 2 (aggregate-first): AG = agg(H1); H2 = relu([AG|H1]*[Wr2|Wo2]^T + b2)
    aggregate_sp<32, 2, 0><<<g2, TB, 0, stream>>>(H1, 256, rowptr, col, wv,
                                                  nullptr, AG, nullptr, 256, Nn);
    gemm7<true, 1><<<dim3(4, mB), 256, 0, stream>>>(AG, H1, wr2, nullptr, wo2, nullptr,
                                                    b2, nullptr, H2,
                                                    Nn, 256, 512, 512, 1);
    // Layer 3 (transform-first): Y3 = [H2*Wr3^T | H2*Wo3^T + b3]; H3 = agg(Yrel)+Yroot
    gemm7<false, 1><<<dim3(4, mB), 256, 0, stream>>>(H2, H2, wr3, nullptr, wo3, nullptr,
                                                     nullptr, b3, Y3,
                                                     Nn, 512, 256, 512, 0);
    aggregate_sp<32, 2, 1><<<g2, TB, 0, stream>>>(Y3, 512, rowptr, col, wv,
                                                  Y3 + 256, H3, nullptr, 256, Nn);
    // GraphNorm + relu in place on H3
    zero_f32<<<2, TB, 0, stream>>>(stats, 512);
    colstats_sp<<<256, TB, 0, stream>>>(H3, sums, sqs, Nn);
    norm_prep<<<1, 256, 0, stream>>>(sums, sqs, gw, gb, gms, scaleF, shiftF, 1.0f / Nn);
    norm_apply_sp<<<(Nn * 32 + TB - 1) / TB, TB, 0, stream>>>(H3, scaleF, shiftF, Nn * 32);
    // Layer 4 (transform-first, fp24 weights): Y4 = [H3*Wr4^T | H3*Wo4^T + b4] (bf16);
    // out = agg(Y4rel) + Y4root (f32)
    gemm7<false, 2><<<dim3(2, mB), 256, 0, stream>>>(H3, H3, wr4h, wr4l, wo4h, wo4l,
                                                     nullptr, b4, Y4,
                                                     Nn, 256, 128, 256, 0);
    aggregate_sp<16, 4, 2><<<g4, TB, 0, stream>>>(Y4, 256, rowptr, col, wv,
                                                  Y4 + 128, nullptr, (float*)d_out, 128, Nn);
}

// Round 14
// 377.688 us; speedup vs baseline: 4.4348x; 1.0710x over previous
//
#include <hip/hip_runtime.h>

#define F_IN 144
typedef __attribute__((ext_vector_type(8))) short short8v;
typedef __attribute__((ext_vector_type(8))) unsigned short ushort8v;
typedef __attribute__((ext_vector_type(4))) float f32x4;
typedef unsigned short u16;

// ---------------- bf16 helpers ----------------
__device__ __forceinline__ u16 bf16rn(float x) {
    union { float f; unsigned u; } a; a.f = x;
    return (u16)((a.u + 0x7FFFu + ((a.u >> 16) & 1u)) >> 16);
}
__device__ __forceinline__ float bf16tof(u16 h) {
    union { float f; unsigned u; } a; a.u = ((unsigned)h) << 16;
    return a.f;
}
__device__ __forceinline__ void gload_lds16(const u16* g, u16* s) {
    __builtin_amdgcn_global_load_lds(
        (const __attribute__((address_space(1))) void*)g,
        (__attribute__((address_space(3))) void*)s, 16, 0, 0);
}

// ---------------- utility ----------------
__global__ void zero_i32(int* __restrict__ p, int n) {
    int i = blockIdx.x * blockDim.x + threadIdx.x;
    if (i < n) p[i] = 0;
}
__global__ void zero_f32(float* __restrict__ p, int n) {
    int i = blockIdx.x * blockDim.x + threadIdx.x;
    if (i < n) p[i] = 0.f;
}
// weights: f32 -> bf16 hi/lo (fp24)
__global__ void conv_hl(const float* __restrict__ src, u16* __restrict__ dh,
                        u16* __restrict__ dl, int n) {
    int i = blockIdx.x * 256 + threadIdx.x;
    if (i < n) {
        float v = src[i];
        u16 h = bf16rn(v);
        dh[i] = h;
        dl[i] = bf16rn(v - bf16tof(h));
    }
}
// f32 -> bf16 single plane
__global__ void conv_bf(const float* __restrict__ src, u16* __restrict__ d, int n) {
    int i = blockIdx.x * 256 + threadIdx.x;
    if (i < n) d[i] = bf16rn(src[i]);
}

// ---------------- CSR build ----------------
__global__ void count_edges(const int* __restrict__ dst, int* __restrict__ counts, int E) {
    int e = blockIdx.x * blockDim.x + threadIdx.x;
    if (e < E) atomicAdd(&counts[dst[e]], 1);
}

// 3-pass parallel exclusive scan (2048 elements per block)
#define SCB 2048
__global__ __launch_bounds__(256) void scan_partial(const int* __restrict__ counts,
                                                    int* __restrict__ rowptr,
                                                    int* __restrict__ bsum, int N) {
    __shared__ int ls[256];
    int t = threadIdx.x;
    int base = blockIdx.x * SCB + t * 8;
    int v[8]; int s = 0;
#pragma unroll
    for (int j = 0; j < 8; ++j) {
        int i = base + j;
        v[j] = (i < N) ? counts[i] : 0;
        s += v[j];
    }
    ls[t] = s;
    __syncthreads();
    for (int off = 1; off < 256; off <<= 1) {
        int x = (t >= off) ? ls[t - off] : 0;
        __syncthreads();
        ls[t] += x;
        __syncthreads();
    }
    int run = (t == 0) ? 0 : ls[t - 1];
#pragma unroll
    for (int j = 0; j < 8; ++j) {
        int i = base + j;
        if (i < N) rowptr[i] = run;
        run += v[j];
    }
    if (t == 255) bsum[blockIdx.x] = ls[255];
}

__global__ __launch_bounds__(256) void scan_tops(const int* __restrict__ bsum,
                                                 int* __restrict__ boff, int nb) {
    __shared__ int ls[256];
    int t = threadIdx.x;
    ls[t] = (t < nb) ? bsum[t] : 0;
    __syncthreads();
    for (int off = 1; off < 256; off <<= 1) {
        int x = (t >= off) ? ls[t - off] : 0;
        __syncthreads();
        ls[t] += x;
        __syncthreads();
    }
    boff[t] = (t == 0) ? 0 : ls[t - 1];   // exclusive block prefix
}

__global__ void scan_add(int* __restrict__ rowptr, int* __restrict__ fillhead,
                         const int* __restrict__ boff, int N, int E) {
    int i = blockIdx.x * 256 + threadIdx.x;
    if (i < N) {
        int r = rowptr[i] + boff[i >> 11];   // SCB = 2048 = 1<<11
        rowptr[i] = r;
        fillhead[i] = r;
    }
    if (i == N) rowptr[N] = E;
}

__global__ void fill_edges(const int* __restrict__ src, const int* __restrict__ dst,
                           const float* __restrict__ ea, int* __restrict__ fillhead,
                           int* __restrict__ col, float* __restrict__ wv, int E) {
    int e = blockIdx.x * blockDim.x + threadIdx.x;
    if (e < E) {
        int d = dst[e];
        int pos = atomicAdd(&fillhead[d], 1);
        col[pos] = src[e];
        wv[pos]  = ea[e];
    }
}

// ------------- single-plane aggregation, NPW nodes per wave -------------
// MODE 0: D = agg(S) (bf16). MODE 1: D = agg(S) + R (bf16). MODE 2: Df = agg(S) + R (f32).
// Edge loop unrolled x4 (4 independent gathers in flight).
template<int NC, int NPW, int MODE>
__global__ __launch_bounds__(256) void aggregate_sp(
    const u16* __restrict__ S, int SS,
    const int* __restrict__ rowptr, const int* __restrict__ col,
    const float* __restrict__ wv,
    const u16* __restrict__ R,
    u16* __restrict__ D, float* __restrict__ Df, int FD, int N)
{
    int wav  = (int)((blockIdx.x * 256 + threadIdx.x) >> 6);
    int lane = threadIdx.x & 63;
    int sub  = lane / NC;
    int cl   = lane % NC;
    int wid  = wav * NPW + sub;
    if (sub >= NPW || wid >= N) return;
    float acc0[8] = {}, acc1[8] = {}, acc2[8] = {}, acc3[8] = {};
    int beg = rowptr[wid], end = rowptr[wid + 1];
    int e = beg;
    for (; e + 4 <= end; e += 4) {
        float w0 = wv[e], w1 = wv[e + 1], w2 = wv[e + 2], w3 = wv[e + 3];
        int   c0 = col[e], c1 = col[e + 1], c2 = col[e + 2], c3 = col[e + 3];
        ushort8v v0 = *(const ushort8v*)&S[(size_t)c0 * SS + (cl << 3)];
        ushort8v v1 = *(const ushort8v*)&S[(size_t)c1 * SS + (cl << 3)];
        ushort8v v2 = *(const ushort8v*)&S[(size_t)c2 * SS + (cl << 3)];
        ushort8v v3 = *(const ushort8v*)&S[(size_t)c3 * SS + (cl << 3)];
#pragma unroll
        for (int r = 0; r < 8; ++r) {
            acc0[r] = fmaf(w0, bf16tof(v0[r]), acc0[r]);
            acc1[r] = fmaf(w1, bf16tof(v1[r]), acc1[r]);
            acc2[r] = fmaf(w2, bf16tof(v2[r]), acc2[r]);
            acc3[r] = fmaf(w3, bf16tof(v3[r]), acc3[r]);
        }
    }
    for (; e < end; ++e) {
        float w0 = wv[e];
        ushort8v v0 = *(const ushort8v*)&S[(size_t)col[e] * SS + (cl << 3)];
#pragma unroll
        for (int r = 0; r < 8; ++r) acc0[r] = fmaf(w0, bf16tof(v0[r]), acc0[r]);
    }
#pragma unroll
    for (int r = 0; r < 8; ++r) acc0[r] += (acc1[r] + acc2[r]) + acc3[r];
    if (MODE >= 1) {
        ushort8v v = *(const ushort8v*)&R[(size_t)wid * SS + (cl << 3)];
#pragma unroll
        for (int r = 0; r < 8; ++r) acc0[r] += bf16tof(v[r]);
    }
    if (MODE == 2) {
        float* o = &Df[(size_t)wid * FD + (cl << 3)];
        *(float4*)o       = make_float4(acc0[0], acc0[1], acc0[2], acc0[3]);
        *(float4*)(o + 4) = make_float4(acc0[4], acc0[5], acc0[6], acc0[7]);
    } else {
        ushort8v o;
#pragma unroll
        for (int r = 0; r < 8; ++r) o[r] = bf16rn(acc0[r]);
        *(ushort8v*)&D[(size_t)wid * FD + (cl << 3)] = o;
    }
}

// ------- MFMA GEMM: A bf16, B = BT planes (1: bf16, 2: fp24 hi/lo) -------
// C = A*(sum of B planes)^T (+bias), bf16 out via LDS-coalesced epilogue.
// DUALK=true: A=[A1|A2], B=[B1|B2] along K (KK=2*K1).
// DUALK=false: A=A1 (KK=K1); B rows r<NR1 -> B1[r] else B2[r-NR1] (NR1 % 128 == 0).
// 128x128 tile, 4 waves. LDS = 3 x (1+BT)*8KB buffers, 3-deep pipeline:
// step t reads buf[t%3], issues stage of tile t+2 into buf[(t+2)%3], MFMAs, then
// s_waitcnt vmcnt(NCH) (only tile t+1's loads must land; t+2's stay in flight) +
// raw s_barrier + sched_barrier(0). Never vmcnt(0) in steady state (T3/T4).
// Bijective XCD-chunk swizzle (m204). Epilogue: acc -> LDS [128][132] -> 256B-row
// coalesced ushort8 stores.
#define GBM 128
#define GBN 128

template<bool DUALK, int BT>
__global__ __launch_bounds__(256) void gemm7(
    const u16* __restrict__ A1, const u16* __restrict__ A2,
    const u16* __restrict__ B1h, const u16* __restrict__ B1l,
    const u16* __restrict__ B2h, const u16* __restrict__ B2l,
    const float* __restrict__ biasA, const float* __restrict__ biasB,
    u16* __restrict__ Ch,
    int M, int K1, int NR1, int ldc, int doRelu)
{
    constexpr int NP  = 1 + BT;           // LDS planes: A, Bh[, Bl]
    constexpr int NCH = 2 * NP;           // staged chunks (loads) per thread per tile
    constexpr int BUF = NP * 4096;        // u16 per buffer
    __shared__ u16 lds[3 * BUF];          // BT=1: 48KB, BT=2: 72KB (>= 33792 epilogue tile)

    const int tid = threadIdx.x;
    const int l = tid & 63, w = tid >> 6;
    const int wm = w >> 1, wn = w & 1;
    const int lane15 = l & 15, slot = l >> 4;

    // ---- bijective XCD-chunk swizzle (m204) ----
    const int nwg = gridDim.x * gridDim.y;
    const int bid = blockIdx.y * gridDim.x + blockIdx.x;
    const int q = nwg >> 3, r8 = nwg & 7;
    const int xcd = bid & 7, v = bid >> 3;
    const int sw = (xcd < r8) ? xcd * (q + 1) + v : r8 * (q + 1) + (xcd - r8) * q + v;
    const int row0 = (sw / gridDim.x) * GBM;
    const int col0 = (sw % gridDim.x) * GBN;

    const int KK = DUALK ? 2 * K1 : K1;
    const int nsteps = KK / 32;

    // ---- staging precompute: NP planes x 512 chunks, NCH per thread ----
    const u16* q1[NCH]; const u16* q2[NCH]; int lim[NCH]; int dstoff[NCH];
#pragma unroll
    for (int i = 0; i < NCH; ++i) {
        int idx0  = i * 256 + (tid & ~63);      // wave-uniform
        int p     = idx0 >> 9;                  // plane 0:A 1:Bh 2:Bl
        int cbase = idx0 & 511;
        int c  = cbase + l;                     // per-lane chunk
        int rw = c >> 2, ch = c & 3;
        int cpk = (ch ^ ((rw >> 1) & 3)) << 3;  // swizzled source k-offset (u16)
        lim[i]    = K1 - cpk;
        dstoff[i] = (p << 12) + (cbase << 3);
        const u16 *b1, *b2; int g;
        if (p == 0) {
            b1 = A1; b2 = A2 - K1;
            g = min(row0 + rw, M - 1);
        } else {
            const u16* h1 = (p == 1) ? B1h : B1l;
            const u16* h2 = (p == 1) ? B2h : B2l;
            if (DUALK) { b1 = h1; b2 = h2 - K1; g = col0 + rw; }
            else {
                bool sec = (col0 >= NR1);
                b1 = sec ? h2 : h1; b2 = b1;
                g = col0 + rw - (sec ? NR1 : 0);
            }
        }
        q1[i] = b1 + g * K1 + cpk;
        q2[i] = b2 + g * K1 + cpk;
    }

    auto stage = [&](u16* base, int kk0) {
#pragma unroll
        for (int i = 0; i < NCH; ++i) {
            const u16* s = (DUALK && kk0 >= lim[i]) ? q2[i] : q1[i];
            gload_lds16(s + kk0, base + dstoff[i]);
        }
    };

    f32x4 acc[4][4] = {};

    // ---- prologue: stage tiles 0 and 1 ----
    stage(lds, 0);
    if (nsteps > 1) {
        stage(lds + BUF, 32);
        asm volatile("s_waitcnt vmcnt(%0)" :: "n"(NCH) : "memory");  // tile0 landed
    } else {
        asm volatile("s_waitcnt vmcnt(0)" ::: "memory");
    }
    __builtin_amdgcn_s_barrier();
    __builtin_amdgcn_sched_barrier(0);

    int ro = 0, so = 2 * BUF;   // read offset (t%3), stage offset ((t+2)%3)
    for (int step = 0; step < nsteps; ++step) {
        const u16* cb = lds + ro;
        // ---- 1. ds_read fragments of current tile ----
        short8v av[4], bh[4], bl[4];
#pragma unroll
        for (int bi = 0; bi < 4; ++bi) {
            int r = wm * 64 + bi * 16 + lane15;
            int j = slot ^ ((r >> 1) & 3);
            av[bi] = *(const short8v*)&cb[r * 32 + j * 8];
        }
#pragma unroll
        for (int bj = 0; bj < 4; ++bj) {
            int c = wn * 64 + bj * 16 + lane15;
            int j = slot ^ ((c >> 1) & 3);
            bh[bj] = *(const short8v*)&cb[4096 + c * 32 + j * 8];
            if (BT == 2) bl[bj] = *(const short8v*)&cb[8192 + c * 32 + j * 8];
        }
        // ---- 2. issue stage of tile t+2 (stays in flight across the barrier) ----
        if (step + 2 < nsteps) stage(lds + so, (step + 2) * 32);
        // ---- 3. MFMA ----
#pragma unroll
        for (int bj = 0; bj < 4; ++bj)
#pragma unroll
            for (int bi = 0; bi < 4; ++bi) {
                acc[bi][bj] = __builtin_amdgcn_mfma_f32_16x16x32_bf16(av[bi], bh[bj], acc[bi][bj], 0, 0, 0);
                if (BT == 2)
                    acc[bi][bj] = __builtin_amdgcn_mfma_f32_16x16x32_bf16(av[bi], bl[bj], acc[bi][bj], 0, 0, 0);
            }
        // ---- 4. counted wait: only tile t+1's loads must land; t+2's keep flying ----
        if (step + 1 < nsteps) {
            if (step + 2 < nsteps)
                asm volatile("s_waitcnt vmcnt(%0)" :: "n"(NCH) : "memory");
            else
                asm volatile("s_waitcnt vmcnt(0)" ::: "memory");
            __builtin_amdgcn_s_barrier();
            __builtin_amdgcn_sched_barrier(0);
        }
        ro += BUF; if (ro == 3 * BUF) ro = 0;
        so += BUF; if (so == 3 * BUF) so = 0;
    }

    // ---- epilogue: acc -> LDS tile [128][132] -> coalesced 256B-row stores ----
    __syncthreads();               // all waves done with K-loop LDS before reuse
    u16* ct = lds;                 // 128 x 132 u16 = 33792 B
#pragma unroll
    for (int bj = 0; bj < 4; ++bj) {
        int cc = wn * 64 + bj * 16 + lane15;
        int gc = col0 + cc;
        float bv = (gc < NR1) ? (biasA ? biasA[gc] : 0.f)
                              : (biasB ? biasB[gc - NR1] : 0.f);
#pragma unroll
        for (int bi = 0; bi < 4; ++bi) {
            int rb = wm * 64 + bi * 16 + slot * 4;
#pragma unroll
            for (int qq = 0; qq < 4; ++qq) {
                float o = acc[bi][bj][qq] + bv;
                if (doRelu) o = fmaxf(o, 0.f);
                ct[(rb + qq) * 132 + cc] = bf16rn(o);
            }
        }
    }
    __syncthreads();
#pragma unroll
    for (int it = 0; it < 8; ++it) {
        int row = it * 16 + (tid >> 4);
        int c16 = (tid & 15) * 8;
        int gr = row0 + row;
        if (gr < M) {
            ushort8v vv = *(const ushort8v*)&ct[row * 132 + c16];
            *(ushort8v*)&Ch[(size_t)gr * ldc + col0 + c16] = vv;
        }
    }
}

// ---------------- GraphNorm stats (F = 256): 8 row-streams x 32 chunks / block ----
__global__ __launch_bounds__(256) void colstats2(const u16* __restrict__ H,
                                                 float* __restrict__ sums,
                                                 float* __restrict__ sqs, int N) {
    __shared__ float lsum[8][256];
    __shared__ float lsq[8][256];
    int t  = threadIdx.x;
    int g  = t >> 5;          // row-stream 0..7
    int cl = t & 31;          // feature chunk (8 feats)
    float s[8] = {}, q[8] = {};
    for (int row = blockIdx.x * 8 + g; row < N; row += gridDim.x * 8) {
        ushort8v v = *(const ushort8v*)&H[(size_t)row * 256 + (cl << 3)];
#pragma unroll
        for (int r = 0; r < 8; ++r) {
            float f = bf16tof(v[r]);
            s[r] += f;
            q[r] = fmaf(f, f, q[r]);
        }
    }
#pragma unroll
    for (int r = 0; r < 8; ++r) {
        lsum[g][(cl << 3) + r] = s[r];
        lsq[g][(cl << 3) + r]  = q[r];
    }
    __syncthreads();
    // thread t reduces feature t across the 8 streams
    float ts = 0.f, tq = 0.f;
#pragma unroll
    for (int gg = 0; gg < 8; ++gg) { ts += lsum[gg][t]; tq += lsq[gg][t]; }
    atomicAdd(&sums[t], ts);
    atomicAdd(&sqs[t], tq);
}

__global__ void norm_prep(const float* __restrict__ sums, const float* __restrict__ sqs,
                          const float* __restrict__ gw, const float* __restrict__ gb,
                          const float* __restrict__ gms, float* __restrict__ scaleF,
                          float* __restrict__ shiftF, float invN) {
    int f = threadIdx.x;  // 256 threads
    float mu  = sums[f] * invN;
    float ex2 = sqs[f] * invN;
    float a   = gms[f] * mu;
    float var = ex2 - 2.f * a * mu + a * a;
    float inv = rsqrtf(var + 1e-5f);
    float sc  = gw[f] * inv;
    scaleF[f] = sc;
    shiftF[f] = gb[f] - a * sc;
}

__global__ __launch_bounds__(256) void norm_apply_sp(
    u16* __restrict__ H, const float* __restrict__ scaleF,
    const float* __restrict__ shiftF, int n8) {
    int i = blockIdx.x * 256 + threadIdx.x;
    if (i >= n8) return;
    int f0 = (i & 31) << 3;   // 256 feats = 32 chunks of 8
    ushort8v h = *(const ushort8v*)&H[(size_t)i * 8];
    ushort8v o;
#pragma unroll
    for (int r = 0; r < 8; ++r) {
        float v = fmaxf(fmaf(bf16tof(h[r]), scaleF[f0 + r], shiftF[f0 + r]), 0.f);
        o[r] = bf16rn(v);
    }
    *(ushort8v*)&H[(size_t)i * 8] = o;
}

// ---------------- launch ----------------
extern "C" void kernel_launch(void* const* d_in, const int* in_sizes, int n_in,
                              void* d_out, int out_size, void* d_ws, size_t ws_size,
                              hipStream_t stream) {
    const float* x   = (const float*)d_in[0];
    const int*   ei  = (const int*)d_in[1];
    const float* ea  = (const float*)d_in[2];
    const float* Wr1 = (const float*)d_in[3];
    const float* b1  = (const float*)d_in[4];
    const float* Wo1 = (const float*)d_in[5];
    const float* Wr2 = (const float*)d_in[6];
    const float* b2  = (const float*)d_in[7];
    const float* Wo2 = (const float*)d_in[8];
    const float* Wr3 = (const float*)d_in[9];
    const float* b3  = (const float*)d_in[10];
    const float* Wo3 = (const float*)d_in[11];
    const float* Wr4 = (const float*)d_in[12];
    const float* b4  = (const float*)d_in[13];
    const float* Wo4 = (const float*)d_in[14];
    const float* gw  = (const float*)d_in[15];
    const float* gb  = (const float*)d_in[16];
    const float* gms = (const float*)d_in[17];

    const int Nn = in_sizes[0] / F_IN;   // 50000
    const int E  = in_sizes[1] / 2;      // 400000
    const int* src = ei;
    const int* dst = ei + E;

    char* wp = (char*)d_ws;
    auto alloc = [&](size_t bytes) -> void* {
        void* p = (void*)wp;
        wp += (bytes + 255) & ~(size_t)255;
        return p;
    };
    int*   counts   = (int*)alloc((size_t)Nn * 4);
    int*   rowptr   = (int*)alloc((size_t)(Nn + 1) * 4);
    int*   fillhead = (int*)alloc((size_t)Nn * 4);
    int*   col      = (int*)alloc((size_t)E * 4);
    float* wv       = (float*)alloc((size_t)E * 4);
    float* stats    = (float*)alloc(1024 * 4);
    float* sums = stats, *sqs = stats + 256, *scaleF = stats + 512, *shiftF = stats + 768;
    int*   bsum     = (int*)alloc(256 * 4);
    int*   boff     = (int*)alloc(256 * 4);
    // weights: L1-L3 single bf16 plane, L4 fp24 hi/lo
    u16* wr1 = (u16*)alloc(2u * 256 * 144);
    u16* wo1 = (u16*)alloc(2u * 256 * 144);
    u16* wr2 = (u16*)alloc(2u * 512 * 256);
    u16* wo2 = (u16*)alloc(2u * 512 * 256);
    u16* wr3 = (u16*)alloc(2u * 256 * 512);
    u16* wo3 = (u16*)alloc(2u * 256 * 512);
    u16* wr4h = (u16*)alloc(2u * 128 * 256); u16* wr4l = (u16*)alloc(2u * 128 * 256);
    u16* wo4h = (u16*)alloc(2u * 128 * 256); u16* wo4l = (u16*)alloc(2u * 128 * 256);

    // ---- lifetime-packed region (u16 units), Nn*1168*2 B = 116.8 MB ----
    // live:  X[0,144) | AG[144,400) | H1[400,656) | H2[656,1168)
    // reuse: Y3 -> [0,512)    (X,AG,H1 dead after GEMM2)
    //        H3 -> [656,912)  (H2 dead after GEMM3)
    //        Y4 -> [0,256)    (Y3 dead after L3 aggregate)
    u16* big = (u16*)alloc((size_t)Nn * 1168 * 2);
    const size_t NS = (size_t)Nn;
    u16* Xb  = big;
    u16* AG  = big + NS * 144;
    u16* H1  = big + NS * 400;
    u16* H2  = big + NS * 656;
    u16* Y3  = big;
    u16* H3  = big + NS * 656;
    u16* Y4  = big;

    const int TB = 256;
    // CSR build (parallel scan)
    int nbScan = (Nn + SCB - 1) / SCB;   // 25
    zero_i32<<<(Nn + TB - 1) / TB, TB, 0, stream>>>(counts, Nn);
    count_edges<<<(E + TB - 1) / TB, TB, 0, stream>>>(dst, counts, E);
    scan_partial<<<nbScan, TB, 0, stream>>>(counts, rowptr, bsum, Nn);
    scan_tops<<<1, TB, 0, stream>>>(bsum, boff, nbScan);
    scan_add<<<(Nn + 1 + TB - 1) / TB, TB, 0, stream>>>(rowptr, fillhead, boff, Nn, E);
    fill_edges<<<(E + TB - 1) / TB, TB, 0, stream>>>(src, dst, ea, fillhead, col, wv, E);

    // conversions
    int nx = Nn * F_IN;
    conv_bf<<<(nx + 255) / 256, 256, 0, stream>>>(x, Xb, nx);
    struct BC { const float* s; u16* d; int n; } bc[6] = {
        {Wr1, wr1, 256 * 144}, {Wo1, wo1, 256 * 144},
        {Wr2, wr2, 512 * 256}, {Wo2, wo2, 512 * 256},
        {Wr3, wr3, 256 * 512}, {Wo3, wo3, 256 * 512}};
    for (int i = 0; i < 6; ++i)
        conv_bf<<<(bc[i].n + 255) / 256, 256, 0, stream>>>(bc[i].s, bc[i].d, bc[i].n);
    conv_hl<<<(128 * 256 + 255) / 256, 256, 0, stream>>>(Wr4, wr4h, wr4l, 128 * 256);
    conv_hl<<<(128 * 256 + 255) / 256, 256, 0, stream>>>(Wo4, wo4h, wo4l, 128 * 256);

    int mB = (Nn + GBM - 1) / GBM;              // 391
    int g3 = (((Nn + 2) / 3) + 3) / 4;          // 3 nodes/wave grids
    int g2 = (((Nn + 1) / 2) + 3) / 4;          // 2 nodes/wave grids
    int g4 = (((Nn + 3) / 4) + 3) / 4;          // 4 nodes/wave grids

    // Layer 1 (aggregate-first): AG = agg(X); H1 = relu([AG|X]*[Wr1|Wo1]^T + b1)
    aggregate_sp<18, 3, 0><<<g3, TB, 0, stream>>>(Xb, 144, rowptr, col, wv,
                                                  nullptr, AG, nullptr, 144, Nn);
    gemm7<true, 1><<<dim3(2, mB), 256, 0, stream>>>(AG, Xb, wr1, nullptr, wo1, nullptr,
                                                    b1, nullptr, H1,
                                                    Nn, 144, 256, 256, 1);
    // Layer 2 (aggregate-first): AG = agg(H1); H2 = relu([AG|H1]*[Wr2|Wo2]^T + b2)
    aggregate_sp<32, 2, 0><<<g2, TB, 0, stream>>>(H1, 256, rowptr, col, wv,
                                                  nullptr, AG, nullptr, 256, Nn);
    gemm7<true, 1><<<dim3(4, mB), 256, 0, stream>>>(AG, H1, wr2, nullptr, wo2, nullptr,
                                                    b2, nullptr, H2,
                                                    Nn, 256, 512, 512, 1);
    // Layer 3 (transform-first): Y3 = [H2*Wr3^T | H2*Wo3^T + b3]; H3 = agg(Yrel)+Yroot
    gemm7<false, 1><<<dim3(4, mB), 256, 0, stream>>>(H2, H2, wr3, nullptr, wo3, nullptr,
                                                     nullptr, b3, Y3,
                                                     Nn, 512, 256, 512, 0);
    aggregate_sp<32, 2, 1><<<g2, TB, 0, stream>>>(Y3, 512, rowptr, col, wv,
                                                  Y3 + 256, H3, nullptr, 256, Nn);
    // GraphNorm + relu in place on H3
    zero_f32<<<2, TB, 0, stream>>>(stats, 512);
    colstats2<<<800, TB, 0, stream>>>(H3, sums, sqs, Nn);
    norm_prep<<<1, 256, 0, stream>>>(sums, sqs, gw, gb, gms, scaleF, shiftF, 1.0f / Nn);
    norm_apply_sp<<<(Nn * 32 + TB - 1) / TB, TB, 0, stream>>>(H3, scaleF, shiftF, Nn * 32);
    // Layer 4 (transform-first, fp24 weights): Y4 = [H3*Wr4^T | H3*Wo4^T + b4] (bf16);
    // out = agg(Y4rel) + Y4root (f32)
    gemm7<false, 2><<<dim3(2, mB), 256, 0, stream>>>(H3, H3, wr4h, wr4l, wo4h, wo4l,
                                                     nullptr, b4, Y4,
                                                     Nn, 256, 128, 256, 0);
    aggregate_sp<16, 4, 2><<<g4, TB, 0, stream>>>(Y4, 256, rowptr, col, wv,
                                                  Y4 + 128, nullptr, (float*)d_out, 128, Nn);
}